// Round 4
// baseline (1421.908 us; speedup 1.0000x reference)
//
#include <hip/hip_runtime.h>
#include <math.h>

typedef __attribute__((ext_vector_type(8))) short s8;
typedef __attribute__((ext_vector_type(8))) unsigned short us8;
typedef __attribute__((ext_vector_type(4))) float f4;
typedef __attribute__((ext_vector_type(4))) unsigned short us4;
typedef __attribute__((ext_vector_type(4))) unsigned int u32x4;

#define DEVI __device__ __forceinline__

static const int NPIX = 65536;   // 256*256

DEVI float b2f(unsigned short u) {
    unsigned int v = ((unsigned int)u) << 16;
    float f; __builtin_memcpy(&f, &v, 4); return f;
}
DEVI unsigned short f2b(float f) {
    unsigned int u; __builtin_memcpy(&u, &f, 4);
    unsigned int r = (u + 0x7FFFu + ((u >> 16) & 1u)) >> 16;
    return (unsigned short)r;
}
DEVI float geluf(float x) { return 0.5f * x * (1.0f + erff(x * 0.70710678118f)); }

// ---------------------------------------------------------------------------
// LayerNorm + transpose: x f32 [b][192][px] -> xnt bf16 [b*px][192]
// ---------------------------------------------------------------------------
__global__ __launch_bounds__(256) void lnt_k(const float* __restrict__ X,
                                             const float* __restrict__ gw,
                                             const float* __restrict__ gb,
                                             unsigned short* __restrict__ Out)
{
    const int i = blockIdx.x * 256 + threadIdx.x;    // 0..262143
    const int b = i >> 16, px = i & 65535;
    const float* xp = X + (size_t)b * 192 * NPIX + px;

    unsigned int pk[96];
    float sum = 0.f, ssq = 0.f;
    #pragma unroll
    for (int c = 0; c < 192; c++) {
        float v = xp[(size_t)c * NPIX];
        sum += v; ssq += v * v;
        unsigned int h = f2b(v);
        if (c & 1) pk[c >> 1] |= h << 16;
        else       pk[c >> 1] = h;
    }
    float mu = sum * (1.0f / 192.0f);
    float var = ssq * (1.0f / 192.0f) - mu * mu;
    float rs = rsqrtf(var + 1e-5f);

    #pragma unroll
    for (int c2 = 0; c2 < 96; c2++) {
        int c = c2 * 2;
        float lo = b2f((unsigned short)(pk[c2] & 0xFFFF));
        float hi = b2f((unsigned short)(pk[c2] >> 16));
        lo = (lo - mu) * rs * gw[c] + gb[c];
        hi = (hi - mu) * rs * gw[c + 1] + gb[c + 1];
        pk[c2] = (unsigned int)f2b(lo) | ((unsigned int)f2b(hi) << 16);
    }
    u32x4* dst = (u32x4*)(Out + (size_t)i * 192);
    #pragma unroll
    for (int j = 0; j < 6; j++) {
        u32x4 v = { pk[4 * j], pk[4 * j + 1], pk[4 * j + 2], pk[4 * j + 3] };
        dst[j] = v;
    }
}

// ---------------------------------------------------------------------------
// LDS-free GEMM (A=pixels, B=weights): Out[b,m,px] bf16 [ch][px] layout.
// Used for qkv (krow/context/qctx consume [ch][px]).
// ---------------------------------------------------------------------------
template<int M, int MQ, bool DO_GELU>
__global__ __launch_bounds__(512) void gemmT_k(
    const unsigned short* __restrict__ xnt, const unsigned short* __restrict__ Wb,
    const float* __restrict__ bias, unsigned short* __restrict__ Out)
{
    constexpr int OT = MQ / 16;
    const int tid = threadIdx.x, bid = blockIdx.x;
    const int wave = tid >> 6, lane = tid & 63;
    const int lr = lane & 15, lg = lane >> 4;
    const int mq = wave >> 1, ph = wave & 1;
    const int b = bid >> 9;
    const int px0 = (bid & 511) * 128 + ph * 64;

    const unsigned short* xb = xnt + ((size_t)(b * NPIX + px0) + lr) * 192 + lg * 8;
    const unsigned short* wb = Wb + ((size_t)(mq * MQ + lr)) * 192 + lg * 8;

    f4 acc[4][OT];
    #pragma unroll
    for (int i = 0; i < 4; i++)
        #pragma unroll
        for (int j = 0; j < OT; j++) acc[i][j] = (f4)0.0f;

    #pragma unroll
    for (int k0 = 0; k0 < 192; k0 += 32) {
        s8 a[4];
        #pragma unroll
        for (int pt = 0; pt < 4; pt++)
            a[pt] = *(const s8*)(xb + (size_t)pt * 16 * 192 + k0);
        #pragma unroll
        for (int ot = 0; ot < OT; ot++) {
            s8 w = *(const s8*)(wb + (size_t)ot * 16 * 192 + k0);
            #pragma unroll
            for (int pt = 0; pt < 4; pt++)
                acc[pt][ot] = __builtin_amdgcn_mfma_f32_16x16x32_bf16(a[pt], w, acc[pt][ot], 0, 0, 0);
        }
    }

    #pragma unroll
    for (int ot = 0; ot < OT; ot++) {
        const int row = mq * MQ + ot * 16 + lr;
        const float bi = bias[row];
        unsigned short* orow = Out + ((size_t)b * M + row) * NPIX + px0 + lg * 4;
        #pragma unroll
        for (int pt = 0; pt < 4; pt++) {
            us4 o;
            #pragma unroll
            for (int r = 0; r < 4; r++) {
                float v = acc[pt][ot][r] + bi;
                if (DO_GELU) v = geluf(v);
                o[r] = f2b(v);
            }
            *(us4*)(orow + pt * 16) = o;
        }
    }
}

// ---------------------------------------------------------------------------
// LDS-free GEMM (A=weights, B=pixels): writes TRANSPOSED bf16 Out[px][M].
// D reg-axis = out-channel -> us4 stores along channel dim.
// ---------------------------------------------------------------------------
template<int K, int M, int MQ, bool DO_GELU>
__global__ __launch_bounds__(512) void gemmTw_k(
    const unsigned short* __restrict__ xnt, const unsigned short* __restrict__ Wb,
    const float* __restrict__ bias, unsigned short* __restrict__ Out)
{
    constexpr int OT = MQ / 16;
    const int tid = threadIdx.x, bid = blockIdx.x;
    const int wave = tid >> 6, lane = tid & 63;
    const int lr = lane & 15, lg = lane >> 4;
    const int mq = wave >> 1, ph = wave & 1;
    const int b = bid >> 9;
    const int px0 = (bid & 511) * 128 + ph * 64;

    const unsigned short* xb = xnt + ((size_t)(b * NPIX + px0) + lr) * K + lg * 8;
    const unsigned short* wb = Wb + ((size_t)(mq * MQ + lr)) * K + lg * 8;

    f4 acc[OT][4];
    #pragma unroll
    for (int i = 0; i < OT; i++)
        #pragma unroll
        for (int j = 0; j < 4; j++) acc[i][j] = (f4)0.0f;

    #pragma unroll
    for (int k0 = 0; k0 < K; k0 += 32) {
        s8 bf[4];
        #pragma unroll
        for (int nt = 0; nt < 4; nt++)
            bf[nt] = *(const s8*)(xb + (size_t)nt * 16 * K + k0);
        #pragma unroll
        for (int ot = 0; ot < OT; ot++) {
            s8 af = *(const s8*)(wb + (size_t)ot * 16 * K + k0);
            #pragma unroll
            for (int nt = 0; nt < 4; nt++)
                acc[ot][nt] = __builtin_amdgcn_mfma_f32_16x16x32_bf16(af, bf[nt], acc[ot][nt], 0, 0, 0);
        }
    }

    #pragma unroll
    for (int ot = 0; ot < OT; ot++) {
        const int chb = mq * MQ + ot * 16 + lg * 4;
        f4 bi = *(const f4*)&bias[chb];
        #pragma unroll
        for (int nt = 0; nt < 4; nt++) {
            const int px = px0 + nt * 16 + lr;
            us4 o;
            #pragma unroll
            for (int r = 0; r < 4; r++) {
                float v = acc[ot][nt][r] + bi[r];
                if (DO_GELU) v = geluf(v);
                o[r] = f2b(v);
            }
            *(us4*)(Out + ((size_t)(b * NPIX + px)) * M + chb) = o;
        }
    }
}

// ---------------------------------------------------------------------------
// LDS-free GEMM reading transposed input (A=pixels from xt[px][K]),
// writing f32 [ch][px] with bias + residual (16B f32x4 stores).
// ---------------------------------------------------------------------------
template<int K, int M, int MQ>
__global__ __launch_bounds__(512) void gemmTr_k(
    const unsigned short* __restrict__ xt, const unsigned short* __restrict__ Wb,
    const float* __restrict__ bias, const float* __restrict__ resid,
    float* __restrict__ Out)
{
    constexpr int OT = MQ / 16;
    const int tid = threadIdx.x, bid = blockIdx.x;
    const int wave = tid >> 6, lane = tid & 63;
    const int lr = lane & 15, lg = lane >> 4;
    const int mq = wave >> 1, ph = wave & 1;
    const int b = bid >> 9;
    const int px0 = (bid & 511) * 128 + ph * 64;

    const unsigned short* xb = xt + ((size_t)(b * NPIX + px0) + lr) * K + lg * 8;
    const unsigned short* wb = Wb + ((size_t)(mq * MQ + lr)) * K + lg * 8;

    f4 acc[4][OT];
    #pragma unroll
    for (int i = 0; i < 4; i++)
        #pragma unroll
        for (int j = 0; j < OT; j++) acc[i][j] = (f4)0.0f;

    #pragma unroll
    for (int k0 = 0; k0 < K; k0 += 32) {
        s8 a[4];
        #pragma unroll
        for (int pt = 0; pt < 4; pt++)
            a[pt] = *(const s8*)(xb + (size_t)pt * 16 * K + k0);
        #pragma unroll
        for (int ot = 0; ot < OT; ot++) {
            s8 w = *(const s8*)(wb + (size_t)ot * 16 * K + k0);
            #pragma unroll
            for (int pt = 0; pt < 4; pt++)
                acc[pt][ot] = __builtin_amdgcn_mfma_f32_16x16x32_bf16(a[pt], w, acc[pt][ot], 0, 0, 0);
        }
    }

    #pragma unroll
    for (int ot = 0; ot < OT; ot++) {
        const int ch = mq * MQ + ot * 16 + lr;
        const float bi = bias[ch];
        #pragma unroll
        for (int pt = 0; pt < 4; pt++) {
            size_t off = ((size_t)b * M + ch) * NPIX + px0 + pt * 16 + lg * 4;
            f4 rv = *(const f4*)(resid + off);
            f4 o;
            #pragma unroll
            for (int r = 0; r < 4; r++) o[r] = acc[pt][ot][r] + bi + rv[r];
            *(f4*)(Out + off) = o;
        }
    }
}

// ---------------------------------------------------------------------------
// Per-row (b, k-channel) max + log-sum-exp over all pixels.
// ---------------------------------------------------------------------------
__global__ __launch_bounds__(256) void krow_k(const unsigned short* __restrict__ qkv,
                                              float* __restrict__ koff)
{
    int r = blockIdx.x;
    int b = r / 192, ch = 192 + (r % 192);
    const unsigned short* Kp = qkv + ((size_t)b * 576 + ch) * NPIX;
    int tid = threadIdx.x;
    float m = -1e30f, s = 0.f;
    for (int i = 0; i < 256; i++) {
        float v = b2f(Kp[tid + (size_t)i * 256]);
        if (v > m) { s = s * __expf(m - v) + 1.f; m = v; }
        else s += __expf(v - m);
    }
    __shared__ float ms[256], ss[256];
    ms[tid] = m; ss[tid] = s;
    __syncthreads();
    for (int off = 128; off > 0; off >>= 1) {
        if (tid < off) {
            float m2 = ms[tid + off], s2 = ss[tid + off];
            float M2 = fmaxf(ms[tid], m2);
            ss[tid] = ss[tid] * __expf(ms[tid] - M2) + s2 * __expf(m2 - M2);
            ms[tid] = M2;
        }
        __syncthreads();
    }
    if (tid == 0) koff[r] = ms[0] + logf(ss[0]);
}

__global__ void zero_k(float* __restrict__ p, int n)
{
    int i = blockIdx.x * 256 + threadIdx.x;
    if (i < n) p[i] = 0.f;
}

__global__ void cvt_k(const float* __restrict__ src, unsigned short* __restrict__ dst, int n)
{
    int i = blockIdx.x * 256 + threadIdx.x;
    if (i < n) dst[i] = f2b(src[i]);
}

// ---------------------------------------------------------------------------
// context: ctxT[b,h,d,c] = sum_n exp(k[c,n]-koff[c]) * v[d,n]
// ---------------------------------------------------------------------------
__global__ __launch_bounds__(64) void context_k(const unsigned short* __restrict__ qkv,
                                                const float* __restrict__ koff,
                                                float* __restrict__ ctxT)
{
    int bid = blockIdx.x;
    int bh = bid >> 6, chunk = bid & 63;
    int b = bh >> 3, h = bh & 7;
    int lane = threadIdx.x, lr = lane & 15, lg = lane >> 4;
    size_t nbase = (size_t)chunk * 1024 + lg * 8;

    int c0 = h * 24 + lr;
    int c1 = h * 24 + 16 + lr;
    float ko0 = koff[b * 192 + c0];
    int i1 = b * 192 + c1; if (i1 > 775) i1 = 775;
    float ko1 = koff[i1];
    bool val1 = lr < 8;

    const unsigned short* k0p = qkv + ((size_t)b * 576 + 192 + c0) * NPIX + nbase;
    const unsigned short* k1p = qkv + ((size_t)b * 576 + 192 + c1) * NPIX + nbase;
    const unsigned short* v0p = qkv + ((size_t)b * 576 + 384 + h * 24 + lr) * NPIX + nbase;
    const unsigned short* v1p = qkv + ((size_t)b * 576 + 384 + h * 24 + 16 + lr) * NPIX + nbase;

    f4 acc[2][2];
    #pragma unroll
    for (int i = 0; i < 2; i++) for (int j = 0; j < 2; j++) acc[i][j] = (f4)0.0f;

    for (int s = 0; s < 32; s++) {
        int off = s * 32;
        s8 kr0 = *(const s8*)(k0p + off);
        s8 kr1 = *(const s8*)(k1p + off);
        s8 vr0 = *(const s8*)(v0p + off);
        s8 vr1 = *(const s8*)(v1p + off);
        s8 p0, p1;
        #pragma unroll
        for (int j = 0; j < 8; j++) {
            p0[j] = (short)f2b(__expf(b2f((unsigned short)kr0[j]) - ko0));
            p1[j] = val1 ? (short)f2b(__expf(b2f((unsigned short)kr1[j]) - ko1)) : (short)0;
        }
        acc[0][0] = __builtin_amdgcn_mfma_f32_16x16x32_bf16(p0, vr0, acc[0][0], 0, 0, 0);
        acc[0][1] = __builtin_amdgcn_mfma_f32_16x16x32_bf16(p0, vr1, acc[0][1], 0, 0, 0);
        acc[1][0] = __builtin_amdgcn_mfma_f32_16x16x32_bf16(p1, vr0, acc[1][0], 0, 0, 0);
        acc[1][1] = __builtin_amdgcn_mfma_f32_16x16x32_bf16(p1, vr1, acc[1][1], 0, 0, 0);
    }
    float* base = ctxT + (size_t)(b * 8 + h) * 1024;
    #pragma unroll
    for (int mt = 0; mt < 2; mt++)
        #pragma unroll
        for (int ct = 0; ct < 2; ct++)
            #pragma unroll
            for (int r = 0; r < 4; r++) {
                int c = mt * 16 + lg * 4 + r;
                int d = ct * 16 + lr;
                atomicAdd(base + d * 32 + c, acc[mt][ct][r]);
            }
}

// ---------------------------------------------------------------------------
// fused: q-softmax -> ctx apply (MFMA) -> out-proj GEMM -> + x residual
// ---------------------------------------------------------------------------
__global__ __launch_bounds__(256) void qctx_proj_k(
    const unsigned short* __restrict__ qkv, const float* __restrict__ ctxT,
    const unsigned short* __restrict__ outWb, const float* __restrict__ outBias,
    const float* __restrict__ xres, float* __restrict__ Out)
{
    __shared__ unsigned short E[64][264];
    __shared__ float sden[8][64];
    __shared__ unsigned short outp[64][200];

    int tid = threadIdx.x, bid = blockIdx.x;
    int b = bid >> 10, n0 = (bid & 1023) * 64;
    int p = tid & 63, g = tid >> 6;

    #pragma unroll
    for (int hh = 0; hh < 2; hh++) {
        int h = g * 2 + hh;
        float s = 0.f;
        const unsigned short* Q = qkv + ((size_t)b * 576 + h * 24) * NPIX + n0 + p;
        #pragma unroll 4
        for (int cc = 0; cc < 24; cc++) {
            float e = __expf(b2f(Q[(size_t)cc * NPIX]));
            s += e;
            E[p][h * 32 + cc] = f2b(e);
        }
        #pragma unroll
        for (int cc = 24; cc < 32; cc++) E[p][h * 32 + cc] = 0;
        sden[h][p] = s;
    }
    __syncthreads();

    int wave = tid >> 6, lane = tid & 63, lr = lane & 15, lg = lane >> 4;

    #pragma unroll
    for (int hh = 0; hh < 2; hh++) {
        int h = wave * 2 + hh;
        s8 af[2];
        #pragma unroll
        for (int mt = 0; mt < 2; mt++) {
            const float* cp = ctxT + ((size_t)(b * 8 + h) * 32 + mt * 16 + lr) * 32 + lg * 8;
            s8 a;
            #pragma unroll
            for (int j = 0; j < 8; j++) a[j] = (short)f2b(cp[j]);
            af[mt] = a;
        }
        #pragma unroll
        for (int nt = 0; nt < 4; nt++) {
            s8 bf = *(const s8*)&E[nt * 16 + lr][h * 32 + lg * 8];
            f4 z = (f4)0.0f;
            f4 d0 = __builtin_amdgcn_mfma_f32_16x16x32_bf16(af[0], bf, z, 0, 0, 0);
            f4 d1 = __builtin_amdgcn_mfma_f32_16x16x32_bf16(af[1], bf, z, 0, 0, 0);
            int n = nt * 16 + lr;
            float sinv = 1.0f / sden[h][n];
            us4 w0;
            #pragma unroll
            for (int r = 0; r < 4; r++) w0[r] = f2b(d0[r] * sinv);
            *(us4*)&outp[n][h * 24 + lg * 4] = w0;
            if (lg < 2) {
                us4 w1;
                #pragma unroll
                for (int r = 0; r < 4; r++) w1[r] = f2b(d1[r] * sinv);
                *(us4*)&outp[n][h * 24 + 16 + lg * 4] = w1;
            }
        }
    }
    __syncthreads();

    f4 acc[3][4];
    #pragma unroll
    for (int i = 0; i < 3; i++) for (int j = 0; j < 4; j++) acc[i][j] = (f4)0.0f;
    #pragma unroll
    for (int k0 = 0; k0 < 192; k0 += 32) {
        s8 bf[4];
        #pragma unroll
        for (int nt = 0; nt < 4; nt++)
            bf[nt] = *(const s8*)&outp[nt * 16 + lr][k0 + lg * 8];
        #pragma unroll
        for (int mt = 0; mt < 3; mt++) {
            s8 af = *(const s8*)&outWb[(size_t)(wave * 48 + mt * 16 + lr) * 192 + k0 + lg * 8];
            #pragma unroll
            for (int nt = 0; nt < 4; nt++)
                acc[mt][nt] = __builtin_amdgcn_mfma_f32_16x16x32_bf16(af, bf[nt], acc[mt][nt], 0, 0, 0);
        }
    }
    #pragma unroll
    for (int mt = 0; mt < 3; mt++)
        #pragma unroll
        for (int nt = 0; nt < 4; nt++) {
            int col = n0 + nt * 16 + lr;
            #pragma unroll
            for (int r = 0; r < 4; r++) {
                int row = wave * 48 + mt * 16 + lg * 4 + r;
                size_t off = ((size_t)b * 192 + row) * NPIX + col;
                Out[off] = acc[mt][nt][r] + outBias[row] + xres[off];
            }
        }
}

// ---------------------------------------------------------------------------
// depthwise 3x3 + gelu on TRANSPOSED layout: h1t[px][384] -> h2t[px][384].
// Block: 32 ch x 8 y x 64 x. LDS halo tile [4cg][10y][66x] us8 (42.2KB).
// Lane owns 8 ch (one us8) at one x; slides 3x3 us8 window down 8 rows.
// ---------------------------------------------------------------------------
__global__ __launch_bounds__(256) void dwconv_t_k(
    const unsigned short* __restrict__ h1t, const float* __restrict__ w,
    const float* __restrict__ bias, unsigned short* __restrict__ h2t)
{
    __shared__ unsigned short tile[4][10][528];   // [cg][yy][xx*8]
    const int bz = blockIdx.z;                    // b*12 + chgrp
    const int b = bz / 12, cb = (bz % 12) * 32;
    const int y0 = blockIdx.y * 8, x0 = blockIdx.x * 64;
    const int tid = threadIdx.x;

    for (int it = 0; it < 11; ++it) {
        int idx = it * 256 + tid;
        if (idx < 2640) {
            int cg = idx & 3, rem = idx >> 2;
            int xx = rem % 66, yy = rem / 66;
            int gy = y0 + yy - 1, gx = x0 + xx - 1;
            us8 v;
            if (gy >= 0 && gy < 256 && gx >= 0 && gx < 256)
                v = *(const us8*)(h1t + ((size_t)b * NPIX + gy * 256 + gx) * 384 + cb + cg * 8);
            else { us8 z = {0,0,0,0,0,0,0,0}; v = z; }
            *(us8*)&tile[cg][yy][xx * 8] = v;
        }
    }

    const int x = tid & 63, cg = tid >> 6;
    const int c0 = cb + cg * 8;
    float wr[9][8];
    #pragma unroll
    for (int j = 0; j < 9; j++)
        #pragma unroll
        for (int i = 0; i < 8; i++) wr[j][i] = w[(c0 + i) * 9 + j];
    float bi[8];
    #pragma unroll
    for (int i = 0; i < 8; i++) bi[i] = bias[c0 + i];
    __syncthreads();

    us8 w0[3], w1[3], w2[3];
    #pragma unroll
    for (int dx = 0; dx < 3; dx++) {
        w0[dx] = *(const us8*)&tile[cg][0][(x + dx) * 8];
        w1[dx] = *(const us8*)&tile[cg][1][(x + dx) * 8];
    }

    #pragma unroll
    for (int y = 0; y < 8; y++) {
        #pragma unroll
        for (int dx = 0; dx < 3; dx++)
            w2[dx] = *(const us8*)&tile[cg][y + 2][(x + dx) * 8];

        float a[8];
        #pragma unroll
        for (int i = 0; i < 8; i++) a[i] = bi[i];
        #pragma unroll
        for (int dx = 0; dx < 3; dx++) {
            #pragma unroll
            for (int i = 0; i < 8; i++) {
                a[i] += wr[0 * 3 + dx][i] * b2f(w0[dx][i]);
                a[i] += wr[1 * 3 + dx][i] * b2f(w1[dx][i]);
                a[i] += wr[2 * 3 + dx][i] * b2f(w2[dx][i]);
            }
        }
        us8 ov;
        #pragma unroll
        for (int i = 0; i < 8; i++) ov[i] = f2b(geluf(a[i]));
        *(us8*)(h2t + ((size_t)b * NPIX + (y0 + y) * 256 + x0 + x) * 384 + c0) = ov;

        #pragma unroll
        for (int dx = 0; dx < 3; dx++) { w0[dx] = w1[dx]; w1[dx] = w2[dx]; }
    }
}

// ---------------------------------------------------------------------------
extern "C" void kernel_launch(void* const* d_in, const int* in_sizes, int n_in,
                              void* d_out, int out_size, void* d_ws, size_t ws_size,
                              hipStream_t stream)
{
    const float* x    = (const float*)d_in[0];
    const float* ln1g = (const float*)d_in[1];
    const float* ln1b = (const float*)d_in[2];
    const float* qkvw = (const float*)d_in[3];
    const float* qkvb = (const float*)d_in[4];
    const float* outw = (const float*)d_in[5];
    const float* outb = (const float*)d_in[6];
    const float* ln2g = (const float*)d_in[7];
    const float* ln2b = (const float*)d_in[8];
    const float* w1   = (const float*)d_in[9];
    const float* b1   = (const float*)d_in[10];
    const float* dww  = (const float*)d_in[11];
    const float* dwb  = (const float*)d_in[12];
    const float* w2   = (const float*)d_in[13];
    const float* b2   = (const float*)d_in[14];
    float* out = (float*)d_out;

    char* ws = (char*)d_ws;
    unsigned short* qkv = (unsigned short*)ws;                            // [0, 302MB)  [ch][px]
    unsigned short* h1t = (unsigned short*)ws;                            // [0, 201MB)  [px][384]
    unsigned short* h2t = (unsigned short*)(ws + (size_t)201326592);      // [201MB, 403MB) [px][384]
    unsigned short* xnt = (unsigned short*)(ws + (size_t)301989888);      // [302MB, 403MB) [px][192]
    size_t off = (size_t)402653184;
    float* koff = (float*)(ws + off); off += 4096;
    float* ctxT = (float*)(ws + off); off += 131072;
    unsigned short* qkvwb = (unsigned short*)(ws + off); off += 221184;
    unsigned short* outwb = (unsigned short*)(ws + off); off += 73728 * 2;
    unsigned short* w1b   = (unsigned short*)(ws + off); off += 147456;
    unsigned short* w2b   = (unsigned short*)(ws + off); off += 147456;

    cvt_k<<<(110592 + 255) / 256, 256, 0, stream>>>(qkvw, qkvwb, 110592);
    cvt_k<<<(36864 + 255) / 256, 256, 0, stream>>>(outw, outwb, 36864);
    cvt_k<<<(73728 + 255) / 256, 256, 0, stream>>>(w1, w1b, 73728);
    cvt_k<<<(73728 + 255) / 256, 256, 0, stream>>>(w2, w2b, 73728);

    // 1) LN1 + transpose -> xnt
    lnt_k<<<1024, 256, 0, stream>>>(x, ln1g, ln1b, xnt);

    // 2) qkv GEMM -> qkv [ch][px]
    gemmT_k<576, 144, false><<<2048, 512, 0, stream>>>(xnt, qkvwb, qkvb, qkv);

    // 3) k-row softmax offsets
    krow_k<<<768, 256, 0, stream>>>(qkv, koff);

    // 4) context accumulation
    zero_k<<<128, 256, 0, stream>>>(ctxT, 32768);
    context_k<<<2048, 64, 0, stream>>>(qkv, koff, ctxT);

    // 5) q softmax + ctx apply + out-proj + residual -> x2 (d_out, f32)
    qctx_proj_k<<<4096, 256, 0, stream>>>(qkv, ctxT, outwb, outb, x, out);

    // 6) LN2 + transpose -> xnt
    lnt_k<<<1024, 256, 0, stream>>>(out, ln2g, ln2b, xnt);

    // 7) w1 GEMM + gelu -> h1t [px][384]  (transposed output)
    gemmTw_k<192, 384, 96, true><<<2048, 512, 0, stream>>>(xnt, w1b, b1, h1t);

    // 8) depthwise 3x3 + gelu on transposed layout -> h2t [px][384]
    dwconv_t_k<<<dim3(4, 32, 48), 256, 0, stream>>>(h1t, dww, dwb, h2t);

    // 9) w2 GEMM + bias + x2 residual -> d_out f32 [ch][px]
    gemmTr_k<384, 192, 48><<<2048, 512, 0, stream>>>(h2t, w2b, b2, out, out);
}

// Round 5
// 1242.704 us; speedup vs baseline: 1.1442x; 1.1442x over previous
//
#include <hip/hip_runtime.h>
#include <math.h>

typedef __attribute__((ext_vector_type(8))) short s8;
typedef __attribute__((ext_vector_type(8))) unsigned short us8;
typedef __attribute__((ext_vector_type(4))) float f4;
typedef __attribute__((ext_vector_type(4))) unsigned short us4;
typedef __attribute__((ext_vector_type(4))) unsigned int u32x4;

#define DEVI __device__ __forceinline__

static const int NPIX = 65536;   // 256*256

DEVI float b2f(unsigned short u) {
    unsigned int v = ((unsigned int)u) << 16;
    float f; __builtin_memcpy(&f, &v, 4); return f;
}
DEVI unsigned short f2b(float f) {
    unsigned int u; __builtin_memcpy(&u, &f, 4);
    unsigned int r = (u + 0x7FFFu + ((u >> 16) & 1u)) >> 16;
    return (unsigned short)r;
}
DEVI float geluf(float x) { return 0.5f * x * (1.0f + erff(x * 0.70710678118f)); }

DEVI void gload_lds16(const unsigned short* g, unsigned short* l) {
    __builtin_amdgcn_global_load_lds(
        (const __attribute__((address_space(1))) unsigned int*)g,
        (__attribute__((address_space(3))) unsigned int*)l,
        16, 0, 0);
}

// ---------------------------------------------------------------------------
// LayerNorm + transpose: x f32 [b][192][px] -> xnt bf16 [b*px][192]
// ---------------------------------------------------------------------------
__global__ __launch_bounds__(256) void lnt_k(const float* __restrict__ X,
                                             const float* __restrict__ gw,
                                             const float* __restrict__ gb,
                                             unsigned short* __restrict__ Out)
{
    const int i = blockIdx.x * 256 + threadIdx.x;    // 0..262143
    const int b = i >> 16, px = i & 65535;
    const float* xp = X + (size_t)b * 192 * NPIX + px;

    unsigned int pk[96];
    float sum = 0.f, ssq = 0.f;
    #pragma unroll
    for (int c = 0; c < 192; c++) {
        float v = xp[(size_t)c * NPIX];
        sum += v; ssq += v * v;
        unsigned int h = f2b(v);
        if (c & 1) pk[c >> 1] |= h << 16;
        else       pk[c >> 1] = h;
    }
    float mu = sum * (1.0f / 192.0f);
    float var = ssq * (1.0f / 192.0f) - mu * mu;
    float rs = rsqrtf(var + 1e-5f);

    #pragma unroll
    for (int c2 = 0; c2 < 96; c2++) {
        int c = c2 * 2;
        float lo = b2f((unsigned short)(pk[c2] & 0xFFFF));
        float hi = b2f((unsigned short)(pk[c2] >> 16));
        lo = (lo - mu) * rs * gw[c] + gb[c];
        hi = (hi - mu) * rs * gw[c + 1] + gb[c + 1];
        pk[c2] = (unsigned int)f2b(lo) | ((unsigned int)f2b(hi) << 16);
    }
    u32x4* dst = (u32x4*)(Out + (size_t)i * 192);
    #pragma unroll
    for (int j = 0; j < 6; j++) {
        u32x4 v = { pk[4 * j], pk[4 * j + 1], pk[4 * j + 2], pk[4 * j + 3] };
        dst[j] = v;
    }
}

// ---------------------------------------------------------------------------
// Staged GEMM over channels (m97-style): block = 64 px x 192 oc-chunk.
// X[gp][K] staged whole-K in LDS via global_load_lds (swizzled source,
// linear LDS dest, swizzled read -> conflict-free ds_read_b128).
// W frags from L2 with 1-iter register prefetch.
// MODE 0: out bf16 [b][OCTOT][px], bias              (qkv)
// MODE 1: out bf16 [gp][OCTOT], bias+gelu            (w1 -> h1t)
// MODE 2: out f32  [b][OCTOT][px], bias+resid        (w2 -> d_out)
// ---------------------------------------------------------------------------
template<int K, int MODE>
__global__ __launch_bounds__(256) void gemm2_k(
    const unsigned short* __restrict__ X, const unsigned short* __restrict__ Wb,
    const float* __restrict__ bias, const float* __restrict__ resid,
    void* __restrict__ Out, int OCTOT)
{
    constexpr int ROWS = 64;
    constexpr int CPR = K / 8;            // 16B chunks per row
    __shared__ unsigned short tile[ROWS * K];

    const int tid = threadIdx.x;
    const int wave = tid >> 6, lane = tid & 63;
    const int lr = lane & 15, lg = lane >> 4;
    const int gp0 = blockIdx.x * ROWS;    // global pixel (incl. batch)
    const int ocb = blockIdx.y * 192 + wave * 48;

    // --- stage X tile: inverse-swizzled global source -> linear LDS dest ---
    constexpr int CALLS = (ROWS * CPR) / 256;
    {
        const unsigned short* Xb = X + (size_t)gp0 * K;
        #pragma unroll
        for (int j = 0; j < CALLS; j++) {
            int ci = (wave * CALLS + j) * 64 + lane;
            int row = (int)((unsigned)ci / (unsigned)CPR);
            int c = ci - row * CPR;
            int csw = (c & ~7) | ((c ^ row) & 7);
            gload_lds16(Xb + (size_t)row * K + csw * 8, &tile[ci * 8]);
        }
    }

    // --- W prefetch (L2) overlaps staging ---
    const unsigned short* wrow = Wb + (size_t)(ocb + lr) * K + lg * 8;
    s8 wf[3];
    #pragma unroll
    for (int ot = 0; ot < 3; ot++) wf[ot] = *(const s8*)(wrow + (size_t)ot * 16 * K);

    __syncthreads();

    const int xr = lr & 7;
    f4 acc[4][3];
    #pragma unroll
    for (int i = 0; i < 4; i++)
        #pragma unroll
        for (int j = 0; j < 3; j++) acc[i][j] = (f4)0.0f;

    #pragma unroll
    for (int k0 = 0; k0 < K; k0 += 32) {
        s8 wn[3];
        if (k0 + 32 < K) {
            #pragma unroll
            for (int ot = 0; ot < 3; ot++)
                wn[ot] = *(const s8*)(wrow + (size_t)ot * 16 * K + k0 + 32);
        }
        const int kc = (k0 >> 3) + lg;
        const int kcs = (kc & ~7) | ((kc ^ xr) & 7);
        s8 a[4];
        #pragma unroll
        for (int pt = 0; pt < 4; pt++) {
            int row = pt * 16 + lr;
            a[pt] = *(const s8*)&tile[(row * CPR + kcs) * 8];
        }
        #pragma unroll
        for (int ot = 0; ot < 3; ot++)
            #pragma unroll
            for (int pt = 0; pt < 4; pt++)
                acc[pt][ot] = (MODE == 1)
                    ? __builtin_amdgcn_mfma_f32_16x16x32_bf16(wf[ot], a[pt], acc[pt][ot], 0, 0, 0)
                    : __builtin_amdgcn_mfma_f32_16x16x32_bf16(a[pt], wf[ot], acc[pt][ot], 0, 0, 0);
        if (k0 + 32 < K) {
            #pragma unroll
            for (int ot = 0; ot < 3; ot++) wf[ot] = wn[ot];
        }
    }

    const int b = gp0 >> 16;
    const int pxb = gp0 & 65535;

    if (MODE == 0 || MODE == 2) {
        // reg axis = pixel (FIRST = X): stores along px
        #pragma unroll
        for (int ot = 0; ot < 3; ot++) {
            const int oc = ocb + ot * 16 + lr;
            const float bi = bias[oc];
            const size_t rowoff = ((size_t)b * OCTOT + oc) * NPIX + pxb + lg * 4;
            #pragma unroll
            for (int pt = 0; pt < 4; pt++) {
                if (MODE == 0) {
                    us4 o;
                    #pragma unroll
                    for (int r = 0; r < 4; r++) o[r] = f2b(acc[pt][ot][r] + bi);
                    *(us4*)((unsigned short*)Out + rowoff + pt * 16) = o;
                } else {
                    f4 rv = *(const f4*)(resid + rowoff + pt * 16);
                    f4 o;
                    #pragma unroll
                    for (int r = 0; r < 4; r++) o[r] = acc[pt][ot][r] + bi + rv[r];
                    *(f4*)((float*)Out + rowoff + pt * 16) = o;
                }
            }
        }
    } else {
        // MODE 1: reg axis = out-channel (FIRST = W): stores along ch into [gp][OCTOT]
        #pragma unroll
        for (int pt = 0; pt < 4; pt++) {
            const int gp = gp0 + pt * 16 + lr;
            unsigned short* orow = (unsigned short*)Out + (size_t)gp * OCTOT + ocb + lg * 4;
            #pragma unroll
            for (int ot = 0; ot < 3; ot++) {
                f4 bi4 = *(const f4*)&bias[ocb + ot * 16 + lg * 4];
                us4 o;
                #pragma unroll
                for (int r = 0; r < 4; r++) o[r] = f2b(geluf(acc[pt][ot][r] + bi4[r]));
                *(us4*)(orow + ot * 16) = o;
            }
        }
    }
}

// ---------------------------------------------------------------------------
// Per-row (b, k-channel) max + log-sum-exp over all pixels.
// ---------------------------------------------------------------------------
__global__ __launch_bounds__(256) void krow_k(const unsigned short* __restrict__ qkv,
                                              float* __restrict__ koff)
{
    int r = blockIdx.x;
    int b = r / 192, ch = 192 + (r % 192);
    const unsigned short* Kp = qkv + ((size_t)b * 576 + ch) * NPIX;
    int tid = threadIdx.x;
    float m = -1e30f, s = 0.f;
    for (int i = 0; i < 256; i++) {
        float v = b2f(Kp[tid + (size_t)i * 256]);
        if (v > m) { s = s * __expf(m - v) + 1.f; m = v; }
        else s += __expf(v - m);
    }
    __shared__ float ms[256], ss[256];
    ms[tid] = m; ss[tid] = s;
    __syncthreads();
    for (int off = 128; off > 0; off >>= 1) {
        if (tid < off) {
            float m2 = ms[tid + off], s2 = ss[tid + off];
            float M2 = fmaxf(ms[tid], m2);
            ss[tid] = ss[tid] * __expf(ms[tid] - M2) + s2 * __expf(m2 - M2);
            ms[tid] = M2;
        }
        __syncthreads();
    }
    if (tid == 0) koff[r] = ms[0] + logf(ss[0]);
}

__global__ void zero_k(float* __restrict__ p, int n)
{
    int i = blockIdx.x * 256 + threadIdx.x;
    if (i < n) p[i] = 0.f;
}

__global__ void cvt_k(const float* __restrict__ src, unsigned short* __restrict__ dst, int n)
{
    int i = blockIdx.x * 256 + threadIdx.x;
    if (i < n) dst[i] = f2b(src[i]);
}

// ---------------------------------------------------------------------------
// context: ctxT[b,h,d,c] = sum_n exp(k[c,n]-koff[c]) * v[d,n]
// ---------------------------------------------------------------------------
__global__ __launch_bounds__(64) void context_k(const unsigned short* __restrict__ qkv,
                                                const float* __restrict__ koff,
                                                float* __restrict__ ctxT)
{
    int bid = blockIdx.x;
    int bh = bid >> 6, chunk = bid & 63;
    int b = bh >> 3, h = bh & 7;
    int lane = threadIdx.x, lr = lane & 15, lg = lane >> 4;
    size_t nbase = (size_t)chunk * 1024 + lg * 8;

    int c0 = h * 24 + lr;
    int c1 = h * 24 + 16 + lr;
    float ko0 = koff[b * 192 + c0];
    int i1 = b * 192 + c1; if (i1 > 775) i1 = 775;
    float ko1 = koff[i1];
    bool val1 = lr < 8;

    const unsigned short* k0p = qkv + ((size_t)b * 576 + 192 + c0) * NPIX + nbase;
    const unsigned short* k1p = qkv + ((size_t)b * 576 + 192 + c1) * NPIX + nbase;
    const unsigned short* v0p = qkv + ((size_t)b * 576 + 384 + h * 24 + lr) * NPIX + nbase;
    const unsigned short* v1p = qkv + ((size_t)b * 576 + 384 + h * 24 + 16 + lr) * NPIX + nbase;

    f4 acc[2][2];
    #pragma unroll
    for (int i = 0; i < 2; i++) for (int j = 0; j < 2; j++) acc[i][j] = (f4)0.0f;

    for (int s = 0; s < 32; s++) {
        int off = s * 32;
        s8 kr0 = *(const s8*)(k0p + off);
        s8 kr1 = *(const s8*)(k1p + off);
        s8 vr0 = *(const s8*)(v0p + off);
        s8 vr1 = *(const s8*)(v1p + off);
        s8 p0, p1;
        #pragma unroll
        for (int j = 0; j < 8; j++) {
            p0[j] = (short)f2b(__expf(b2f((unsigned short)kr0[j]) - ko0));
            p1[j] = val1 ? (short)f2b(__expf(b2f((unsigned short)kr1[j]) - ko1)) : (short)0;
        }
        acc[0][0] = __builtin_amdgcn_mfma_f32_16x16x32_bf16(p0, vr0, acc[0][0], 0, 0, 0);
        acc[0][1] = __builtin_amdgcn_mfma_f32_16x16x32_bf16(p0, vr1, acc[0][1], 0, 0, 0);
        acc[1][0] = __builtin_amdgcn_mfma_f32_16x16x32_bf16(p1, vr0, acc[1][0], 0, 0, 0);
        acc[1][1] = __builtin_amdgcn_mfma_f32_16x16x32_bf16(p1, vr1, acc[1][1], 0, 0, 0);
    }
    float* base = ctxT + (size_t)(b * 8 + h) * 1024;
    #pragma unroll
    for (int mt = 0; mt < 2; mt++)
        #pragma unroll
        for (int ct = 0; ct < 2; ct++)
            #pragma unroll
            for (int r = 0; r < 4; r++) {
                int c = mt * 16 + lg * 4 + r;
                int d = ct * 16 + lr;
                atomicAdd(base + d * 32 + c, acc[mt][ct][r]);
            }
}

// ---------------------------------------------------------------------------
// fused: q-softmax -> ctx apply (MFMA) -> out-proj GEMM -> + x residual
// ---------------------------------------------------------------------------
__global__ __launch_bounds__(256) void qctx_proj_k(
    const unsigned short* __restrict__ qkv, const float* __restrict__ ctxT,
    const unsigned short* __restrict__ outWb, const float* __restrict__ outBias,
    const float* __restrict__ xres, float* __restrict__ Out)
{
    __shared__ unsigned short E[64][264];
    __shared__ float sden[8][64];
    __shared__ unsigned short outp[64][200];

    int tid = threadIdx.x, bid = blockIdx.x;
    int b = bid >> 10, n0 = (bid & 1023) * 64;
    int p = tid & 63, g = tid >> 6;

    #pragma unroll
    for (int hh = 0; hh < 2; hh++) {
        int h = g * 2 + hh;
        float s = 0.f;
        const unsigned short* Q = qkv + ((size_t)b * 576 + h * 24) * NPIX + n0 + p;
        #pragma unroll 4
        for (int cc = 0; cc < 24; cc++) {
            float e = __expf(b2f(Q[(size_t)cc * NPIX]));
            s += e;
            E[p][h * 32 + cc] = f2b(e);
        }
        #pragma unroll
        for (int cc = 24; cc < 32; cc++) E[p][h * 32 + cc] = 0;
        sden[h][p] = s;
    }
    __syncthreads();

    int wave = tid >> 6, lane = tid & 63, lr = lane & 15, lg = lane >> 4;

    #pragma unroll
    for (int hh = 0; hh < 2; hh++) {
        int h = wave * 2 + hh;
        s8 af[2];
        #pragma unroll
        for (int mt = 0; mt < 2; mt++) {
            const float* cp = ctxT + ((size_t)(b * 8 + h) * 32 + mt * 16 + lr) * 32 + lg * 8;
            s8 a;
            #pragma unroll
            for (int j = 0; j < 8; j++) a[j] = (short)f2b(cp[j]);
            af[mt] = a;
        }
        #pragma unroll
        for (int nt = 0; nt < 4; nt++) {
            s8 bf = *(const s8*)&E[nt * 16 + lr][h * 32 + lg * 8];
            f4 z = (f4)0.0f;
            f4 d0 = __builtin_amdgcn_mfma_f32_16x16x32_bf16(af[0], bf, z, 0, 0, 0);
            f4 d1 = __builtin_amdgcn_mfma_f32_16x16x32_bf16(af[1], bf, z, 0, 0, 0);
            int n = nt * 16 + lr;
            float sinv = 1.0f / sden[h][n];
            us4 w0;
            #pragma unroll
            for (int r = 0; r < 4; r++) w0[r] = f2b(d0[r] * sinv);
            *(us4*)&outp[n][h * 24 + lg * 4] = w0;
            if (lg < 2) {
                us4 w1;
                #pragma unroll
                for (int r = 0; r < 4; r++) w1[r] = f2b(d1[r] * sinv);
                *(us4*)&outp[n][h * 24 + 16 + lg * 4] = w1;
            }
        }
    }
    __syncthreads();

    f4 acc[3][4];
    #pragma unroll
    for (int i = 0; i < 3; i++) for (int j = 0; j < 4; j++) acc[i][j] = (f4)0.0f;
    #pragma unroll
    for (int k0 = 0; k0 < 192; k0 += 32) {
        s8 bf[4];
        #pragma unroll
        for (int nt = 0; nt < 4; nt++)
            bf[nt] = *(const s8*)&outp[nt * 16 + lr][k0 + lg * 8];
        #pragma unroll
        for (int mt = 0; mt < 3; mt++) {
            s8 af = *(const s8*)&outWb[(size_t)(wave * 48 + mt * 16 + lr) * 192 + k0 + lg * 8];
            #pragma unroll
            for (int nt = 0; nt < 4; nt++)
                acc[mt][nt] = __builtin_amdgcn_mfma_f32_16x16x32_bf16(af, bf[nt], acc[mt][nt], 0, 0, 0);
        }
    }
    #pragma unroll
    for (int mt = 0; mt < 3; mt++)
        #pragma unroll
        for (int nt = 0; nt < 4; nt++) {
            int col = n0 + nt * 16 + lr;
            #pragma unroll
            for (int r = 0; r < 4; r++) {
                int row = wave * 48 + mt * 16 + lg * 4 + r;
                size_t off = ((size_t)b * 192 + row) * NPIX + col;
                Out[off] = acc[mt][nt][r] + outBias[row] + xres[off];
            }
        }
}

// ---------------------------------------------------------------------------
// depthwise 3x3 + gelu on TRANSPOSED layout: h1t[px][384] -> h2t[px][384].
// ---------------------------------------------------------------------------
__global__ __launch_bounds__(256) void dwconv_t_k(
    const unsigned short* __restrict__ h1t, const float* __restrict__ w,
    const float* __restrict__ bias, unsigned short* __restrict__ h2t)
{
    __shared__ unsigned short tile[4][10][528];   // [cg][yy][xx*8]
    const int bz = blockIdx.z;                    // b*12 + chgrp
    const int b = bz / 12, cb = (bz % 12) * 32;
    const int y0 = blockIdx.y * 8, x0 = blockIdx.x * 64;
    const int tid = threadIdx.x;

    for (int it = 0; it < 11; ++it) {
        int idx = it * 256 + tid;
        if (idx < 2640) {
            int cg = idx & 3, rem = idx >> 2;
            int xx = rem % 66, yy = rem / 66;
            int gy = y0 + yy - 1, gx = x0 + xx - 1;
            us8 v;
            if (gy >= 0 && gy < 256 && gx >= 0 && gx < 256)
                v = *(const us8*)(h1t + ((size_t)b * NPIX + gy * 256 + gx) * 384 + cb + cg * 8);
            else { us8 z = {0,0,0,0,0,0,0,0}; v = z; }
            *(us8*)&tile[cg][yy][xx * 8] = v;
        }
    }

    const int x = tid & 63, cg = tid >> 6;
    const int c0 = cb + cg * 8;
    float wr[9][8];
    #pragma unroll
    for (int j = 0; j < 9; j++)
        #pragma unroll
        for (int i = 0; i < 8; i++) wr[j][i] = w[(c0 + i) * 9 + j];
    float bi[8];
    #pragma unroll
    for (int i = 0; i < 8; i++) bi[i] = bias[c0 + i];
    __syncthreads();

    us8 w0[3], w1[3], w2[3];
    #pragma unroll
    for (int dx = 0; dx < 3; dx++) {
        w0[dx] = *(const us8*)&tile[cg][0][(x + dx) * 8];
        w1[dx] = *(const us8*)&tile[cg][1][(x + dx) * 8];
    }

    #pragma unroll
    for (int y = 0; y < 8; y++) {
        #pragma unroll
        for (int dx = 0; dx < 3; dx++)
            w2[dx] = *(const us8*)&tile[cg][y + 2][(x + dx) * 8];

        float a[8];
        #pragma unroll
        for (int i = 0; i < 8; i++) a[i] = bi[i];
        #pragma unroll
        for (int dx = 0; dx < 3; dx++) {
            #pragma unroll
            for (int i = 0; i < 8; i++) {
                a[i] += wr[0 * 3 + dx][i] * b2f(w0[dx][i]);
                a[i] += wr[1 * 3 + dx][i] * b2f(w1[dx][i]);
                a[i] += wr[2 * 3 + dx][i] * b2f(w2[dx][i]);
            }
        }
        us8 ov;
        #pragma unroll
        for (int i = 0; i < 8; i++) ov[i] = f2b(geluf(a[i]));
        *(us8*)(h2t + ((size_t)b * NPIX + (y0 + y) * 256 + x0 + x) * 384 + c0) = ov;

        #pragma unroll
        for (int dx = 0; dx < 3; dx++) { w0[dx] = w1[dx]; w1[dx] = w2[dx]; }
    }
}

// ---------------------------------------------------------------------------
extern "C" void kernel_launch(void* const* d_in, const int* in_sizes, int n_in,
                              void* d_out, int out_size, void* d_ws, size_t ws_size,
                              hipStream_t stream)
{
    const float* x    = (const float*)d_in[0];
    const float* ln1g = (const float*)d_in[1];
    const float* ln1b = (const float*)d_in[2];
    const float* qkvw = (const float*)d_in[3];
    const float* qkvb = (const float*)d_in[4];
    const float* outw = (const float*)d_in[5];
    const float* outb = (const float*)d_in[6];
    const float* ln2g = (const float*)d_in[7];
    const float* ln2b = (const float*)d_in[8];
    const float* w1   = (const float*)d_in[9];
    const float* b1   = (const float*)d_in[10];
    const float* dww  = (const float*)d_in[11];
    const float* dwb  = (const float*)d_in[12];
    const float* w2   = (const float*)d_in[13];
    const float* b2   = (const float*)d_in[14];
    float* out = (float*)d_out;

    char* ws = (char*)d_ws;
    unsigned short* qkv = (unsigned short*)ws;                            // [0, 302MB)  [ch][px]
    unsigned short* h1t = (unsigned short*)ws;                            // [0, 201MB)  [px][384]
    unsigned short* h2t = (unsigned short*)(ws + (size_t)201326592);      // [201MB, 403MB) [px][384]
    unsigned short* xnt = (unsigned short*)(ws + (size_t)301989888);      // [302MB, 403MB) [px][192]
    size_t off = (size_t)402653184;
    float* koff = (float*)(ws + off); off += 4096;
    float* ctxT = (float*)(ws + off); off += 131072;
    unsigned short* qkvwb = (unsigned short*)(ws + off); off += 221184;
    unsigned short* outwb = (unsigned short*)(ws + off); off += 73728 * 2;
    unsigned short* w1b   = (unsigned short*)(ws + off); off += 147456;
    unsigned short* w2b   = (unsigned short*)(ws + off); off += 147456;

    cvt_k<<<(110592 + 255) / 256, 256, 0, stream>>>(qkvw, qkvwb, 110592);
    cvt_k<<<(36864 + 255) / 256, 256, 0, stream>>>(outw, outwb, 36864);
    cvt_k<<<(73728 + 255) / 256, 256, 0, stream>>>(w1, w1b, 73728);
    cvt_k<<<(73728 + 255) / 256, 256, 0, stream>>>(w2, w2b, 73728);

    // 1) LN1 + transpose -> xnt
    lnt_k<<<1024, 256, 0, stream>>>(x, ln1g, ln1b, xnt);

    // 2) qkv GEMM (staged) -> qkv [ch][px]; 3 oc-chunks of 192
    gemm2_k<192, 0><<<dim3(4096, 3), 256, 0, stream>>>(xnt, qkvwb, qkvb, nullptr, qkv, 576);

    // 3) k-row softmax offsets
    krow_k<<<768, 256, 0, stream>>>(qkv, koff);

    // 4) context accumulation
    zero_k<<<128, 256, 0, stream>>>(ctxT, 32768);
    context_k<<<2048, 64, 0, stream>>>(qkv, koff, ctxT);

    // 5) q softmax + ctx apply + out-proj + residual -> x2 (d_out, f32)
    qctx_proj_k<<<4096, 256, 0, stream>>>(qkv, ctxT, outwb, outb, x, out);

    // 6) LN2 + transpose -> xnt
    lnt_k<<<1024, 256, 0, stream>>>(out, ln2g, ln2b, xnt);

    // 7) w1 GEMM + gelu -> h1t [px][384] (staged); 2 oc-chunks
    gemm2_k<192, 1><<<dim3(4096, 2), 256, 0, stream>>>(xnt, w1b, b1, nullptr, h1t, 384);

    // 8) depthwise 3x3 + gelu on transposed layout -> h2t [px][384]
    dwconv_t_k<<<dim3(4, 32, 48), 256, 0, stream>>>(h1t, dww, dwb, h2t);

    // 9) w2 GEMM + bias + x2 residual -> d_out f32 (staged)
    gemm2_k<384, 2><<<dim3(4096, 1), 256, 0, stream>>>(h2t, w2b, b2, out, out, 192);
}

// Round 6
// 1219.502 us; speedup vs baseline: 1.1660x; 1.0190x over previous
//
#include <hip/hip_runtime.h>
#include <math.h>

typedef __attribute__((ext_vector_type(8))) short s8;
typedef __attribute__((ext_vector_type(8))) unsigned short us8;
typedef __attribute__((ext_vector_type(4))) float f4;
typedef __attribute__((ext_vector_type(4))) unsigned short us4;
typedef __attribute__((ext_vector_type(4))) unsigned int u32x4;

#define DEVI __device__ __forceinline__

static const int NPIX = 65536;   // 256*256

DEVI float b2f(unsigned short u) {
    unsigned int v = ((unsigned int)u) << 16;
    float f; __builtin_memcpy(&f, &v, 4); return f;
}
DEVI unsigned short f2b(float f) {
    unsigned int u; __builtin_memcpy(&u, &f, 4);
    unsigned int r = (u + 0x7FFFu + ((u >> 16) & 1u)) >> 16;
    return (unsigned short)r;
}
DEVI float geluf(float x) { return 0.5f * x * (1.0f + erff(x * 0.70710678118f)); }
// tanh-form gelu (max abs err ~1e-3): x * sigmoid(1.5957691*(x + 0.044715 x^3))
DEVI float gelu_t(float x) {
    float z = 1.595769122f * (x + 0.044715f * x * x * x);
    return x * __builtin_amdgcn_rcpf(1.0f + __expf(-z));
}
DEVI float rfl(float v) {
    int i; __builtin_memcpy(&i, &v, 4);
    i = __builtin_amdgcn_readfirstlane(i);
    float o; __builtin_memcpy(&o, &i, 4); return o;
}

DEVI void gload_lds16(const unsigned short* g, unsigned short* l) {
    __builtin_amdgcn_global_load_lds(
        (const __attribute__((address_space(1))) unsigned int*)g,
        (__attribute__((address_space(3))) unsigned int*)l,
        16, 0, 0);
}

// ---------------------------------------------------------------------------
// LayerNorm + transpose: x f32 [b][192][px] -> xnt bf16 [b*px][192]
// ---------------------------------------------------------------------------
__global__ __launch_bounds__(256) void lnt_k(const float* __restrict__ X,
                                             const float* __restrict__ gw,
                                             const float* __restrict__ gb,
                                             unsigned short* __restrict__ Out)
{
    const int i = blockIdx.x * 256 + threadIdx.x;    // 0..262143
    const int b = i >> 16, px = i & 65535;
    const float* xp = X + (size_t)b * 192 * NPIX + px;

    unsigned int pk[96];
    float sum = 0.f, ssq = 0.f;
    #pragma unroll
    for (int c = 0; c < 192; c++) {
        float v = xp[(size_t)c * NPIX];
        sum += v; ssq += v * v;
        unsigned int h = f2b(v);
        if (c & 1) pk[c >> 1] |= h << 16;
        else       pk[c >> 1] = h;
    }
    float mu = sum * (1.0f / 192.0f);
    float var = ssq * (1.0f / 192.0f) - mu * mu;
    float rs = rsqrtf(var + 1e-5f);

    #pragma unroll
    for (int c2 = 0; c2 < 96; c2++) {
        int c = c2 * 2;
        float lo = b2f((unsigned short)(pk[c2] & 0xFFFF));
        float hi = b2f((unsigned short)(pk[c2] >> 16));
        lo = (lo - mu) * rs * gw[c] + gb[c];
        hi = (hi - mu) * rs * gw[c + 1] + gb[c + 1];
        pk[c2] = (unsigned int)f2b(lo) | ((unsigned int)f2b(hi) << 16);
    }
    u32x4* dst = (u32x4*)(Out + (size_t)i * 192);
    #pragma unroll
    for (int j = 0; j < 6; j++) {
        u32x4 v = { pk[4 * j], pk[4 * j + 1], pk[4 * j + 2], pk[4 * j + 3] };
        dst[j] = v;
    }
}

// ---------------------------------------------------------------------------
// Staged GEMM over channels (m97-style): block = 64 px x 192 oc-chunk.
// ---------------------------------------------------------------------------
template<int K, int MODE>
__global__ __launch_bounds__(256) void gemm2_k(
    const unsigned short* __restrict__ X, const unsigned short* __restrict__ Wb,
    const float* __restrict__ bias, const float* __restrict__ resid,
    void* __restrict__ Out, int OCTOT)
{
    constexpr int ROWS = 64;
    constexpr int CPR = K / 8;            // 16B chunks per row
    __shared__ unsigned short tile[ROWS * K];

    const int tid = threadIdx.x;
    const int wave = tid >> 6, lane = tid & 63;
    const int lr = lane & 15, lg = lane >> 4;
    const int gp0 = blockIdx.x * ROWS;    // global pixel (incl. batch)
    const int ocb = blockIdx.y * 192 + wave * 48;

    constexpr int CALLS = (ROWS * CPR) / 256;
    {
        const unsigned short* Xb = X + (size_t)gp0 * K;
        #pragma unroll
        for (int j = 0; j < CALLS; j++) {
            int ci = (wave * CALLS + j) * 64 + lane;
            int row = (int)((unsigned)ci / (unsigned)CPR);
            int c = ci - row * CPR;
            int csw = (c & ~7) | ((c ^ row) & 7);
            gload_lds16(Xb + (size_t)row * K + csw * 8, &tile[ci * 8]);
        }
    }

    const unsigned short* wrow = Wb + (size_t)(ocb + lr) * K + lg * 8;
    s8 wf[3];
    #pragma unroll
    for (int ot = 0; ot < 3; ot++) wf[ot] = *(const s8*)(wrow + (size_t)ot * 16 * K);

    __syncthreads();

    const int xr = lr & 7;
    f4 acc[4][3];
    #pragma unroll
    for (int i = 0; i < 4; i++)
        #pragma unroll
        for (int j = 0; j < 3; j++) acc[i][j] = (f4)0.0f;

    #pragma unroll
    for (int k0 = 0; k0 < K; k0 += 32) {
        s8 wn[3];
        if (k0 + 32 < K) {
            #pragma unroll
            for (int ot = 0; ot < 3; ot++)
                wn[ot] = *(const s8*)(wrow + (size_t)ot * 16 * K + k0 + 32);
        }
        const int kc = (k0 >> 3) + lg;
        const int kcs = (kc & ~7) | ((kc ^ xr) & 7);
        s8 a[4];
        #pragma unroll
        for (int pt = 0; pt < 4; pt++) {
            int row = pt * 16 + lr;
            a[pt] = *(const s8*)&tile[(row * CPR + kcs) * 8];
        }
        #pragma unroll
        for (int ot = 0; ot < 3; ot++)
            #pragma unroll
            for (int pt = 0; pt < 4; pt++)
                acc[pt][ot] = (MODE == 1)
                    ? __builtin_amdgcn_mfma_f32_16x16x32_bf16(wf[ot], a[pt], acc[pt][ot], 0, 0, 0)
                    : __builtin_amdgcn_mfma_f32_16x16x32_bf16(a[pt], wf[ot], acc[pt][ot], 0, 0, 0);
        if (k0 + 32 < K) {
            #pragma unroll
            for (int ot = 0; ot < 3; ot++) wf[ot] = wn[ot];
        }
    }

    const int b = gp0 >> 16;
    const int pxb = gp0 & 65535;

    if (MODE == 0 || MODE == 2) {
        #pragma unroll
        for (int ot = 0; ot < 3; ot++) {
            const int oc = ocb + ot * 16 + lr;
            const float bi = bias[oc];
            const size_t rowoff = ((size_t)b * OCTOT + oc) * NPIX + pxb + lg * 4;
            #pragma unroll
            for (int pt = 0; pt < 4; pt++) {
                if (MODE == 0) {
                    us4 o;
                    #pragma unroll
                    for (int r = 0; r < 4; r++) o[r] = f2b(acc[pt][ot][r] + bi);
                    *(us4*)((unsigned short*)Out + rowoff + pt * 16) = o;
                } else {
                    f4 rv = *(const f4*)(resid + rowoff + pt * 16);
                    f4 o;
                    #pragma unroll
                    for (int r = 0; r < 4; r++) o[r] = acc[pt][ot][r] + bi + rv[r];
                    *(f4*)((float*)Out + rowoff + pt * 16) = o;
                }
            }
        }
    } else {
        #pragma unroll
        for (int pt = 0; pt < 4; pt++) {
            const int gp = gp0 + pt * 16 + lr;
            unsigned short* orow = (unsigned short*)Out + (size_t)gp * OCTOT + ocb + lg * 4;
            #pragma unroll
            for (int ot = 0; ot < 3; ot++) {
                f4 bi4 = *(const f4*)&bias[ocb + ot * 16 + lg * 4];
                us4 o;
                #pragma unroll
                for (int r = 0; r < 4; r++) o[r] = f2b(geluf(acc[pt][ot][r] + bi4[r]));
                *(us4*)(orow + ot * 16) = o;
            }
        }
    }
}

// ---------------------------------------------------------------------------
// Per-row (b, k-channel) max + log-sum-exp over all pixels.
// ---------------------------------------------------------------------------
__global__ __launch_bounds__(256) void krow_k(const unsigned short* __restrict__ qkv,
                                              float* __restrict__ koff)
{
    int r = blockIdx.x;
    int b = r / 192, ch = 192 + (r % 192);
    const unsigned short* Kp = qkv + ((size_t)b * 576 + ch) * NPIX;
    int tid = threadIdx.x;
    float m = -1e30f, s = 0.f;
    for (int i = 0; i < 256; i++) {
        float v = b2f(Kp[tid + (size_t)i * 256]);
        if (v > m) { s = s * __expf(m - v) + 1.f; m = v; }
        else s += __expf(v - m);
    }
    __shared__ float ms[256], ss[256];
    ms[tid] = m; ss[tid] = s;
    __syncthreads();
    for (int off = 128; off > 0; off >>= 1) {
        if (tid < off) {
            float m2 = ms[tid + off], s2 = ss[tid + off];
            float M2 = fmaxf(ms[tid], m2);
            ss[tid] = ss[tid] * __expf(ms[tid] - M2) + s2 * __expf(m2 - M2);
            ms[tid] = M2;
        }
        __syncthreads();
    }
    if (tid == 0) koff[r] = ms[0] + logf(ss[0]);
}

__global__ void zero_k(float* __restrict__ p, int n)
{
    int i = blockIdx.x * 256 + threadIdx.x;
    if (i < n) p[i] = 0.f;
}

__global__ void cvt_k(const float* __restrict__ src, unsigned short* __restrict__ dst, int n)
{
    int i = blockIdx.x * 256 + threadIdx.x;
    if (i < n) dst[i] = f2b(src[i]);
}

// ---------------------------------------------------------------------------
// context: ctxT[b,h,d,c] = sum_n exp(k[c,n]-koff[c]) * v[d,n]
// ---------------------------------------------------------------------------
__global__ __launch_bounds__(64) void context_k(const unsigned short* __restrict__ qkv,
                                                const float* __restrict__ koff,
                                                float* __restrict__ ctxT)
{
    int bid = blockIdx.x;
    int bh = bid >> 6, chunk = bid & 63;
    int b = bh >> 3, h = bh & 7;
    int lane = threadIdx.x, lr = lane & 15, lg = lane >> 4;
    size_t nbase = (size_t)chunk * 1024 + lg * 8;

    int c0 = h * 24 + lr;
    int c1 = h * 24 + 16 + lr;
    float ko0 = koff[b * 192 + c0];
    int i1 = b * 192 + c1; if (i1 > 775) i1 = 775;
    float ko1 = koff[i1];
    bool val1 = lr < 8;

    const unsigned short* k0p = qkv + ((size_t)b * 576 + 192 + c0) * NPIX + nbase;
    const unsigned short* k1p = qkv + ((size_t)b * 576 + 192 + c1) * NPIX + nbase;
    const unsigned short* v0p = qkv + ((size_t)b * 576 + 384 + h * 24 + lr) * NPIX + nbase;
    const unsigned short* v1p = qkv + ((size_t)b * 576 + 384 + h * 24 + 16 + lr) * NPIX + nbase;

    f4 acc[2][2];
    #pragma unroll
    for (int i = 0; i < 2; i++) for (int j = 0; j < 2; j++) acc[i][j] = (f4)0.0f;

    for (int s = 0; s < 32; s++) {
        int off = s * 32;
        s8 kr0 = *(const s8*)(k0p + off);
        s8 kr1 = *(const s8*)(k1p + off);
        s8 vr0 = *(const s8*)(v0p + off);
        s8 vr1 = *(const s8*)(v1p + off);
        s8 p0, p1;
        #pragma unroll
        for (int j = 0; j < 8; j++) {
            p0[j] = (short)f2b(__expf(b2f((unsigned short)kr0[j]) - ko0));
            p1[j] = val1 ? (short)f2b(__expf(b2f((unsigned short)kr1[j]) - ko1)) : (short)0;
        }
        acc[0][0] = __builtin_amdgcn_mfma_f32_16x16x32_bf16(p0, vr0, acc[0][0], 0, 0, 0);
        acc[0][1] = __builtin_amdgcn_mfma_f32_16x16x32_bf16(p0, vr1, acc[0][1], 0, 0, 0);
        acc[1][0] = __builtin_amdgcn_mfma_f32_16x16x32_bf16(p1, vr0, acc[1][0], 0, 0, 0);
        acc[1][1] = __builtin_amdgcn_mfma_f32_16x16x32_bf16(p1, vr1, acc[1][1], 0, 0, 0);
    }
    float* base = ctxT + (size_t)(b * 8 + h) * 1024;
    #pragma unroll
    for (int mt = 0; mt < 2; mt++)
        #pragma unroll
        for (int ct = 0; ct < 2; ct++)
            #pragma unroll
            for (int r = 0; r < 4; r++) {
                int c = mt * 16 + lg * 4 + r;
                int d = ct * 16 + lr;
                atomicAdd(base + d * 32 + c, acc[mt][ct][r]);
            }
}

// ---------------------------------------------------------------------------
// fused: q-softmax -> ctx apply (MFMA) -> out-proj GEMM -> + x residual
// ---------------------------------------------------------------------------
__global__ __launch_bounds__(256) void qctx_proj_k(
    const unsigned short* __restrict__ qkv, const float* __restrict__ ctxT,
    const unsigned short* __restrict__ outWb, const float* __restrict__ outBias,
    const float* __restrict__ xres, float* __restrict__ Out)
{
    __shared__ unsigned short E[64][264];
    __shared__ float sden[8][64];
    __shared__ unsigned short outp[64][200];

    int tid = threadIdx.x, bid = blockIdx.x;
    int b = bid >> 10, n0 = (bid & 1023) * 64;
    int p = tid & 63, g = tid >> 6;

    #pragma unroll
    for (int hh = 0; hh < 2; hh++) {
        int h = g * 2 + hh;
        float s = 0.f;
        const unsigned short* Q = qkv + ((size_t)b * 576 + h * 24) * NPIX + n0 + p;
        #pragma unroll 4
        for (int cc = 0; cc < 24; cc++) {
            float e = __expf(b2f(Q[(size_t)cc * NPIX]));
            s += e;
            E[p][h * 32 + cc] = f2b(e);
        }
        #pragma unroll
        for (int cc = 24; cc < 32; cc++) E[p][h * 32 + cc] = 0;
        sden[h][p] = s;
    }
    __syncthreads();

    int wave = tid >> 6, lane = tid & 63, lr = lane & 15, lg = lane >> 4;

    #pragma unroll
    for (int hh = 0; hh < 2; hh++) {
        int h = wave * 2 + hh;
        s8 af[2];
        #pragma unroll
        for (int mt = 0; mt < 2; mt++) {
            const float* cp = ctxT + ((size_t)(b * 8 + h) * 32 + mt * 16 + lr) * 32 + lg * 8;
            s8 a;
            #pragma unroll
            for (int j = 0; j < 8; j++) a[j] = (short)f2b(cp[j]);
            af[mt] = a;
        }
        #pragma unroll
        for (int nt = 0; nt < 4; nt++) {
            s8 bf = *(const s8*)&E[nt * 16 + lr][h * 32 + lg * 8];
            f4 z = (f4)0.0f;
            f4 d0 = __builtin_amdgcn_mfma_f32_16x16x32_bf16(af[0], bf, z, 0, 0, 0);
            f4 d1 = __builtin_amdgcn_mfma_f32_16x16x32_bf16(af[1], bf, z, 0, 0, 0);
            int n = nt * 16 + lr;
            float sinv = 1.0f / sden[h][n];
            us4 w0;
            #pragma unroll
            for (int r = 0; r < 4; r++) w0[r] = f2b(d0[r] * sinv);
            *(us4*)&outp[n][h * 24 + lg * 4] = w0;
            if (lg < 2) {
                us4 w1;
                #pragma unroll
                for (int r = 0; r < 4; r++) w1[r] = f2b(d1[r] * sinv);
                *(us4*)&outp[n][h * 24 + 16 + lg * 4] = w1;
            }
        }
    }
    __syncthreads();

    f4 acc[3][4];
    #pragma unroll
    for (int i = 0; i < 3; i++) for (int j = 0; j < 4; j++) acc[i][j] = (f4)0.0f;
    #pragma unroll
    for (int k0 = 0; k0 < 192; k0 += 32) {
        s8 bf[4];
        #pragma unroll
        for (int nt = 0; nt < 4; nt++)
            bf[nt] = *(const s8*)&outp[nt * 16 + lr][k0 + lg * 8];
        #pragma unroll
        for (int mt = 0; mt < 3; mt++) {
            s8 af = *(const s8*)&outWb[(size_t)(wave * 48 + mt * 16 + lr) * 192 + k0 + lg * 8];
            #pragma unroll
            for (int nt = 0; nt < 4; nt++)
                acc[mt][nt] = __builtin_amdgcn_mfma_f32_16x16x32_bf16(af, bf[nt], acc[mt][nt], 0, 0, 0);
        }
    }
    #pragma unroll
    for (int mt = 0; mt < 3; mt++)
        #pragma unroll
        for (int nt = 0; nt < 4; nt++) {
            int col = n0 + nt * 16 + lr;
            #pragma unroll
            for (int r = 0; r < 4; r++) {
                int row = wave * 48 + mt * 16 + lg * 4 + r;
                size_t off = ((size_t)b * 192 + row) * NPIX + col;
                Out[off] = acc[mt][nt][r] + outBias[row] + xres[off];
            }
        }
}

// ---------------------------------------------------------------------------
// depthwise 3x3 + gelu on [px][384], row-streamed LDS ring (16.9KB),
// global_load_lds staging, SGPR weights, tanh-gelu.
// Block: 32ch x 64x x 8y. Threads: 256 = 4 waves; wave = cg (8ch), lane = x.
// Ring: [4 slots][4 cg][66 xx] us8 chunks.
// ---------------------------------------------------------------------------
__global__ __launch_bounds__(256) void dwconv_t2_k(
    const unsigned short* __restrict__ h1t, const float* __restrict__ w,
    const float* __restrict__ bias, unsigned short* __restrict__ h2t)
{
    __shared__ unsigned short ring[4 * 4 * 66 * 8];   // 16.9 KB
    const int bz = blockIdx.z;                        // b*12 + cbgrp
    const int b = bz / 12, cb = (bz % 12) * 32;
    const int y0 = blockIdx.y * 8, x0 = blockIdx.x * 64;
    const int tid = threadIdx.x;
    const int x = tid & 63, cg = tid >> 6;
    const int c0 = cb + cg * 8;
    const size_t bbase = (size_t)b << 16;

    // wave-uniform weights & bias -> SGPRs
    float wr[9][8], bi[8];
    #pragma unroll
    for (int i = 0; i < 8; i++) {
        #pragma unroll
        for (int j = 0; j < 9; j++) wr[j][i] = rfl(w[(c0 + i) * 9 + j]);
        bi[i] = rfl(bias[c0 + i]);
    }

    const us8 zz = {0, 0, 0, 0, 0, 0, 0, 0};

    auto stage_row = [&](int gy, int s) {
        unsigned short* ldsrow = &ring[((s * 4 + cg) * 66) * 8];
        if (gy >= 0 && gy <= 255) {
            us8 ev = zz;
            if (x == 0 && x0 > 0)
                ev = *(const us8*)(h1t + (bbase + gy * 256 + x0 - 1) * 384 + c0);
            if (x == 63 && x0 + 64 < 256)
                ev = *(const us8*)(h1t + (bbase + gy * 256 + x0 + 64) * 384 + c0);
            gload_lds16(h1t + (bbase + gy * 256 + x0 + x) * 384 + c0,
                        ldsrow + (1 + x) * 8);
            if (x == 0)  *(us8*)&ldsrow[0]      = ev;
            if (x == 63) *(us8*)&ldsrow[65 * 8] = ev;
        } else {
            *(us8*)&ldsrow[(1 + x) * 8] = zz;
            if (x == 0)  *(us8*)&ldsrow[0]      = zz;
            if (x == 63) *(us8*)&ldsrow[65 * 8] = zz;
        }
    };

    stage_row(y0 - 1, 0);
    stage_row(y0,     1);
    stage_row(y0 + 1, 2);
    __syncthreads();

    #pragma unroll
    for (int y = 0; y < 8; y++) {
        if (y < 7) stage_row(y0 + y + 2, (y + 3) & 3);

        float a[8];
        #pragma unroll
        for (int i = 0; i < 8; i++) a[i] = bi[i];
        #pragma unroll
        for (int t = 0; t < 3; t++) {
            const int s = (y + t) & 3;
            const unsigned short* rp = &ring[((s * 4 + cg) * 66 + x) * 8];
            us8 L = *(const us8*)(rp);
            us8 C = *(const us8*)(rp + 8);
            us8 R = *(const us8*)(rp + 16);
            #pragma unroll
            for (int i = 0; i < 8; i++) {
                a[i] += wr[t * 3 + 0][i] * b2f(L[i]);
                a[i] += wr[t * 3 + 1][i] * b2f(C[i]);
                a[i] += wr[t * 3 + 2][i] * b2f(R[i]);
            }
        }
        us8 ov;
        #pragma unroll
        for (int i = 0; i < 8; i++) ov[i] = f2b(gelu_t(a[i]));
        *(us8*)(h2t + (bbase + (y0 + y) * 256 + x0 + x) * 384 + c0) = ov;

        __syncthreads();
    }
}

// ---------------------------------------------------------------------------
extern "C" void kernel_launch(void* const* d_in, const int* in_sizes, int n_in,
                              void* d_out, int out_size, void* d_ws, size_t ws_size,
                              hipStream_t stream)
{
    const float* x    = (const float*)d_in[0];
    const float* ln1g = (const float*)d_in[1];
    const float* ln1b = (const float*)d_in[2];
    const float* qkvw = (const float*)d_in[3];
    const float* qkvb = (const float*)d_in[4];
    const float* outw = (const float*)d_in[5];
    const float* outb = (const float*)d_in[6];
    const float* ln2g = (const float*)d_in[7];
    const float* ln2b = (const float*)d_in[8];
    const float* w1   = (const float*)d_in[9];
    const float* b1   = (const float*)d_in[10];
    const float* dww  = (const float*)d_in[11];
    const float* dwb  = (const float*)d_in[12];
    const float* w2   = (const float*)d_in[13];
    const float* b2   = (const float*)d_in[14];
    float* out = (float*)d_out;

    char* ws = (char*)d_ws;
    unsigned short* qkv = (unsigned short*)ws;                            // [0, 302MB)  [ch][px]
    unsigned short* h1t = (unsigned short*)ws;                            // [0, 201MB)  [px][384]
    unsigned short* h2t = (unsigned short*)(ws + (size_t)201326592);      // [201MB, 403MB) [px][384]
    unsigned short* xnt = (unsigned short*)(ws + (size_t)301989888);      // [302MB, 403MB) [px][192]
    size_t off = (size_t)402653184;
    float* koff = (float*)(ws + off); off += 4096;
    float* ctxT = (float*)(ws + off); off += 131072;
    unsigned short* qkvwb = (unsigned short*)(ws + off); off += 221184;
    unsigned short* outwb = (unsigned short*)(ws + off); off += 73728 * 2;
    unsigned short* w1b   = (unsigned short*)(ws + off); off += 147456;
    unsigned short* w2b   = (unsigned short*)(ws + off); off += 147456;

    cvt_k<<<(110592 + 255) / 256, 256, 0, stream>>>(qkvw, qkvwb, 110592);
    cvt_k<<<(36864 + 255) / 256, 256, 0, stream>>>(outw, outwb, 36864);
    cvt_k<<<(73728 + 255) / 256, 256, 0, stream>>>(w1, w1b, 73728);
    cvt_k<<<(73728 + 255) / 256, 256, 0, stream>>>(w2, w2b, 73728);

    // 1) LN1 + transpose -> xnt
    lnt_k<<<1024, 256, 0, stream>>>(x, ln1g, ln1b, xnt);

    // 2) qkv GEMM (staged) -> qkv [ch][px]; 3 oc-chunks of 192
    gemm2_k<192, 0><<<dim3(4096, 3), 256, 0, stream>>>(xnt, qkvwb, qkvb, nullptr, qkv, 576);

    // 3) k-row softmax offsets
    krow_k<<<768, 256, 0, stream>>>(qkv, koff);

    // 4) context accumulation
    zero_k<<<128, 256, 0, stream>>>(ctxT, 32768);
    context_k<<<2048, 64, 0, stream>>>(qkv, koff, ctxT);

    // 5) q softmax + ctx apply + out-proj + residual -> x2 (d_out, f32)
    qctx_proj_k<<<4096, 256, 0, stream>>>(qkv, ctxT, outwb, outb, x, out);

    // 6) LN2 + transpose -> xnt
    lnt_k<<<1024, 256, 0, stream>>>(out, ln2g, ln2b, xnt);

    // 7) w1 GEMM + gelu -> h1t [px][384] (staged); 2 oc-chunks
    gemm2_k<192, 1><<<dim3(4096, 2), 256, 0, stream>>>(xnt, w1b, b1, nullptr, h1t, 384);

    // 8) depthwise 3x3 + gelu, row-streamed ring -> h2t [px][384]
    dwconv_t2_k<<<dim3(4, 32, 48), 256, 0, stream>>>(h1t, dww, dwb, h2t);

    // 9) w2 GEMM + bias + x2 residual -> d_out f32 (staged)
    gemm2_k<384, 2><<<dim3(4096, 1), 256, 0, stream>>>(h2t, w2b, b2, out, out, 192);
}

// Round 7
// 1205.544 us; speedup vs baseline: 1.1795x; 1.0116x over previous
//
#include <hip/hip_runtime.h>
#include <math.h>

typedef __attribute__((ext_vector_type(8))) short s8;
typedef __attribute__((ext_vector_type(8))) unsigned short us8;
typedef __attribute__((ext_vector_type(4))) float f4;
typedef __attribute__((ext_vector_type(4))) unsigned short us4;
typedef __attribute__((ext_vector_type(4))) unsigned int u32x4;

#define DEVI __device__ __forceinline__

static const int NPIX = 65536;   // 256*256

DEVI float b2f(unsigned short u) {
    unsigned int v = ((unsigned int)u) << 16;
    float f; __builtin_memcpy(&f, &v, 4); return f;
}
DEVI unsigned short f2b(float f) {
    unsigned int u; __builtin_memcpy(&u, &f, 4);
    unsigned int r = (u + 0x7FFFu + ((u >> 16) & 1u)) >> 16;
    return (unsigned short)r;
}
DEVI float geluf(float x) { return 0.5f * x * (1.0f + erff(x * 0.70710678118f)); }
// tanh-form gelu (max abs err ~1e-3)
DEVI float gelu_t(float x) {
    float z = 1.595769122f * (x + 0.044715f * x * x * x);
    return x * __builtin_amdgcn_rcpf(1.0f + __expf(-z));
}
DEVI float rfl(float v) {
    int i; __builtin_memcpy(&i, &v, 4);
    i = __builtin_amdgcn_readfirstlane(i);
    float o; __builtin_memcpy(&o, &i, 4); return o;
}

DEVI void gload_lds16(const unsigned short* g, unsigned short* l) {
    __builtin_amdgcn_global_load_lds(
        (const __attribute__((address_space(1))) unsigned int*)g,
        (__attribute__((address_space(3))) unsigned int*)l,
        16, 0, 0);
}

// ---------------------------------------------------------------------------
// LayerNorm + transpose: x f32 [b][192][px] -> xnt bf16 [b*px][192]
// ---------------------------------------------------------------------------
__global__ __launch_bounds__(256) void lnt_k(const float* __restrict__ X,
                                             const float* __restrict__ gw,
                                             const float* __restrict__ gb,
                                             unsigned short* __restrict__ Out)
{
    const int i = blockIdx.x * 256 + threadIdx.x;    // 0..262143
    const int b = i >> 16, px = i & 65535;
    const float* xp = X + (size_t)b * 192 * NPIX + px;

    unsigned int pk[96];
    float sum = 0.f, ssq = 0.f;
    #pragma unroll
    for (int c = 0; c < 192; c++) {
        float v = xp[(size_t)c * NPIX];
        sum += v; ssq += v * v;
        unsigned int h = f2b(v);
        if (c & 1) pk[c >> 1] |= h << 16;
        else       pk[c >> 1] = h;
    }
    float mu = sum * (1.0f / 192.0f);
    float var = ssq * (1.0f / 192.0f) - mu * mu;
    float rs = rsqrtf(var + 1e-5f);

    #pragma unroll
    for (int c2 = 0; c2 < 96; c2++) {
        int c = c2 * 2;
        float lo = b2f((unsigned short)(pk[c2] & 0xFFFF));
        float hi = b2f((unsigned short)(pk[c2] >> 16));
        lo = (lo - mu) * rs * gw[c] + gb[c];
        hi = (hi - mu) * rs * gw[c + 1] + gb[c + 1];
        pk[c2] = (unsigned int)f2b(lo) | ((unsigned int)f2b(hi) << 16);
    }
    u32x4* dst = (u32x4*)(Out + (size_t)i * 192);
    #pragma unroll
    for (int j = 0; j < 6; j++) {
        u32x4 v = { pk[4 * j], pk[4 * j + 1], pk[4 * j + 2], pk[4 * j + 3] };
        dst[j] = v;
    }
}

// ---------------------------------------------------------------------------
// Staged GEMM over channels: block = 64 px; X staged ONCE in LDS, then
// NCHUNK oc-chunks of 192 computed from the same tile (no re-stage).
// MODE 0: out bf16 [b][OCTOT][px], bias              (qkv, NCHUNK=3)
// MODE 1: out bf16 [gp][OCTOT], bias+gelu            (w1 -> h1t, NCHUNK=2)
// MODE 2: out f32  [b][OCTOT][px], bias+resid        (w2 -> d_out, NCHUNK=1)
// ---------------------------------------------------------------------------
template<int K, int MODE, int NCHUNK>
__global__ __launch_bounds__(256) void gemm2_k(
    const unsigned short* __restrict__ X, const unsigned short* __restrict__ Wb,
    const float* __restrict__ bias, const float* __restrict__ resid,
    void* __restrict__ Out, int OCTOT)
{
    constexpr int ROWS = 64;
    constexpr int CPR = K / 8;            // 16B chunks per row
    __shared__ unsigned short tile[ROWS * K];

    const int tid = threadIdx.x;
    const int wave = tid >> 6, lane = tid & 63;
    const int lr = lane & 15, lg = lane >> 4;
    const int gp0 = blockIdx.x * ROWS;    // global pixel (incl. batch)

    constexpr int CALLS = (ROWS * CPR) / 256;
    {
        const unsigned short* Xb = X + (size_t)gp0 * K;
        #pragma unroll
        for (int j = 0; j < CALLS; j++) {
            int ci = (wave * CALLS + j) * 64 + lane;
            int row = (int)((unsigned)ci / (unsigned)CPR);
            int c = ci - row * CPR;
            int csw = (c & ~7) | ((c ^ row) & 7);
            gload_lds16(Xb + (size_t)row * K + csw * 8, &tile[ci * 8]);
        }
    }

    __syncthreads();

    const int xr = lr & 7;
    const int b = gp0 >> 16;
    const int pxb = gp0 & 65535;

    for (int cn = 0; cn < NCHUNK; cn++) {
        const int ocb = cn * 192 + wave * 48;
        const unsigned short* wrow = Wb + (size_t)(ocb + lr) * K + lg * 8;

        s8 wf[3];
        #pragma unroll
        for (int ot = 0; ot < 3; ot++) wf[ot] = *(const s8*)(wrow + (size_t)ot * 16 * K);

        f4 acc[4][3];
        #pragma unroll
        for (int i = 0; i < 4; i++)
            #pragma unroll
            for (int j = 0; j < 3; j++) acc[i][j] = (f4)0.0f;

        #pragma unroll
        for (int k0 = 0; k0 < K; k0 += 32) {
            s8 wn[3];
            if (k0 + 32 < K) {
                #pragma unroll
                for (int ot = 0; ot < 3; ot++)
                    wn[ot] = *(const s8*)(wrow + (size_t)ot * 16 * K + k0 + 32);
            }
            const int kc = (k0 >> 3) + lg;
            const int kcs = (kc & ~7) | ((kc ^ xr) & 7);
            s8 a[4];
            #pragma unroll
            for (int pt = 0; pt < 4; pt++) {
                int row = pt * 16 + lr;
                a[pt] = *(const s8*)&tile[(row * CPR + kcs) * 8];
            }
            #pragma unroll
            for (int ot = 0; ot < 3; ot++)
                #pragma unroll
                for (int pt = 0; pt < 4; pt++)
                    acc[pt][ot] = (MODE == 1)
                        ? __builtin_amdgcn_mfma_f32_16x16x32_bf16(wf[ot], a[pt], acc[pt][ot], 0, 0, 0)
                        : __builtin_amdgcn_mfma_f32_16x16x32_bf16(a[pt], wf[ot], acc[pt][ot], 0, 0, 0);
            if (k0 + 32 < K) {
                #pragma unroll
                for (int ot = 0; ot < 3; ot++) wf[ot] = wn[ot];
            }
        }

        if (MODE == 0 || MODE == 2) {
            #pragma unroll
            for (int ot = 0; ot < 3; ot++) {
                const int oc = ocb + ot * 16 + lr;
                const float bi = bias[oc];
                const size_t rowoff = ((size_t)b * OCTOT + oc) * NPIX + pxb + lg * 4;
                #pragma unroll
                for (int pt = 0; pt < 4; pt++) {
                    if (MODE == 0) {
                        us4 o;
                        #pragma unroll
                        for (int r = 0; r < 4; r++) o[r] = f2b(acc[pt][ot][r] + bi);
                        *(us4*)((unsigned short*)Out + rowoff + pt * 16) = o;
                    } else {
                        f4 rv = *(const f4*)(resid + rowoff + pt * 16);
                        f4 o;
                        #pragma unroll
                        for (int r = 0; r < 4; r++) o[r] = acc[pt][ot][r] + bi + rv[r];
                        *(f4*)((float*)Out + rowoff + pt * 16) = o;
                    }
                }
            }
        } else {
            #pragma unroll
            for (int pt = 0; pt < 4; pt++) {
                const int gp = gp0 + pt * 16 + lr;
                unsigned short* orow = (unsigned short*)Out + (size_t)gp * OCTOT + ocb + lg * 4;
                #pragma unroll
                for (int ot = 0; ot < 3; ot++) {
                    f4 bi4 = *(const f4*)&bias[ocb + ot * 16 + lg * 4];
                    us4 o;
                    #pragma unroll
                    for (int r = 0; r < 4; r++) o[r] = f2b(geluf(acc[pt][ot][r] + bi4[r]));
                    *(us4*)(orow + ot * 16) = o;
                }
            }
        }
    }
}

// ---------------------------------------------------------------------------
// Per-row (b, k-channel) max + log-sum-exp over all pixels.
// ---------------------------------------------------------------------------
__global__ __launch_bounds__(256) void krow_k(const unsigned short* __restrict__ qkv,
                                              float* __restrict__ koff)
{
    int r = blockIdx.x;
    int b = r / 192, ch = 192 + (r % 192);
    const unsigned short* Kp = qkv + ((size_t)b * 576 + ch) * NPIX;
    int tid = threadIdx.x;
    float m = -1e30f, s = 0.f;
    for (int i = 0; i < 256; i++) {
        float v = b2f(Kp[tid + (size_t)i * 256]);
        if (v > m) { s = s * __expf(m - v) + 1.f; m = v; }
        else s += __expf(v - m);
    }
    __shared__ float ms[256], ss[256];
    ms[tid] = m; ss[tid] = s;
    __syncthreads();
    for (int off = 128; off > 0; off >>= 1) {
        if (tid < off) {
            float m2 = ms[tid + off], s2 = ss[tid + off];
            float M2 = fmaxf(ms[tid], m2);
            ss[tid] = ss[tid] * __expf(ms[tid] - M2) + s2 * __expf(m2 - M2);
            ms[tid] = M2;
        }
        __syncthreads();
    }
    if (tid == 0) koff[r] = ms[0] + logf(ss[0]);
}

__global__ void zero_k(float* __restrict__ p, int n)
{
    int i = blockIdx.x * 256 + threadIdx.x;
    if (i < n) p[i] = 0.f;
}

__global__ void cvt_k(const float* __restrict__ src, unsigned short* __restrict__ dst, int n)
{
    int i = blockIdx.x * 256 + threadIdx.x;
    if (i < n) dst[i] = f2b(src[i]);
}

// ---------------------------------------------------------------------------
// context: ctxT[b,h,d,c] = sum_n exp(k[c,n]-koff[c]) * v[d,n]
// ---------------------------------------------------------------------------
__global__ __launch_bounds__(64) void context_k(const unsigned short* __restrict__ qkv,
                                                const float* __restrict__ koff,
                                                float* __restrict__ ctxT)
{
    int bid = blockIdx.x;
    int bh = bid >> 6, chunk = bid & 63;
    int b = bh >> 3, h = bh & 7;
    int lane = threadIdx.x, lr = lane & 15, lg = lane >> 4;
    size_t nbase = (size_t)chunk * 1024 + lg * 8;

    int c0 = h * 24 + lr;
    int c1 = h * 24 + 16 + lr;
    float ko0 = koff[b * 192 + c0];
    int i1 = b * 192 + c1; if (i1 > 775) i1 = 775;
    float ko1 = koff[i1];
    bool val1 = lr < 8;

    const unsigned short* k0p = qkv + ((size_t)b * 576 + 192 + c0) * NPIX + nbase;
    const unsigned short* k1p = qkv + ((size_t)b * 576 + 192 + c1) * NPIX + nbase;
    const unsigned short* v0p = qkv + ((size_t)b * 576 + 384 + h * 24 + lr) * NPIX + nbase;
    const unsigned short* v1p = qkv + ((size_t)b * 576 + 384 + h * 24 + 16 + lr) * NPIX + nbase;

    f4 acc[2][2];
    #pragma unroll
    for (int i = 0; i < 2; i++) for (int j = 0; j < 2; j++) acc[i][j] = (f4)0.0f;

    for (int s = 0; s < 32; s++) {
        int off = s * 32;
        s8 kr0 = *(const s8*)(k0p + off);
        s8 kr1 = *(const s8*)(k1p + off);
        s8 vr0 = *(const s8*)(v0p + off);
        s8 vr1 = *(const s8*)(v1p + off);
        s8 p0, p1;
        #pragma unroll
        for (int j = 0; j < 8; j++) {
            p0[j] = (short)f2b(__expf(b2f((unsigned short)kr0[j]) - ko0));
            p1[j] = val1 ? (short)f2b(__expf(b2f((unsigned short)kr1[j]) - ko1)) : (short)0;
        }
        acc[0][0] = __builtin_amdgcn_mfma_f32_16x16x32_bf16(p0, vr0, acc[0][0], 0, 0, 0);
        acc[0][1] = __builtin_amdgcn_mfma_f32_16x16x32_bf16(p0, vr1, acc[0][1], 0, 0, 0);
        acc[1][0] = __builtin_amdgcn_mfma_f32_16x16x32_bf16(p1, vr0, acc[1][0], 0, 0, 0);
        acc[1][1] = __builtin_amdgcn_mfma_f32_16x16x32_bf16(p1, vr1, acc[1][1], 0, 0, 0);
    }
    float* base = ctxT + (size_t)(b * 8 + h) * 1024;
    #pragma unroll
    for (int mt = 0; mt < 2; mt++)
        #pragma unroll
        for (int ct = 0; ct < 2; ct++)
            #pragma unroll
            for (int r = 0; r < 4; r++) {
                int c = mt * 16 + lg * 4 + r;
                int d = ct * 16 + lr;
                atomicAdd(base + d * 32 + c, acc[mt][ct][r]);
            }
}

// ---------------------------------------------------------------------------
// fused: q-softmax -> ctx apply (MFMA) -> out-proj GEMM -> + x residual
// ---------------------------------------------------------------------------
__global__ __launch_bounds__(256) void qctx_proj_k(
    const unsigned short* __restrict__ qkv, const float* __restrict__ ctxT,
    const unsigned short* __restrict__ outWb, const float* __restrict__ outBias,
    const float* __restrict__ xres, float* __restrict__ Out)
{
    __shared__ unsigned short E[64][264];
    __shared__ float sden[8][64];
    __shared__ unsigned short outp[64][200];

    int tid = threadIdx.x, bid = blockIdx.x;
    int b = bid >> 10, n0 = (bid & 1023) * 64;
    int p = tid & 63, g = tid >> 6;

    #pragma unroll
    for (int hh = 0; hh < 2; hh++) {
        int h = g * 2 + hh;
        float s = 0.f;
        const unsigned short* Q = qkv + ((size_t)b * 576 + h * 24) * NPIX + n0 + p;
        #pragma unroll 4
        for (int cc = 0; cc < 24; cc++) {
            float e = __expf(b2f(Q[(size_t)cc * NPIX]));
            s += e;
            E[p][h * 32 + cc] = f2b(e);
        }
        #pragma unroll
        for (int cc = 24; cc < 32; cc++) E[p][h * 32 + cc] = 0;
        sden[h][p] = s;
    }
    __syncthreads();

    int wave = tid >> 6, lane = tid & 63, lr = lane & 15, lg = lane >> 4;

    #pragma unroll
    for (int hh = 0; hh < 2; hh++) {
        int h = wave * 2 + hh;
        s8 af[2];
        #pragma unroll
        for (int mt = 0; mt < 2; mt++) {
            const float* cp = ctxT + ((size_t)(b * 8 + h) * 32 + mt * 16 + lr) * 32 + lg * 8;
            s8 a;
            #pragma unroll
            for (int j = 0; j < 8; j++) a[j] = (short)f2b(cp[j]);
            af[mt] = a;
        }
        #pragma unroll
        for (int nt = 0; nt < 4; nt++) {
            s8 bf = *(const s8*)&E[nt * 16 + lr][h * 32 + lg * 8];
            f4 z = (f4)0.0f;
            f4 d0 = __builtin_amdgcn_mfma_f32_16x16x32_bf16(af[0], bf, z, 0, 0, 0);
            f4 d1 = __builtin_amdgcn_mfma_f32_16x16x32_bf16(af[1], bf, z, 0, 0, 0);
            int n = nt * 16 + lr;
            float sinv = 1.0f / sden[h][n];
            us4 w0;
            #pragma unroll
            for (int r = 0; r < 4; r++) w0[r] = f2b(d0[r] * sinv);
            *(us4*)&outp[n][h * 24 + lg * 4] = w0;
            if (lg < 2) {
                us4 w1;
                #pragma unroll
                for (int r = 0; r < 4; r++) w1[r] = f2b(d1[r] * sinv);
                *(us4*)&outp[n][h * 24 + 16 + lg * 4] = w1;
            }
        }
    }
    __syncthreads();

    f4 acc[3][4];
    #pragma unroll
    for (int i = 0; i < 3; i++) for (int j = 0; j < 4; j++) acc[i][j] = (f4)0.0f;
    #pragma unroll
    for (int k0 = 0; k0 < 192; k0 += 32) {
        s8 bf[4];
        #pragma unroll
        for (int nt = 0; nt < 4; nt++)
            bf[nt] = *(const s8*)&outp[nt * 16 + lr][k0 + lg * 8];
        #pragma unroll
        for (int mt = 0; mt < 3; mt++) {
            s8 af = *(const s8*)&outWb[(size_t)(wave * 48 + mt * 16 + lr) * 192 + k0 + lg * 8];
            #pragma unroll
            for (int nt = 0; nt < 4; nt++)
                acc[mt][nt] = __builtin_amdgcn_mfma_f32_16x16x32_bf16(af, bf[nt], acc[mt][nt], 0, 0, 0);
        }
    }
    #pragma unroll
    for (int mt = 0; mt < 3; mt++)
        #pragma unroll
        for (int nt = 0; nt < 4; nt++) {
            int col = n0 + nt * 16 + lr;
            #pragma unroll
            for (int r = 0; r < 4; r++) {
                int row = wave * 48 + mt * 16 + lg * 4 + r;
                size_t off = ((size_t)b * 192 + row) * NPIX + col;
                Out[off] = acc[mt][nt][r] + outBias[row] + xres[off];
            }
        }
}

// ---------------------------------------------------------------------------
// depthwise 3x3 + gelu on [px][384], row-streamed LDS ring (16.9KB)
// ---------------------------------------------------------------------------
__global__ __launch_bounds__(256) void dwconv_t2_k(
    const unsigned short* __restrict__ h1t, const float* __restrict__ w,
    const float* __restrict__ bias, unsigned short* __restrict__ h2t)
{
    __shared__ unsigned short ring[4 * 4 * 66 * 8];   // 16.9 KB
    const int bz = blockIdx.z;                        // b*12 + cbgrp
    const int b = bz / 12, cb = (bz % 12) * 32;
    const int y0 = blockIdx.y * 8, x0 = blockIdx.x * 64;
    const int tid = threadIdx.x;
    const int x = tid & 63, cg = tid >> 6;
    const int c0 = cb + cg * 8;
    const size_t bbase = (size_t)b << 16;

    float wr[9][8], bi[8];
    #pragma unroll
    for (int i = 0; i < 8; i++) {
        #pragma unroll
        for (int j = 0; j < 9; j++) wr[j][i] = rfl(w[(c0 + i) * 9 + j]);
        bi[i] = rfl(bias[c0 + i]);
    }

    const us8 zz = {0, 0, 0, 0, 0, 0, 0, 0};

    auto stage_row = [&](int gy, int s) {
        unsigned short* ldsrow = &ring[((s * 4 + cg) * 66) * 8];
        if (gy >= 0 && gy <= 255) {
            us8 ev = zz;
            if (x == 0 && x0 > 0)
                ev = *(const us8*)(h1t + (bbase + gy * 256 + x0 - 1) * 384 + c0);
            if (x == 63 && x0 + 64 < 256)
                ev = *(const us8*)(h1t + (bbase + gy * 256 + x0 + 64) * 384 + c0);
            gload_lds16(h1t + (bbase + gy * 256 + x0 + x) * 384 + c0,
                        ldsrow + (1 + x) * 8);
            if (x == 0)  *(us8*)&ldsrow[0]      = ev;
            if (x == 63) *(us8*)&ldsrow[65 * 8] = ev;
        } else {
            *(us8*)&ldsrow[(1 + x) * 8] = zz;
            if (x == 0)  *(us8*)&ldsrow[0]      = zz;
            if (x == 63) *(us8*)&ldsrow[65 * 8] = zz;
        }
    };

    stage_row(y0 - 1, 0);
    stage_row(y0,     1);
    stage_row(y0 + 1, 2);
    __syncthreads();

    #pragma unroll
    for (int y = 0; y < 8; y++) {
        if (y < 7) stage_row(y0 + y + 2, (y + 3) & 3);

        float a[8];
        #pragma unroll
        for (int i = 0; i < 8; i++) a[i] = bi[i];
        #pragma unroll
        for (int t = 0; t < 3; t++) {
            const int s = (y + t) & 3;
            const unsigned short* rp = &ring[((s * 4 + cg) * 66 + x) * 8];
            us8 L = *(const us8*)(rp);
            us8 C = *(const us8*)(rp + 8);
            us8 R = *(const us8*)(rp + 16);
            #pragma unroll
            for (int i = 0; i < 8; i++) {
                a[i] += wr[t * 3 + 0][i] * b2f(L[i]);
                a[i] += wr[t * 3 + 1][i] * b2f(C[i]);
                a[i] += wr[t * 3 + 2][i] * b2f(R[i]);
            }
        }
        us8 ov;
        #pragma unroll
        for (int i = 0; i < 8; i++) ov[i] = f2b(gelu_t(a[i]));
        *(us8*)(h2t + (bbase + (y0 + y) * 256 + x0 + x) * 384 + c0) = ov;

        __syncthreads();
    }
}

// ---------------------------------------------------------------------------
extern "C" void kernel_launch(void* const* d_in, const int* in_sizes, int n_in,
                              void* d_out, int out_size, void* d_ws, size_t ws_size,
                              hipStream_t stream)
{
    const float* x    = (const float*)d_in[0];
    const float* ln1g = (const float*)d_in[1];
    const float* ln1b = (const float*)d_in[2];
    const float* qkvw = (const float*)d_in[3];
    const float* qkvb = (const float*)d_in[4];
    const float* outw = (const float*)d_in[5];
    const float* outb = (const float*)d_in[6];
    const float* ln2g = (const float*)d_in[7];
    const float* ln2b = (const float*)d_in[8];
    const float* w1   = (const float*)d_in[9];
    const float* b1   = (const float*)d_in[10];
    const float* dww  = (const float*)d_in[11];
    const float* dwb  = (const float*)d_in[12];
    const float* w2   = (const float*)d_in[13];
    const float* b2   = (const float*)d_in[14];
    float* out = (float*)d_out;

    char* ws = (char*)d_ws;
    unsigned short* qkv = (unsigned short*)ws;                            // [0, 302MB)  [ch][px]
    unsigned short* h1t = (unsigned short*)ws;                            // [0, 201MB)  [px][384]
    unsigned short* h2t = (unsigned short*)(ws + (size_t)201326592);      // [201MB, 403MB) [px][384]
    unsigned short* xnt = (unsigned short*)(ws + (size_t)301989888);      // [302MB, 403MB) [px][192]
    size_t off = (size_t)402653184;
    float* koff = (float*)(ws + off); off += 4096;
    float* ctxT = (float*)(ws + off); off += 131072;
    unsigned short* qkvwb = (unsigned short*)(ws + off); off += 221184;
    unsigned short* outwb = (unsigned short*)(ws + off); off += 73728 * 2;
    unsigned short* w1b   = (unsigned short*)(ws + off); off += 147456;
    unsigned short* w2b   = (unsigned short*)(ws + off); off += 147456;

    cvt_k<<<(110592 + 255) / 256, 256, 0, stream>>>(qkvw, qkvwb, 110592);
    cvt_k<<<(36864 + 255) / 256, 256, 0, stream>>>(outw, outwb, 36864);
    cvt_k<<<(73728 + 255) / 256, 256, 0, stream>>>(w1, w1b, 73728);
    cvt_k<<<(73728 + 255) / 256, 256, 0, stream>>>(w2, w2b, 73728);

    // 1) LN1 + transpose -> xnt
    lnt_k<<<1024, 256, 0, stream>>>(x, ln1g, ln1b, xnt);

    // 2) qkv GEMM (staged, 3 chunks in-block) -> qkv [ch][px]
    gemm2_k<192, 0, 3><<<4096, 256, 0, stream>>>(xnt, qkvwb, qkvb, nullptr, qkv, 576);

    // 3) k-row softmax offsets
    krow_k<<<768, 256, 0, stream>>>(qkv, koff);

    // 4) context accumulation
    zero_k<<<128, 256, 0, stream>>>(ctxT, 32768);
    context_k<<<2048, 64, 0, stream>>>(qkv, koff, ctxT);

    // 5) q softmax + ctx apply + out-proj + residual -> x2 (d_out, f32)
    qctx_proj_k<<<4096, 256, 0, stream>>>(qkv, ctxT, outwb, outb, x, out);

    // 6) LN2 + transpose -> xnt
    lnt_k<<<1024, 256, 0, stream>>>(out, ln2g, ln2b, xnt);

    // 7) w1 GEMM + gelu -> h1t [px][384] (staged, 2 chunks in-block)
    gemm2_k<192, 1, 2><<<4096, 256, 0, stream>>>(xnt, w1b, b1, nullptr, h1t, 384);

    // 8) depthwise 3x3 + gelu, row-streamed ring -> h2t [px][384]
    dwconv_t2_k<<<dim3(4, 32, 48), 256, 0, stream>>>(h1t, dww, dwb, h2t);

    // 9) w2 GEMM + bias + x2 residual -> d_out f32 (staged)
    gemm2_k<384, 2, 1><<<4096, 256, 0, stream>>>(h2t, w2b, b2, out, out, 192);
}

// Round 8
// 1189.000 us; speedup vs baseline: 1.1959x; 1.0139x over previous
//
#include <hip/hip_runtime.h>
#include <math.h>

typedef __attribute__((ext_vector_type(8))) short s8;
typedef __attribute__((ext_vector_type(8))) unsigned short us8;
typedef __attribute__((ext_vector_type(4))) float f4;
typedef __attribute__((ext_vector_type(4))) unsigned short us4;
typedef __attribute__((ext_vector_type(4))) unsigned int u32x4;

#define DEVI __device__ __forceinline__

static const int NPIX = 65536;   // 256*256

DEVI float b2f(unsigned short u) {
    unsigned int v = ((unsigned int)u) << 16;
    float f; __builtin_memcpy(&f, &v, 4); return f;
}
DEVI unsigned short f2b(float f) {
    unsigned int u; __builtin_memcpy(&u, &f, 4);
    unsigned int r = (u + 0x7FFFu + ((u >> 16) & 1u)) >> 16;
    return (unsigned short)r;
}
DEVI float geluf(float x) { return 0.5f * x * (1.0f + erff(x * 0.70710678118f)); }
// tanh-form gelu (max abs err ~1e-3)
DEVI float gelu_t(float x) {
    float z = 1.595769122f * (x + 0.044715f * x * x * x);
    return x * __builtin_amdgcn_rcpf(1.0f + __expf(-z));
}
DEVI float rfl(float v) {
    int i; __builtin_memcpy(&i, &v, 4);
    i = __builtin_amdgcn_readfirstlane(i);
    float o; __builtin_memcpy(&o, &i, 4); return o;
}

DEVI void gload_lds16(const unsigned short* g, unsigned short* l) {
    __builtin_amdgcn_global_load_lds(
        (const __attribute__((address_space(1))) unsigned int*)g,
        (__attribute__((address_space(3))) unsigned int*)l,
        16, 0, 0);
}

// ---------------------------------------------------------------------------
// LayerNorm + transpose: x f32 [b][192][px] -> xnt bf16 [b*px][192]
// ---------------------------------------------------------------------------
__global__ __launch_bounds__(256) void lnt_k(const float* __restrict__ X,
                                             const float* __restrict__ gw,
                                             const float* __restrict__ gb,
                                             unsigned short* __restrict__ Out)
{
    const int i = blockIdx.x * 256 + threadIdx.x;    // 0..262143
    const int b = i >> 16, px = i & 65535;
    const float* xp = X + (size_t)b * 192 * NPIX + px;

    unsigned int pk[96];
    float sum = 0.f, ssq = 0.f;
    #pragma unroll
    for (int c = 0; c < 192; c++) {
        float v = xp[(size_t)c * NPIX];
        sum += v; ssq += v * v;
        unsigned int h = f2b(v);
        if (c & 1) pk[c >> 1] |= h << 16;
        else       pk[c >> 1] = h;
    }
    float mu = sum * (1.0f / 192.0f);
    float var = ssq * (1.0f / 192.0f) - mu * mu;
    float rs = rsqrtf(var + 1e-5f);

    #pragma unroll
    for (int c2 = 0; c2 < 96; c2++) {
        int c = c2 * 2;
        float lo = b2f((unsigned short)(pk[c2] & 0xFFFF));
        float hi = b2f((unsigned short)(pk[c2] >> 16));
        lo = (lo - mu) * rs * gw[c] + gb[c];
        hi = (hi - mu) * rs * gw[c + 1] + gb[c + 1];
        pk[c2] = (unsigned int)f2b(lo) | ((unsigned int)f2b(hi) << 16);
    }
    u32x4* dst = (u32x4*)(Out + (size_t)i * 192);
    #pragma unroll
    for (int j = 0; j < 6; j++) {
        u32x4 v = { pk[4 * j], pk[4 * j + 1], pk[4 * j + 2], pk[4 * j + 3] };
        dst[j] = v;
    }
}

// ---------------------------------------------------------------------------
// Staged GEMM: block = 64 px; X staged once in LDS; per 192-oc chunk the
// full K-block of W frags is preloaded in one burst (one latency exposure),
// then a pure LDS+MFMA k-loop.
// MODE 0: out bf16 [b][OCTOT][px], bias              (qkv, NCHUNK=3)
// MODE 1: out bf16 [gp][OCTOT], bias+gelu            (w1 -> h1t, NCHUNK=2)
// MODE 2: out f32  [b][OCTOT][px], bias+resid        (w2 -> d_out, NCHUNK=1)
// ---------------------------------------------------------------------------
template<int K, int MODE, int NCHUNK>
__global__ __launch_bounds__(256) void gemm2_k(
    const unsigned short* __restrict__ X, const unsigned short* __restrict__ Wb,
    const float* __restrict__ bias, const float* __restrict__ resid,
    void* __restrict__ Out, int OCTOT)
{
    constexpr int ROWS = 64;
    constexpr int CPR = K / 8;            // 16B chunks per row
    __shared__ unsigned short tile[ROWS * K];

    const int tid = threadIdx.x;
    const int wave = tid >> 6, lane = tid & 63;
    const int lr = lane & 15, lg = lane >> 4;
    const int gp0 = blockIdx.x * ROWS;    // global pixel (incl. batch)

    constexpr int CALLS = (ROWS * CPR) / 256;
    {
        const unsigned short* Xb = X + (size_t)gp0 * K;
        #pragma unroll
        for (int j = 0; j < CALLS; j++) {
            int ci = (wave * CALLS + j) * 64 + lane;
            int row = (int)((unsigned)ci / (unsigned)CPR);
            int c = ci - row * CPR;
            int csw = (c & ~7) | ((c ^ row) & 7);
            gload_lds16(Xb + (size_t)row * K + csw * 8, &tile[ci * 8]);
        }
    }

    __syncthreads();

    const int xr = lr & 7;
    const int b = gp0 >> 16;
    const int pxb = gp0 & 65535;

    for (int cn = 0; cn < NCHUNK; cn++) {
        const int ocb = cn * 192 + wave * 48;
        const unsigned short* wrow = Wb + (size_t)(ocb + lr) * K + lg * 8;

        f4 acc[4][3];
        #pragma unroll
        for (int i = 0; i < 4; i++)
            #pragma unroll
            for (int j = 0; j < 3; j++) acc[i][j] = (f4)0.0f;

        #pragma unroll
        for (int kb = 0; kb < K; kb += 192) {
            // batch-preload all W frags for this 192-wide K block (18 loads)
            s8 wf[3][6];
            #pragma unroll
            for (int ot = 0; ot < 3; ot++)
                #pragma unroll
                for (int kk = 0; kk < 6; kk++)
                    wf[ot][kk] = *(const s8*)(wrow + (size_t)ot * 16 * K + kb + kk * 32);

            #pragma unroll
            for (int kk = 0; kk < 6; kk++) {
                const int k0 = kb + kk * 32;
                const int kc = (k0 >> 3) + lg;
                const int kcs = (kc & ~7) | ((kc ^ xr) & 7);
                s8 a[4];
                #pragma unroll
                for (int pt = 0; pt < 4; pt++) {
                    int row = pt * 16 + lr;
                    a[pt] = *(const s8*)&tile[(row * CPR + kcs) * 8];
                }
                #pragma unroll
                for (int ot = 0; ot < 3; ot++)
                    #pragma unroll
                    for (int pt = 0; pt < 4; pt++)
                        acc[pt][ot] = (MODE == 1)
                            ? __builtin_amdgcn_mfma_f32_16x16x32_bf16(wf[ot][kk], a[pt], acc[pt][ot], 0, 0, 0)
                            : __builtin_amdgcn_mfma_f32_16x16x32_bf16(a[pt], wf[ot][kk], acc[pt][ot], 0, 0, 0);
            }
        }

        if (MODE == 0 || MODE == 2) {
            #pragma unroll
            for (int ot = 0; ot < 3; ot++) {
                const int oc = ocb + ot * 16 + lr;
                const float bi = bias[oc];
                const size_t rowoff = ((size_t)b * OCTOT + oc) * NPIX + pxb + lg * 4;
                #pragma unroll
                for (int pt = 0; pt < 4; pt++) {
                    if (MODE == 0) {
                        us4 o;
                        #pragma unroll
                        for (int r = 0; r < 4; r++) o[r] = f2b(acc[pt][ot][r] + bi);
                        *(us4*)((unsigned short*)Out + rowoff + pt * 16) = o;
                    } else {
                        f4 rv = *(const f4*)(resid + rowoff + pt * 16);
                        f4 o;
                        #pragma unroll
                        for (int r = 0; r < 4; r++) o[r] = acc[pt][ot][r] + bi + rv[r];
                        *(f4*)((float*)Out + rowoff + pt * 16) = o;
                    }
                }
            }
        } else {
            #pragma unroll
            for (int pt = 0; pt < 4; pt++) {
                const int gp = gp0 + pt * 16 + lr;
                unsigned short* orow = (unsigned short*)Out + (size_t)gp * OCTOT + ocb + lg * 4;
                #pragma unroll
                for (int ot = 0; ot < 3; ot++) {
                    f4 bi4 = *(const f4*)&bias[ocb + ot * 16 + lg * 4];
                    us4 o;
                    #pragma unroll
                    for (int r = 0; r < 4; r++) o[r] = f2b(geluf(acc[pt][ot][r] + bi4[r]));
                    *(us4*)(orow + ot * 16) = o;
                }
            }
        }
    }
}

// ---------------------------------------------------------------------------
// Per-row (b, k-channel) max + log-sum-exp over all pixels.
// ---------------------------------------------------------------------------
__global__ __launch_bounds__(256) void krow_k(const unsigned short* __restrict__ qkv,
                                              float* __restrict__ koff)
{
    int r = blockIdx.x;
    int b = r / 192, ch = 192 + (r % 192);
    const unsigned short* Kp = qkv + ((size_t)b * 576 + ch) * NPIX;
    int tid = threadIdx.x;
    float m = -1e30f, s = 0.f;
    for (int i = 0; i < 256; i++) {
        float v = b2f(Kp[tid + (size_t)i * 256]);
        if (v > m) { s = s * __expf(m - v) + 1.f; m = v; }
        else s += __expf(v - m);
    }
    __shared__ float ms[256], ss[256];
    ms[tid] = m; ss[tid] = s;
    __syncthreads();
    for (int off = 128; off > 0; off >>= 1) {
        if (tid < off) {
            float m2 = ms[tid + off], s2 = ss[tid + off];
            float M2 = fmaxf(ms[tid], m2);
            ss[tid] = ss[tid] * __expf(ms[tid] - M2) + s2 * __expf(m2 - M2);
            ms[tid] = M2;
        }
        __syncthreads();
    }
    if (tid == 0) koff[r] = ms[0] + logf(ss[0]);
}

__global__ void zero_k(float* __restrict__ p, int n)
{
    int i = blockIdx.x * 256 + threadIdx.x;
    if (i < n) p[i] = 0.f;
}

__global__ void cvt_k(const float* __restrict__ src, unsigned short* __restrict__ dst, int n)
{
    int i = blockIdx.x * 256 + threadIdx.x;
    if (i < n) dst[i] = f2b(src[i]);
}

// ---------------------------------------------------------------------------
// context: ctxT[b,h,d,c] = sum_n exp(k[c,n]-koff[c]) * v[d,n]
// ---------------------------------------------------------------------------
__global__ __launch_bounds__(64) void context_k(const unsigned short* __restrict__ qkv,
                                                const float* __restrict__ koff,
                                                float* __restrict__ ctxT)
{
    int bid = blockIdx.x;
    int bh = bid >> 6, chunk = bid & 63;
    int b = bh >> 3, h = bh & 7;
    int lane = threadIdx.x, lr = lane & 15, lg = lane >> 4;
    size_t nbase = (size_t)chunk * 1024 + lg * 8;

    int c0 = h * 24 + lr;
    int c1 = h * 24 + 16 + lr;
    float ko0 = koff[b * 192 + c0];
    int i1 = b * 192 + c1; if (i1 > 775) i1 = 775;
    float ko1 = koff[i1];
    bool val1 = lr < 8;

    const unsigned short* k0p = qkv + ((size_t)b * 576 + 192 + c0) * NPIX + nbase;
    const unsigned short* k1p = qkv + ((size_t)b * 576 + 192 + c1) * NPIX + nbase;
    const unsigned short* v0p = qkv + ((size_t)b * 576 + 384 + h * 24 + lr) * NPIX + nbase;
    const unsigned short* v1p = qkv + ((size_t)b * 576 + 384 + h * 24 + 16 + lr) * NPIX + nbase;

    f4 acc[2][2];
    #pragma unroll
    for (int i = 0; i < 2; i++) for (int j = 0; j < 2; j++) acc[i][j] = (f4)0.0f;

    for (int s = 0; s < 32; s++) {
        int off = s * 32;
        s8 kr0 = *(const s8*)(k0p + off);
        s8 kr1 = *(const s8*)(k1p + off);
        s8 vr0 = *(const s8*)(v0p + off);
        s8 vr1 = *(const s8*)(v1p + off);
        s8 p0, p1;
        #pragma unroll
        for (int j = 0; j < 8; j++) {
            p0[j] = (short)f2b(__expf(b2f((unsigned short)kr0[j]) - ko0));
            p1[j] = val1 ? (short)f2b(__expf(b2f((unsigned short)kr1[j]) - ko1)) : (short)0;
        }
        acc[0][0] = __builtin_amdgcn_mfma_f32_16x16x32_bf16(p0, vr0, acc[0][0], 0, 0, 0);
        acc[0][1] = __builtin_amdgcn_mfma_f32_16x16x32_bf16(p0, vr1, acc[0][1], 0, 0, 0);
        acc[1][0] = __builtin_amdgcn_mfma_f32_16x16x32_bf16(p1, vr0, acc[1][0], 0, 0, 0);
        acc[1][1] = __builtin_amdgcn_mfma_f32_16x16x32_bf16(p1, vr1, acc[1][1], 0, 0, 0);
    }
    float* base = ctxT + (size_t)(b * 8 + h) * 1024;
    #pragma unroll
    for (int mt = 0; mt < 2; mt++)
        #pragma unroll
        for (int ct = 0; ct < 2; ct++)
            #pragma unroll
            for (int r = 0; r < 4; r++) {
                int c = mt * 16 + lg * 4 + r;
                int d = ct * 16 + lr;
                atomicAdd(base + d * 32 + c, acc[mt][ct][r]);
            }
}

// ---------------------------------------------------------------------------
// fused: q-softmax -> ctx apply -> out-proj GEMM -> + x resid -> x2 (f32)
//        -> LN2 over channels (block-wide) -> xnt bf16 [px][192]
// Each block owns ALL 192 out-channels for its 64-px tile.
// ---------------------------------------------------------------------------
__global__ __launch_bounds__(256) void qctx_proj_k(
    const unsigned short* __restrict__ qkv, const float* __restrict__ ctxT,
    const unsigned short* __restrict__ outWb, const float* __restrict__ outBias,
    const float* __restrict__ xres, float* __restrict__ Out,
    const float* __restrict__ ln2g, const float* __restrict__ ln2b,
    unsigned short* __restrict__ xnt)
{
    __shared__ unsigned short E[64][264];
    __shared__ float sden[8][64];
    __shared__ unsigned short outp[64][200];
    __shared__ float lnS[4][64], lnQ[4][64];

    int tid = threadIdx.x, bid = blockIdx.x;
    int b = bid >> 10, n0 = (bid & 1023) * 64;
    int p = tid & 63, g = tid >> 6;

    #pragma unroll
    for (int hh = 0; hh < 2; hh++) {
        int h = g * 2 + hh;
        float s = 0.f;
        const unsigned short* Q = qkv + ((size_t)b * 576 + h * 24) * NPIX + n0 + p;
        #pragma unroll 4
        for (int cc = 0; cc < 24; cc++) {
            float e = __expf(b2f(Q[(size_t)cc * NPIX]));
            s += e;
            E[p][h * 32 + cc] = f2b(e);
        }
        #pragma unroll
        for (int cc = 24; cc < 32; cc++) E[p][h * 32 + cc] = 0;
        sden[h][p] = s;
    }
    __syncthreads();

    int wave = tid >> 6, lane = tid & 63, lr = lane & 15, lg = lane >> 4;

    #pragma unroll
    for (int hh = 0; hh < 2; hh++) {
        int h = wave * 2 + hh;
        s8 af[2];
        #pragma unroll
        for (int mt = 0; mt < 2; mt++) {
            const float* cp = ctxT + ((size_t)(b * 8 + h) * 32 + mt * 16 + lr) * 32 + lg * 8;
            s8 a;
            #pragma unroll
            for (int j = 0; j < 8; j++) a[j] = (short)f2b(cp[j]);
            af[mt] = a;
        }
        #pragma unroll
        for (int nt = 0; nt < 4; nt++) {
            s8 bf = *(const s8*)&E[nt * 16 + lr][h * 32 + lg * 8];
            f4 z = (f4)0.0f;
            f4 d0 = __builtin_amdgcn_mfma_f32_16x16x32_bf16(af[0], bf, z, 0, 0, 0);
            f4 d1 = __builtin_amdgcn_mfma_f32_16x16x32_bf16(af[1], bf, z, 0, 0, 0);
            int n = nt * 16 + lr;
            float sinv = 1.0f / sden[h][n];
            us4 w0;
            #pragma unroll
            for (int r = 0; r < 4; r++) w0[r] = f2b(d0[r] * sinv);
            *(us4*)&outp[n][h * 24 + lg * 4] = w0;
            if (lg < 2) {
                us4 w1;
                #pragma unroll
                for (int r = 0; r < 4; r++) w1[r] = f2b(d1[r] * sinv);
                *(us4*)&outp[n][h * 24 + 16 + lg * 4] = w1;
            }
        }
    }
    __syncthreads();

    f4 acc[3][4];
    #pragma unroll
    for (int i = 0; i < 3; i++) for (int j = 0; j < 4; j++) acc[i][j] = (f4)0.0f;
    #pragma unroll
    for (int k0 = 0; k0 < 192; k0 += 32) {
        s8 bf[4];
        #pragma unroll
        for (int nt = 0; nt < 4; nt++)
            bf[nt] = *(const s8*)&outp[nt * 16 + lr][k0 + lg * 8];
        #pragma unroll
        for (int mt = 0; mt < 3; mt++) {
            s8 af = *(const s8*)&outWb[(size_t)(wave * 48 + mt * 16 + lr) * 192 + k0 + lg * 8];
            #pragma unroll
            for (int nt = 0; nt < 4; nt++)
                acc[mt][nt] = __builtin_amdgcn_mfma_f32_16x16x32_bf16(af, bf[nt], acc[mt][nt], 0, 0, 0);
        }
    }

    // x2 = proj + bias + x  (write f32, keep in acc), partial LN sums per col
    float s4[4] = {0.f, 0.f, 0.f, 0.f}, q4[4] = {0.f, 0.f, 0.f, 0.f};
    #pragma unroll
    for (int mt = 0; mt < 3; mt++)
        #pragma unroll
        for (int nt = 0; nt < 4; nt++) {
            int col = n0 + nt * 16 + lr;
            #pragma unroll
            for (int r = 0; r < 4; r++) {
                int row = wave * 48 + mt * 16 + lg * 4 + r;
                size_t off = ((size_t)b * 192 + row) * NPIX + col;
                float v = acc[mt][nt][r] + outBias[row] + xres[off];
                acc[mt][nt][r] = v;
                Out[off] = v;
                s4[nt] += v; q4[nt] += v * v;
            }
        }
    // reduce across lg (lanes xor 16,32) then across waves via LDS
    #pragma unroll
    for (int nt = 0; nt < 4; nt++) {
        s4[nt] += __shfl_xor(s4[nt], 16); s4[nt] += __shfl_xor(s4[nt], 32);
        q4[nt] += __shfl_xor(q4[nt], 16); q4[nt] += __shfl_xor(q4[nt], 32);
    }
    if (lg == 0) {
        #pragma unroll
        for (int nt = 0; nt < 4; nt++) {
            lnS[wave][nt * 16 + lr] = s4[nt];
            lnQ[wave][nt * 16 + lr] = q4[nt];
        }
    }
    __syncthreads();

    float mus[4], rss[4];
    #pragma unroll
    for (int nt = 0; nt < 4; nt++) {
        int c16 = nt * 16 + lr;
        float S = lnS[0][c16] + lnS[1][c16] + lnS[2][c16] + lnS[3][c16];
        float Qq = lnQ[0][c16] + lnQ[1][c16] + lnQ[2][c16] + lnQ[3][c16];
        float mu = S * (1.0f / 192.0f);
        float var = Qq * (1.0f / 192.0f) - mu * mu;
        mus[nt] = mu; rss[nt] = rsqrtf(var + 1e-5f);
    }
    #pragma unroll
    for (int mt = 0; mt < 3; mt++) {
        int rb = wave * 48 + mt * 16 + lg * 4;
        f4 g4v = *(const f4*)&ln2g[rb];
        f4 b4v = *(const f4*)&ln2b[rb];
        #pragma unroll
        for (int nt = 0; nt < 4; nt++) {
            int gp = (b << 16) + n0 + nt * 16 + lr;
            us4 o;
            #pragma unroll
            for (int r = 0; r < 4; r++) {
                float xn = (acc[mt][nt][r] - mus[nt]) * rss[nt] * g4v[r] + b4v[r];
                o[r] = f2b(xn);
            }
            *(us4*)(xnt + (size_t)gp * 192 + rb) = o;
        }
    }
}

// ---------------------------------------------------------------------------
// depthwise 3x3 + gelu on [px][384], row-streamed LDS ring (16.9KB)
// ---------------------------------------------------------------------------
__global__ __launch_bounds__(256) void dwconv_t2_k(
    const unsigned short* __restrict__ h1t, const float* __restrict__ w,
    const float* __restrict__ bias, unsigned short* __restrict__ h2t)
{
    __shared__ unsigned short ring[4 * 4 * 66 * 8];   // 16.9 KB
    const int bz = blockIdx.z;                        // b*12 + cbgrp
    const int b = bz / 12, cb = (bz % 12) * 32;
    const int y0 = blockIdx.y * 8, x0 = blockIdx.x * 64;
    const int tid = threadIdx.x;
    const int x = tid & 63, cg = tid >> 6;
    const int c0 = cb + cg * 8;
    const size_t bbase = (size_t)b << 16;

    float wr[9][8], bi[8];
    #pragma unroll
    for (int i = 0; i < 8; i++) {
        #pragma unroll
        for (int j = 0; j < 9; j++) wr[j][i] = rfl(w[(c0 + i) * 9 + j]);
        bi[i] = rfl(bias[c0 + i]);
    }

    const us8 zz = {0, 0, 0, 0, 0, 0, 0, 0};

    auto stage_row = [&](int gy, int s) {
        unsigned short* ldsrow = &ring[((s * 4 + cg) * 66) * 8];
        if (gy >= 0 && gy <= 255) {
            us8 ev = zz;
            if (x == 0 && x0 > 0)
                ev = *(const us8*)(h1t + (bbase + gy * 256 + x0 - 1) * 384 + c0);
            if (x == 63 && x0 + 64 < 256)
                ev = *(const us8*)(h1t + (bbase + gy * 256 + x0 + 64) * 384 + c0);
            gload_lds16(h1t + (bbase + gy * 256 + x0 + x) * 384 + c0,
                        ldsrow + (1 + x) * 8);
            if (x == 0)  *(us8*)&ldsrow[0]      = ev;
            if (x == 63) *(us8*)&ldsrow[65 * 8] = ev;
        } else {
            *(us8*)&ldsrow[(1 + x) * 8] = zz;
            if (x == 0)  *(us8*)&ldsrow[0]      = zz;
            if (x == 63) *(us8*)&ldsrow[65 * 8] = zz;
        }
    };

    stage_row(y0 - 1, 0);
    stage_row(y0,     1);
    stage_row(y0 + 1, 2);
    __syncthreads();

    #pragma unroll
    for (int y = 0; y < 8; y++) {
        if (y < 7) stage_row(y0 + y + 2, (y + 3) & 3);

        float a[8];
        #pragma unroll
        for (int i = 0; i < 8; i++) a[i] = bi[i];
        #pragma unroll
        for (int t = 0; t < 3; t++) {
            const int s = (y + t) & 3;
            const unsigned short* rp = &ring[((s * 4 + cg) * 66 + x) * 8];
            us8 L = *(const us8*)(rp);
            us8 C = *(const us8*)(rp + 8);
            us8 R = *(const us8*)(rp + 16);
            #pragma unroll
            for (int i = 0; i < 8; i++) {
                a[i] += wr[t * 3 + 0][i] * b2f(L[i]);
                a[i] += wr[t * 3 + 1][i] * b2f(C[i]);
                a[i] += wr[t * 3 + 2][i] * b2f(R[i]);
            }
        }
        us8 ov;
        #pragma unroll
        for (int i = 0; i < 8; i++) ov[i] = f2b(gelu_t(a[i]));
        *(us8*)(h2t + (bbase + (y0 + y) * 256 + x0 + x) * 384 + c0) = ov;

        __syncthreads();
    }
}

// ---------------------------------------------------------------------------
extern "C" void kernel_launch(void* const* d_in, const int* in_sizes, int n_in,
                              void* d_out, int out_size, void* d_ws, size_t ws_size,
                              hipStream_t stream)
{
    const float* x    = (const float*)d_in[0];
    const float* ln1g = (const float*)d_in[1];
    const float* ln1b = (const float*)d_in[2];
    const float* qkvw = (const float*)d_in[3];
    const float* qkvb = (const float*)d_in[4];
    const float* outw = (const float*)d_in[5];
    const float* outb = (const float*)d_in[6];
    const float* ln2g = (const float*)d_in[7];
    const float* ln2b = (const float*)d_in[8];
    const float* w1   = (const float*)d_in[9];
    const float* b1   = (const float*)d_in[10];
    const float* dww  = (const float*)d_in[11];
    const float* dwb  = (const float*)d_in[12];
    const float* w2   = (const float*)d_in[13];
    const float* b2   = (const float*)d_in[14];
    float* out = (float*)d_out;

    char* ws = (char*)d_ws;
    unsigned short* qkv = (unsigned short*)ws;                            // [0, 288MiB)  [ch][px]
    unsigned short* h1t = (unsigned short*)ws;                            // [0, 192MiB)  [px][384]
    unsigned short* h2t = (unsigned short*)(ws + (size_t)201326592);      // [192MiB, 384MiB) [px][384]
    unsigned short* xnt = (unsigned short*)(ws + (size_t)301989888);      // [288MiB, 384MiB) [px][192]
    size_t off = (size_t)402653184;
    float* koff = (float*)(ws + off); off += 4096;
    float* ctxT = (float*)(ws + off); off += 131072;
    unsigned short* qkvwb = (unsigned short*)(ws + off); off += 221184;
    unsigned short* outwb = (unsigned short*)(ws + off); off += 73728 * 2;
    unsigned short* w1b   = (unsigned short*)(ws + off); off += 147456;
    unsigned short* w2b   = (unsigned short*)(ws + off); off += 147456;

    cvt_k<<<(110592 + 255) / 256, 256, 0, stream>>>(qkvw, qkvwb, 110592);
    cvt_k<<<(36864 + 255) / 256, 256, 0, stream>>>(outw, outwb, 36864);
    cvt_k<<<(73728 + 255) / 256, 256, 0, stream>>>(w1, w1b, 73728);
    cvt_k<<<(73728 + 255) / 256, 256, 0, stream>>>(w2, w2b, 73728);

    // 1) LN1 + transpose -> xnt
    lnt_k<<<1024, 256, 0, stream>>>(x, ln1g, ln1b, xnt);

    // 2) qkv GEMM (staged, batched-W) -> qkv [ch][px]
    gemm2_k<192, 0, 3><<<4096, 256, 0, stream>>>(xnt, qkvwb, qkvb, nullptr, qkv, 576);

    // 3) k-row softmax offsets
    krow_k<<<768, 256, 0, stream>>>(qkv, koff);

    // 4) context accumulation
    zero_k<<<128, 256, 0, stream>>>(ctxT, 32768);
    context_k<<<2048, 64, 0, stream>>>(qkv, koff, ctxT);

    // 5) q softmax + ctx + proj + resid -> x2 (d_out f32) + fused LN2 -> xnt
    qctx_proj_k<<<4096, 256, 0, stream>>>(qkv, ctxT, outwb, outb, x, out,
                                          ln2g, ln2b, xnt);

    // 6) w1 GEMM + gelu -> h1t [px][384] (staged, batched-W)
    gemm2_k<192, 1, 2><<<4096, 256, 0, stream>>>(xnt, w1b, b1, nullptr, h1t, 384);

    // 7) depthwise 3x3 + gelu, row-streamed ring -> h2t [px][384]
    dwconv_t2_k<<<dim3(4, 32, 48), 256, 0, stream>>>(h1t, dww, dwb, h2t);

    // 8) w2 GEMM + bias + x2 residual -> d_out f32 (staged, batched-W)
    gemm2_k<384, 2, 1><<<4096, 256, 0, stream>>>(h2t, w2b, b2, out, out, 192);
}

// Round 9
// 1184.880 us; speedup vs baseline: 1.2000x; 1.0035x over previous
//
#include <hip/hip_runtime.h>
#include <math.h>

typedef __attribute__((ext_vector_type(8))) short s8;
typedef __attribute__((ext_vector_type(8))) unsigned short us8;
typedef __attribute__((ext_vector_type(4))) float f4;
typedef __attribute__((ext_vector_type(4))) unsigned short us4;
typedef __attribute__((ext_vector_type(4))) unsigned int u32x4;

#define DEVI __device__ __forceinline__

static const int NPIX = 65536;   // 256*256

DEVI float b2f(unsigned short u) {
    unsigned int v = ((unsigned int)u) << 16;
    float f; __builtin_memcpy(&f, &v, 4); return f;
}
DEVI unsigned short f2b(float f) {
    unsigned int u; __builtin_memcpy(&u, &f, 4);
    unsigned int r = (u + 0x7FFFu + ((u >> 16) & 1u)) >> 16;
    return (unsigned short)r;
}
DEVI float geluf(float x) { return 0.5f * x * (1.0f + erff(x * 0.70710678118f)); }
// tanh-form gelu (max abs err ~1e-3)
DEVI float gelu_t(float x) {
    float z = 1.595769122f * (x + 0.044715f * x * x * x);
    return x * __builtin_amdgcn_rcpf(1.0f + __expf(-z));
}
DEVI float rfl(float v) {
    int i; __builtin_memcpy(&i, &v, 4);
    i = __builtin_amdgcn_readfirstlane(i);
    float o; __builtin_memcpy(&o, &i, 4); return o;
}

DEVI void gload_lds16(const unsigned short* g, unsigned short* l) {
    __builtin_amdgcn_global_load_lds(
        (const __attribute__((address_space(1))) unsigned int*)g,
        (__attribute__((address_space(3))) unsigned int*)l,
        16, 0, 0);
}

// ---------------------------------------------------------------------------
// LayerNorm + transpose: x f32 [b][192][px] -> xnt bf16 [b*px][192]
// ---------------------------------------------------------------------------
__global__ __launch_bounds__(256) void lnt_k(const float* __restrict__ X,
                                             const float* __restrict__ gw,
                                             const float* __restrict__ gb,
                                             unsigned short* __restrict__ Out)
{
    const int i = blockIdx.x * 256 + threadIdx.x;    // 0..262143
    const int b = i >> 16, px = i & 65535;
    const float* xp = X + (size_t)b * 192 * NPIX + px;

    unsigned int pk[96];
    float sum = 0.f, ssq = 0.f;
    #pragma unroll
    for (int c = 0; c < 192; c++) {
        float v = xp[(size_t)c * NPIX];
        sum += v; ssq += v * v;
        unsigned int h = f2b(v);
        if (c & 1) pk[c >> 1] |= h << 16;
        else       pk[c >> 1] = h;
    }
    float mu = sum * (1.0f / 192.0f);
    float var = ssq * (1.0f / 192.0f) - mu * mu;
    float rs = rsqrtf(var + 1e-5f);

    #pragma unroll
    for (int c2 = 0; c2 < 96; c2++) {
        int c = c2 * 2;
        float lo = b2f((unsigned short)(pk[c2] & 0xFFFF));
        float hi = b2f((unsigned short)(pk[c2] >> 16));
        lo = (lo - mu) * rs * gw[c] + gb[c];
        hi = (hi - mu) * rs * gw[c + 1] + gb[c + 1];
        pk[c2] = (unsigned int)f2b(lo) | ((unsigned int)f2b(hi) << 16);
    }
    u32x4* dst = (u32x4*)(Out + (size_t)i * 192);
    #pragma unroll
    for (int j = 0; j < 6; j++) {
        u32x4 v = { pk[4 * j], pk[4 * j + 1], pk[4 * j + 2], pk[4 * j + 3] };
        dst[j] = v;
    }
}

// ---------------------------------------------------------------------------
// Staged GEMM: block = 64 px; X staged once in LDS; batched W preload.
// MODE 0: out bf16 [b][OCTOT][px], bias              (generic)
// MODE 1: out bf16 [gp][OCTOT], bias+gelu            (w1 -> h1t, NCHUNK=2)
// MODE 2: out f32  [b][OCTOT][px], bias+resid        (w2 -> d_out, NCHUNK=1)
// MODE 3: qkv fused: cn==0 -> q transposed to qT[gp][192] (swapped operands);
//         cn=1,2 -> k,v to kv[b][384][px].  OCTOT unused for q.
// ---------------------------------------------------------------------------
template<int K, int MODE, int NCHUNK>
__global__ __launch_bounds__(256) void gemm2_k(
    const unsigned short* __restrict__ X, const unsigned short* __restrict__ Wb,
    const float* __restrict__ bias, const float* __restrict__ resid,
    void* __restrict__ Out, int OCTOT, unsigned short* __restrict__ qT)
{
    constexpr int ROWS = 64;
    constexpr int CPR = K / 8;            // 16B chunks per row
    __shared__ unsigned short tile[ROWS * K];

    const int tid = threadIdx.x;
    const int wave = tid >> 6, lane = tid & 63;
    const int lr = lane & 15, lg = lane >> 4;
    const int gp0 = blockIdx.x * ROWS;    // global pixel (incl. batch)

    constexpr int CALLS = (ROWS * CPR) / 256;
    {
        const unsigned short* Xb = X + (size_t)gp0 * K;
        #pragma unroll
        for (int j = 0; j < CALLS; j++) {
            int ci = (wave * CALLS + j) * 64 + lane;
            int row = (int)((unsigned)ci / (unsigned)CPR);
            int c = ci - row * CPR;
            int csw = (c & ~7) | ((c ^ row) & 7);
            gload_lds16(Xb + (size_t)row * K + csw * 8, &tile[ci * 8]);
        }
    }

    __syncthreads();

    const int xr = lr & 7;
    const int b = gp0 >> 16;
    const int pxb = gp0 & 65535;

    #pragma unroll
    for (int cn = 0; cn < NCHUNK; cn++) {
        const int ocb = cn * 192 + wave * 48;
        const unsigned short* wrow = Wb + (size_t)(ocb + lr) * K + lg * 8;
        const bool swapped = (MODE == 1) || (MODE == 3 && cn == 0);

        f4 acc[4][3];
        #pragma unroll
        for (int i = 0; i < 4; i++)
            #pragma unroll
            for (int j = 0; j < 3; j++) acc[i][j] = (f4)0.0f;

        #pragma unroll
        for (int kb = 0; kb < K; kb += 192) {
            s8 wf[3][6];
            #pragma unroll
            for (int ot = 0; ot < 3; ot++)
                #pragma unroll
                for (int kk = 0; kk < 6; kk++)
                    wf[ot][kk] = *(const s8*)(wrow + (size_t)ot * 16 * K + kb + kk * 32);

            #pragma unroll
            for (int kk = 0; kk < 6; kk++) {
                const int k0 = kb + kk * 32;
                const int kc = (k0 >> 3) + lg;
                const int kcs = (kc & ~7) | ((kc ^ xr) & 7);
                s8 a[4];
                #pragma unroll
                for (int pt = 0; pt < 4; pt++) {
                    int row = pt * 16 + lr;
                    a[pt] = *(const s8*)&tile[(row * CPR + kcs) * 8];
                }
                #pragma unroll
                for (int ot = 0; ot < 3; ot++)
                    #pragma unroll
                    for (int pt = 0; pt < 4; pt++)
                        acc[pt][ot] = swapped
                            ? __builtin_amdgcn_mfma_f32_16x16x32_bf16(wf[ot][kk], a[pt], acc[pt][ot], 0, 0, 0)
                            : __builtin_amdgcn_mfma_f32_16x16x32_bf16(a[pt], wf[ot][kk], acc[pt][ot], 0, 0, 0);
            }
        }

        if (MODE == 3 && cn == 0) {
            // q transposed: D row = oc (lg*4+r), col = px (lr)
            #pragma unroll
            for (int pt = 0; pt < 4; pt++) {
                const int gp = gp0 + pt * 16 + lr;
                unsigned short* orow = qT + (size_t)gp * 192 + wave * 48 + lg * 4;
                #pragma unroll
                for (int ot = 0; ot < 3; ot++) {
                    f4 bi4 = *(const f4*)&bias[wave * 48 + ot * 16 + lg * 4];
                    us4 o;
                    #pragma unroll
                    for (int r = 0; r < 4; r++) o[r] = f2b(acc[pt][ot][r] + bi4[r]);
                    *(us4*)(orow + ot * 16) = o;
                }
            }
        } else if (MODE == 3) {
            // k/v -> kv[b][384][px]
            #pragma unroll
            for (int ot = 0; ot < 3; ot++) {
                const int oc = ocb + ot * 16 + lr;           // global 192..575
                const float bi = bias[oc];
                const size_t rowoff = ((size_t)b * 384 + (oc - 192)) * NPIX + pxb + lg * 4;
                #pragma unroll
                for (int pt = 0; pt < 4; pt++) {
                    us4 o;
                    #pragma unroll
                    for (int r = 0; r < 4; r++) o[r] = f2b(acc[pt][ot][r] + bi);
                    *(us4*)((unsigned short*)Out + rowoff + pt * 16) = o;
                }
            }
        } else if (MODE == 0 || MODE == 2) {
            #pragma unroll
            for (int ot = 0; ot < 3; ot++) {
                const int oc = ocb + ot * 16 + lr;
                const float bi = bias[oc];
                const size_t rowoff = ((size_t)b * OCTOT + oc) * NPIX + pxb + lg * 4;
                #pragma unroll
                for (int pt = 0; pt < 4; pt++) {
                    if (MODE == 0) {
                        us4 o;
                        #pragma unroll
                        for (int r = 0; r < 4; r++) o[r] = f2b(acc[pt][ot][r] + bi);
                        *(us4*)((unsigned short*)Out + rowoff + pt * 16) = o;
                    } else {
                        f4 rv = *(const f4*)(resid + rowoff + pt * 16);
                        f4 o;
                        #pragma unroll
                        for (int r = 0; r < 4; r++) o[r] = acc[pt][ot][r] + bi + rv[r];
                        *(f4*)((float*)Out + rowoff + pt * 16) = o;
                    }
                }
            }
        } else {
            #pragma unroll
            for (int pt = 0; pt < 4; pt++) {
                const int gp = gp0 + pt * 16 + lr;
                unsigned short* orow = (unsigned short*)Out + (size_t)gp * OCTOT + ocb + lg * 4;
                #pragma unroll
                for (int ot = 0; ot < 3; ot++) {
                    f4 bi4 = *(const f4*)&bias[ocb + ot * 16 + lg * 4];
                    us4 o;
                    #pragma unroll
                    for (int r = 0; r < 4; r++) o[r] = f2b(geluf(acc[pt][ot][r] + bi4[r]));
                    *(us4*)(orow + ot * 16) = o;
                }
            }
        }
    }
}

// ---------------------------------------------------------------------------
// Per-row (b, k-channel) max + log-sum-exp over all pixels. kv[b][384][px],
// k = channels 0..191.
// ---------------------------------------------------------------------------
__global__ __launch_bounds__(256) void krow_k(const unsigned short* __restrict__ kv,
                                              float* __restrict__ koff)
{
    int r = blockIdx.x;
    int b = r / 192, ch = r % 192;
    const unsigned short* Kp = kv + ((size_t)b * 384 + ch) * NPIX;
    int tid = threadIdx.x;
    float m = -1e30f, s = 0.f;
    for (int i = 0; i < 256; i++) {
        float v = b2f(Kp[tid + (size_t)i * 256]);
        if (v > m) { s = s * __expf(m - v) + 1.f; m = v; }
        else s += __expf(v - m);
    }
    __shared__ float ms[256], ss[256];
    ms[tid] = m; ss[tid] = s;
    __syncthreads();
    for (int off = 128; off > 0; off >>= 1) {
        if (tid < off) {
            float m2 = ms[tid + off], s2 = ss[tid + off];
            float M2 = fmaxf(ms[tid], m2);
            ss[tid] = ss[tid] * __expf(ms[tid] - M2) + s2 * __expf(m2 - M2);
            ms[tid] = M2;
        }
        __syncthreads();
    }
    if (tid == 0) koff[r] = ms[0] + logf(ss[0]);
}

__global__ void zero_k(float* __restrict__ p, int n)
{
    int i = blockIdx.x * 256 + threadIdx.x;
    if (i < n) p[i] = 0.f;
}

__global__ void cvt_k(const float* __restrict__ src, unsigned short* __restrict__ dst, int n)
{
    int i = blockIdx.x * 256 + threadIdx.x;
    if (i < n) dst[i] = f2b(src[i]);
}

// ---------------------------------------------------------------------------
// context: ctxT[b,h,d,c] = sum_n exp(k[c,n]-koff[c]) * v[d,n]
// kv[b][384][px]: k = 0..191, v = 192..383.
// ---------------------------------------------------------------------------
__global__ __launch_bounds__(64) void context_k(const unsigned short* __restrict__ kv,
                                                const float* __restrict__ koff,
                                                float* __restrict__ ctxT)
{
    int bid = blockIdx.x;
    int bh = bid >> 6, chunk = bid & 63;
    int b = bh >> 3, h = bh & 7;
    int lane = threadIdx.x, lr = lane & 15, lg = lane >> 4;
    size_t nbase = (size_t)chunk * 1024 + lg * 8;

    int c0 = h * 24 + lr;
    int c1 = h * 24 + 16 + lr;
    float ko0 = koff[b * 192 + c0];
    int i1 = b * 192 + c1; if (i1 > 775) i1 = 775;
    float ko1 = koff[i1];
    bool val1 = lr < 8;

    const unsigned short* k0p = kv + ((size_t)b * 384 + c0) * NPIX + nbase;
    const unsigned short* k1p = kv + ((size_t)b * 384 + (c1 > 191 ? 191 : c1)) * NPIX + nbase;
    const unsigned short* v0p = kv + ((size_t)b * 384 + 192 + h * 24 + lr) * NPIX + nbase;
    const unsigned short* v1p = kv + ((size_t)b * 384 + 192 + ((h * 24 + 16 + lr > 191) ? 191 : h * 24 + 16 + lr)) * NPIX + nbase;

    f4 acc[2][2];
    #pragma unroll
    for (int i = 0; i < 2; i++) for (int j = 0; j < 2; j++) acc[i][j] = (f4)0.0f;

    for (int s = 0; s < 32; s++) {
        int off = s * 32;
        s8 kr0 = *(const s8*)(k0p + off);
        s8 kr1 = *(const s8*)(k1p + off);
        s8 vr0 = *(const s8*)(v0p + off);
        s8 vr1 = *(const s8*)(v1p + off);
        s8 p0, p1;
        #pragma unroll
        for (int j = 0; j < 8; j++) {
            p0[j] = (short)f2b(__expf(b2f((unsigned short)kr0[j]) - ko0));
            p1[j] = val1 ? (short)f2b(__expf(b2f((unsigned short)kr1[j]) - ko1)) : (short)0;
        }
        acc[0][0] = __builtin_amdgcn_mfma_f32_16x16x32_bf16(p0, vr0, acc[0][0], 0, 0, 0);
        acc[0][1] = __builtin_amdgcn_mfma_f32_16x16x32_bf16(p0, vr1, acc[0][1], 0, 0, 0);
        acc[1][0] = __builtin_amdgcn_mfma_f32_16x16x32_bf16(p1, vr0, acc[1][0], 0, 0, 0);
        acc[1][1] = __builtin_amdgcn_mfma_f32_16x16x32_bf16(p1, vr1, acc[1][1], 0, 0, 0);
    }
    float* base = ctxT + (size_t)(b * 8 + h) * 1024;
    #pragma unroll
    for (int mt = 0; mt < 2; mt++)
        #pragma unroll
        for (int ct = 0; ct < 2; ct++)
            #pragma unroll
            for (int r = 0; r < 4; r++) {
                int c = mt * 16 + lg * 4 + r;
                int d = ct * 16 + lr;
                atomicAdd(base + d * 32 + c, acc[mt][ct][r]);
            }
}

// ---------------------------------------------------------------------------
// fused: q-softmax (from qT, in-register) -> ctx apply -> out-proj GEMM
//        -> + x resid -> x2 (f32) -> LN2 -> xnt bf16 [px][192]
// LDS: outp 25.6KB + lnS/lnQ 2KB (E eliminated).
// ---------------------------------------------------------------------------
__global__ __launch_bounds__(256) void qctx_proj_k(
    const unsigned short* __restrict__ qT, const float* __restrict__ ctxT,
    const unsigned short* __restrict__ outWb, const float* __restrict__ outBias,
    const float* __restrict__ xres, float* __restrict__ Out,
    const float* __restrict__ ln2g, const float* __restrict__ ln2b,
    unsigned short* __restrict__ xnt)
{
    __shared__ unsigned short outp[64][200];
    __shared__ float lnS[4][64], lnQ[4][64];

    int tid = threadIdx.x, bid = blockIdx.x;
    int b = bid >> 10, n0 = (bid & 1023) * 64;
    int wave = tid >> 6, lane = tid & 63, lr = lane & 15, lg = lane >> 4;
    const size_t bpx = (size_t)b << 16;

    #pragma unroll
    for (int hh = 0; hh < 2; hh++) {
        int h = wave * 2 + hh;
        s8 af[2];
        #pragma unroll
        for (int mt = 0; mt < 2; mt++) {
            const float* cp = ctxT + ((size_t)(b * 8 + h) * 32 + mt * 16 + lr) * 32 + lg * 8;
            s8 a;
            #pragma unroll
            for (int j = 0; j < 8; j++) a[j] = (short)f2b(cp[j]);
            af[mt] = a;
        }
        #pragma unroll
        for (int nt = 0; nt < 4; nt++) {
            int n = nt * 16 + lr;
            s8 bfq = (s8)0;
            float sown = 0.f;
            if (lg < 3) {
                us8 qv = *(const us8*)(qT + (bpx + n0 + n) * 192 + h * 24 + lg * 8);
                #pragma unroll
                for (int j = 0; j < 8; j++) {
                    float e = __expf(b2f((unsigned short)qv[j]));
                    sown += e;
                    bfq[j] = (short)f2b(e);
                }
            }
            float den = sown;
            den += __shfl_xor(den, 16);
            den += __shfl_xor(den, 32);
            f4 z = (f4)0.0f;
            f4 d0 = __builtin_amdgcn_mfma_f32_16x16x32_bf16(af[0], bfq, z, 0, 0, 0);
            f4 d1 = __builtin_amdgcn_mfma_f32_16x16x32_bf16(af[1], bfq, z, 0, 0, 0);
            float sinv = 1.0f / den;
            us4 w0;
            #pragma unroll
            for (int r = 0; r < 4; r++) w0[r] = f2b(d0[r] * sinv);
            *(us4*)&outp[n][h * 24 + lg * 4] = w0;
            if (lg < 2) {
                us4 w1;
                #pragma unroll
                for (int r = 0; r < 4; r++) w1[r] = f2b(d1[r] * sinv);
                *(us4*)&outp[n][h * 24 + 16 + lg * 4] = w1;
            }
        }
    }
    __syncthreads();

    f4 acc[3][4];
    #pragma unroll
    for (int i = 0; i < 3; i++) for (int j = 0; j < 4; j++) acc[i][j] = (f4)0.0f;
    #pragma unroll
    for (int k0 = 0; k0 < 192; k0 += 32) {
        s8 bf[4];
        #pragma unroll
        for (int nt = 0; nt < 4; nt++)
            bf[nt] = *(const s8*)&outp[nt * 16 + lr][k0 + lg * 8];
        #pragma unroll
        for (int mt = 0; mt < 3; mt++) {
            s8 af = *(const s8*)&outWb[(size_t)(wave * 48 + mt * 16 + lr) * 192 + k0 + lg * 8];
            #pragma unroll
            for (int nt = 0; nt < 4; nt++)
                acc[mt][nt] = __builtin_amdgcn_mfma_f32_16x16x32_bf16(af, bf[nt], acc[mt][nt], 0, 0, 0);
        }
    }

    // x2 = proj + bias + x; partial LN sums per column
    float s4[4] = {0.f, 0.f, 0.f, 0.f}, q4[4] = {0.f, 0.f, 0.f, 0.f};
    #pragma unroll
    for (int mt = 0; mt < 3; mt++)
        #pragma unroll
        for (int nt = 0; nt < 4; nt++) {
            int col = n0 + nt * 16 + lr;
            #pragma unroll
            for (int r = 0; r < 4; r++) {
                int row = wave * 48 + mt * 16 + lg * 4 + r;
                size_t off = ((size_t)b * 192 + row) * NPIX + col;
                float v = acc[mt][nt][r] + outBias[row] + xres[off];
                acc[mt][nt][r] = v;
                Out[off] = v;
                s4[nt] += v; q4[nt] += v * v;
            }
        }
    #pragma unroll
    for (int nt = 0; nt < 4; nt++) {
        s4[nt] += __shfl_xor(s4[nt], 16); s4[nt] += __shfl_xor(s4[nt], 32);
        q4[nt] += __shfl_xor(q4[nt], 16); q4[nt] += __shfl_xor(q4[nt], 32);
    }
    if (lg == 0) {
        #pragma unroll
        for (int nt = 0; nt < 4; nt++) {
            lnS[wave][nt * 16 + lr] = s4[nt];
            lnQ[wave][nt * 16 + lr] = q4[nt];
        }
    }
    __syncthreads();

    float mus[4], rss[4];
    #pragma unroll
    for (int nt = 0; nt < 4; nt++) {
        int c16 = nt * 16 + lr;
        float S = lnS[0][c16] + lnS[1][c16] + lnS[2][c16] + lnS[3][c16];
        float Qq = lnQ[0][c16] + lnQ[1][c16] + lnQ[2][c16] + lnQ[3][c16];
        float mu = S * (1.0f / 192.0f);
        float var = Qq * (1.0f / 192.0f) - mu * mu;
        mus[nt] = mu; rss[nt] = rsqrtf(var + 1e-5f);
    }
    #pragma unroll
    for (int mt = 0; mt < 3; mt++) {
        int rb = wave * 48 + mt * 16 + lg * 4;
        f4 g4v = *(const f4*)&ln2g[rb];
        f4 b4v = *(const f4*)&ln2b[rb];
        #pragma unroll
        for (int nt = 0; nt < 4; nt++) {
            int gp = (b << 16) + n0 + nt * 16 + lr;
            us4 o;
            #pragma unroll
            for (int r = 0; r < 4; r++) {
                float xn = (acc[mt][nt][r] - mus[nt]) * rss[nt] * g4v[r] + b4v[r];
                o[r] = f2b(xn);
            }
            *(us4*)(xnt + (size_t)gp * 192 + rb) = o;
        }
    }
}

// ---------------------------------------------------------------------------
// depthwise 3x3 + gelu on [px][384], row-streamed LDS ring (16.9KB)
// ---------------------------------------------------------------------------
__global__ __launch_bounds__(256) void dwconv_t2_k(
    const unsigned short* __restrict__ h1t, const float* __restrict__ w,
    const float* __restrict__ bias, unsigned short* __restrict__ h2t)
{
    __shared__ unsigned short ring[4 * 4 * 66 * 8];   // 16.9 KB
    const int bz = blockIdx.z;                        // b*12 + cbgrp
    const int b = bz / 12, cb = (bz % 12) * 32;
    const int y0 = blockIdx.y * 8, x0 = blockIdx.x * 64;
    const int tid = threadIdx.x;
    const int x = tid & 63, cg = tid >> 6;
    const int c0 = cb + cg * 8;
    const size_t bbase = (size_t)b << 16;

    float wr[9][8], bi[8];
    #pragma unroll
    for (int i = 0; i < 8; i++) {
        #pragma unroll
        for (int j = 0; j < 9; j++) wr[j][i] = rfl(w[(c0 + i) * 9 + j]);
        bi[i] = rfl(bias[c0 + i]);
    }

    const us8 zz = {0, 0, 0, 0, 0, 0, 0, 0};

    auto stage_row = [&](int gy, int s) {
        unsigned short* ldsrow = &ring[((s * 4 + cg) * 66) * 8];
        if (gy >= 0 && gy <= 255) {
            us8 ev = zz;
            if (x == 0 && x0 > 0)
                ev = *(const us8*)(h1t + (bbase + gy * 256 + x0 - 1) * 384 + c0);
            if (x == 63 && x0 + 64 < 256)
                ev = *(const us8*)(h1t + (bbase + gy * 256 + x0 + 64) * 384 + c0);
            gload_lds16(h1t + (bbase + gy * 256 + x0 + x) * 384 + c0,
                        ldsrow + (1 + x) * 8);
            if (x == 0)  *(us8*)&ldsrow[0]      = ev;
            if (x == 63) *(us8*)&ldsrow[65 * 8] = ev;
        } else {
            *(us8*)&ldsrow[(1 + x) * 8] = zz;
            if (x == 0)  *(us8*)&ldsrow[0]      = zz;
            if (x == 63) *(us8*)&ldsrow[65 * 8] = zz;
        }
    };

    stage_row(y0 - 1, 0);
    stage_row(y0,     1);
    stage_row(y0 + 1, 2);
    __syncthreads();

    #pragma unroll
    for (int y = 0; y < 8; y++) {
        if (y < 7) stage_row(y0 + y + 2, (y + 3) & 3);

        float a[8];
        #pragma unroll
        for (int i = 0; i < 8; i++) a[i] = bi[i];
        #pragma unroll
        for (int t = 0; t < 3; t++) {
            const int s = (y + t) & 3;
            const unsigned short* rp = &ring[((s * 4 + cg) * 66 + x) * 8];
            us8 L = *(const us8*)(rp);
            us8 C = *(const us8*)(rp + 8);
            us8 R = *(const us8*)(rp + 16);
            #pragma unroll
            for (int i = 0; i < 8; i++) {
                a[i] += wr[t * 3 + 0][i] * b2f(L[i]);
                a[i] += wr[t * 3 + 1][i] * b2f(C[i]);
                a[i] += wr[t * 3 + 2][i] * b2f(R[i]);
            }
        }
        us8 ov;
        #pragma unroll
        for (int i = 0; i < 8; i++) ov[i] = f2b(gelu_t(a[i]));
        *(us8*)(h2t + (bbase + (y0 + y) * 256 + x0 + x) * 384 + c0) = ov;

        __syncthreads();
    }
}

// ---------------------------------------------------------------------------
extern "C" void kernel_launch(void* const* d_in, const int* in_sizes, int n_in,
                              void* d_out, int out_size, void* d_ws, size_t ws_size,
                              hipStream_t stream)
{
    const float* x    = (const float*)d_in[0];
    const float* ln1g = (const float*)d_in[1];
    const float* ln1b = (const float*)d_in[2];
    const float* qkvw = (const float*)d_in[3];
    const float* qkvb = (const float*)d_in[4];
    const float* outw = (const float*)d_in[5];
    const float* outb = (const float*)d_in[6];
    const float* ln2g = (const float*)d_in[7];
    const float* ln2b = (const float*)d_in[8];
    const float* w1   = (const float*)d_in[9];
    const float* b1   = (const float*)d_in[10];
    const float* dww  = (const float*)d_in[11];
    const float* dwb  = (const float*)d_in[12];
    const float* w2   = (const float*)d_in[13];
    const float* b2   = (const float*)d_in[14];
    float* out = (float*)d_out;

    char* ws = (char*)d_ws;
    // lifetimes: kv (step2-4) shares [0,192MiB) with h1t (step6-7);
    // qT (step2-5) at [192,288MiB) shares with h2t (step7-8);
    // xnt (steps 1-2, 5-6) at [288,384MiB).
    unsigned short* kv  = (unsigned short*)ws;                            // [0,192MiB) [b][384][px]
    unsigned short* h1t = (unsigned short*)ws;                            // [0,192MiB) [px][384]
    unsigned short* h2t = (unsigned short*)(ws + (size_t)201326592);      // [192,384MiB) [px][384]
    unsigned short* qT  = (unsigned short*)(ws + (size_t)201326592);      // [192,288MiB) [px][192]
    unsigned short* xnt = (unsigned short*)(ws + (size_t)301989888);      // [288,384MiB) [px][192]
    size_t off = (size_t)402653184;
    float* koff = (float*)(ws + off); off += 4096;
    float* ctxT = (float*)(ws + off); off += 131072;
    unsigned short* qkvwb = (unsigned short*)(ws + off); off += 221184;
    unsigned short* outwb = (unsigned short*)(ws + off); off += 73728 * 2;
    unsigned short* w1b   = (unsigned short*)(ws + off); off += 147456;
    unsigned short* w2b   = (unsigned short*)(ws + off); off += 147456;

    cvt_k<<<(110592 + 255) / 256, 256, 0, stream>>>(qkvw, qkvwb, 110592);
    cvt_k<<<(36864 + 255) / 256, 256, 0, stream>>>(outw, outwb, 36864);
    cvt_k<<<(73728 + 255) / 256, 256, 0, stream>>>(w1, w1b, 73728);
    cvt_k<<<(73728 + 255) / 256, 256, 0, stream>>>(w2, w2b, 73728);

    // 1) LN1 + transpose -> xnt
    lnt_k<<<1024, 256, 0, stream>>>(x, ln1g, ln1b, xnt);

    // 2) qkv GEMM: q -> qT[px][192] (transposed), k/v -> kv[b][384][px]
    gemm2_k<192, 3, 3><<<4096, 256, 0, stream>>>(xnt, qkvwb, qkvb, nullptr, kv, 384, qT);

    // 3) k-row softmax offsets
    krow_k<<<768, 256, 0, stream>>>(kv, koff);

    // 4) context accumulation
    zero_k<<<128, 256, 0, stream>>>(ctxT, 32768);
    context_k<<<2048, 64, 0, stream>>>(kv, koff, ctxT);

    // 5) q softmax (register) + ctx + proj + resid -> x2 (d_out) + LN2 -> xnt
    qctx_proj_k<<<4096, 256, 0, stream>>>(qT, ctxT, outwb, outb, x, out,
                                          ln2g, ln2b, xnt);

    // 6) w1 GEMM + gelu -> h1t [px][384]
    gemm2_k<192, 1, 2><<<4096, 256, 0, stream>>>(xnt, w1b, b1, nullptr, h1t, 384, nullptr);

    // 7) depthwise 3x3 + gelu, row-streamed ring -> h2t [px][384]
    dwconv_t2_k<<<dim3(4, 32, 48), 256, 0, stream>>>(h1t, dww, dwb, h2t);

    // 8) w2 GEMM + bias + x2 residual -> d_out f32
    gemm2_k<384, 2, 1><<<4096, 256, 0, stream>>>(h2t, w2b, b2, out, out, 192, nullptr);
}

// Round 10
// 1048.373 us; speedup vs baseline: 1.3563x; 1.1302x over previous
//
#include <hip/hip_runtime.h>
#include <math.h>

typedef __attribute__((ext_vector_type(8))) short s8;
typedef __attribute__((ext_vector_type(8))) unsigned short us8;
typedef __attribute__((ext_vector_type(4))) float f4;
typedef __attribute__((ext_vector_type(4))) unsigned short us4;
typedef __attribute__((ext_vector_type(4))) unsigned int u32x4;

#define DEVI __device__ __forceinline__

static const int NPIX = 65536;   // 256*256

DEVI float b2f(unsigned short u) {
    unsigned int v = ((unsigned int)u) << 16;
    float f; __builtin_memcpy(&f, &v, 4); return f;
}
DEVI unsigned short f2b(float f) {
    unsigned int u; __builtin_memcpy(&u, &f, 4);
    unsigned int r = (u + 0x7FFFu + ((u >> 16) & 1u)) >> 16;
    return (unsigned short)r;
}
DEVI float geluf(float x) { return 0.5f * x * (1.0f + erff(x * 0.70710678118f)); }
DEVI float gelu_t(float x) {
    float z = 1.595769122f * (x + 0.044715f * x * x * x);
    return x * __builtin_amdgcn_rcpf(1.0f + __expf(-z));
}
DEVI float rfl(float v) {
    int i; __builtin_memcpy(&i, &v, 4);
    i = __builtin_amdgcn_readfirstlane(i);
    float o; __builtin_memcpy(&o, &i, 4); return o;
}

DEVI void gload_lds16(const unsigned short* g, unsigned short* l) {
    __builtin_amdgcn_global_load_lds(
        (const __attribute__((address_space(1))) unsigned int*)g,
        (__attribute__((address_space(3))) unsigned int*)l,
        16, 0, 0);
}

// ---------------------------------------------------------------------------
// LayerNorm + transpose: x f32 [b][192][px] -> xnt bf16 [b*px][192]
// ---------------------------------------------------------------------------
__global__ __launch_bounds__(256) void lnt_k(const float* __restrict__ X,
                                             const float* __restrict__ gw,
                                             const float* __restrict__ gb,
                                             unsigned short* __restrict__ Out)
{
    const int i = blockIdx.x * 256 + threadIdx.x;
    const int b = i >> 16, px = i & 65535;
    const float* xp = X + (size_t)b * 192 * NPIX + px;

    unsigned int pk[96];
    float sum = 0.f, ssq = 0.f;
    #pragma unroll
    for (int c = 0; c < 192; c++) {
        float v = xp[(size_t)c * NPIX];
        sum += v; ssq += v * v;
        unsigned int h = f2b(v);
        if (c & 1) pk[c >> 1] |= h << 16;
        else       pk[c >> 1] = h;
    }
    float mu = sum * (1.0f / 192.0f);
    float var = ssq * (1.0f / 192.0f) - mu * mu;
    float rs = rsqrtf(var + 1e-5f);

    #pragma unroll
    for (int c2 = 0; c2 < 96; c2++) {
        int c = c2 * 2;
        float lo = b2f((unsigned short)(pk[c2] & 0xFFFF));
        float hi = b2f((unsigned short)(pk[c2] >> 16));
        lo = (lo - mu) * rs * gw[c] + gb[c];
        hi = (hi - mu) * rs * gw[c + 1] + gb[c + 1];
        pk[c2] = (unsigned int)f2b(lo) | ((unsigned int)f2b(hi) << 16);
    }
    u32x4* dst = (u32x4*)(Out + (size_t)i * 192);
    #pragma unroll
    for (int j = 0; j < 6; j++) {
        u32x4 v = { pk[4 * j], pk[4 * j + 1], pk[4 * j + 2], pk[4 * j + 3] };
        dst[j] = v;
    }
}

// ---------------------------------------------------------------------------
// Staged GEMM: block = 64 px; X staged once in LDS; batched W preload.
// MODE 0: out bf16 [b][OCTOT][px], bias
// MODE 1: out bf16 [gp][OCTOT], bias+gelu            (w1 -> h1t)
// MODE 2: out f32  [b][OCTOT][px], bias + f32 resid  (w2, small-ws path)
// MODE 3: qkv fused: cn==0 -> qT[gp][192]; cn=1,2 -> kv[b][384][px]
// MODE 4: out f32  [b][OCTOT][px], bias + bf16 resid (w2, big-ws path)
// ---------------------------------------------------------------------------
template<int K, int MODE, int NCHUNK>
__global__ __launch_bounds__(256) void gemm2_k(
    const unsigned short* __restrict__ X, const unsigned short* __restrict__ Wb,
    const float* __restrict__ bias, const void* __restrict__ resid,
    void* __restrict__ Out, int OCTOT, unsigned short* __restrict__ qT)
{
    constexpr int ROWS = 64;
    constexpr int CPR = K / 8;
    __shared__ unsigned short tile[ROWS * K];

    const int tid = threadIdx.x;
    const int wave = tid >> 6, lane = tid & 63;
    const int lr = lane & 15, lg = lane >> 4;
    const int gp0 = blockIdx.x * ROWS;

    constexpr int CALLS = (ROWS * CPR) / 256;
    {
        const unsigned short* Xb = X + (size_t)gp0 * K;
        #pragma unroll
        for (int j = 0; j < CALLS; j++) {
            int ci = (wave * CALLS + j) * 64 + lane;
            int row = (int)((unsigned)ci / (unsigned)CPR);
            int c = ci - row * CPR;
            int csw = (c & ~7) | ((c ^ row) & 7);
            gload_lds16(Xb + (size_t)row * K + csw * 8, &tile[ci * 8]);
        }
    }

    __syncthreads();

    const int xr = lr & 7;
    const int b = gp0 >> 16;
    const int pxb = gp0 & 65535;

    #pragma unroll
    for (int cn = 0; cn < NCHUNK; cn++) {
        const int ocb = cn * 192 + wave * 48;
        const unsigned short* wrow = Wb + (size_t)(ocb + lr) * K + lg * 8;
        const bool swapped = (MODE == 1) || (MODE == 3 && cn == 0);

        f4 acc[4][3];
        #pragma unroll
        for (int i = 0; i < 4; i++)
            #pragma unroll
            for (int j = 0; j < 3; j++) acc[i][j] = (f4)0.0f;

        #pragma unroll
        for (int kb = 0; kb < K; kb += 192) {
            s8 wf[3][6];
            #pragma unroll
            for (int ot = 0; ot < 3; ot++)
                #pragma unroll
                for (int kk = 0; kk < 6; kk++)
                    wf[ot][kk] = *(const s8*)(wrow + (size_t)ot * 16 * K + kb + kk * 32);

            #pragma unroll
            for (int kk = 0; kk < 6; kk++) {
                const int k0 = kb + kk * 32;
                const int kc = (k0 >> 3) + lg;
                const int kcs = (kc & ~7) | ((kc ^ xr) & 7);
                s8 a[4];
                #pragma unroll
                for (int pt = 0; pt < 4; pt++) {
                    int row = pt * 16 + lr;
                    a[pt] = *(const s8*)&tile[(row * CPR + kcs) * 8];
                }
                #pragma unroll
                for (int ot = 0; ot < 3; ot++)
                    #pragma unroll
                    for (int pt = 0; pt < 4; pt++)
                        acc[pt][ot] = swapped
                            ? __builtin_amdgcn_mfma_f32_16x16x32_bf16(wf[ot][kk], a[pt], acc[pt][ot], 0, 0, 0)
                            : __builtin_amdgcn_mfma_f32_16x16x32_bf16(a[pt], wf[ot][kk], acc[pt][ot], 0, 0, 0);
            }
        }

        if (MODE == 3 && cn == 0) {
            #pragma unroll
            for (int pt = 0; pt < 4; pt++) {
                const int gp = gp0 + pt * 16 + lr;
                unsigned short* orow = qT + (size_t)gp * 192 + wave * 48 + lg * 4;
                #pragma unroll
                for (int ot = 0; ot < 3; ot++) {
                    f4 bi4 = *(const f4*)&bias[wave * 48 + ot * 16 + lg * 4];
                    us4 o;
                    #pragma unroll
                    for (int r = 0; r < 4; r++) o[r] = f2b(acc[pt][ot][r] + bi4[r]);
                    *(us4*)(orow + ot * 16) = o;
                }
            }
        } else if (MODE == 3) {
            #pragma unroll
            for (int ot = 0; ot < 3; ot++) {
                const int oc = ocb + ot * 16 + lr;
                const float bi = bias[oc];
                const size_t rowoff = ((size_t)b * 384 + (oc - 192)) * NPIX + pxb + lg * 4;
                #pragma unroll
                for (int pt = 0; pt < 4; pt++) {
                    us4 o;
                    #pragma unroll
                    for (int r = 0; r < 4; r++) o[r] = f2b(acc[pt][ot][r] + bi);
                    *(us4*)((unsigned short*)Out + rowoff + pt * 16) = o;
                }
            }
        } else if (MODE == 0 || MODE == 2 || MODE == 4) {
            #pragma unroll
            for (int ot = 0; ot < 3; ot++) {
                const int oc = ocb + ot * 16 + lr;
                const float bi = bias[oc];
                const size_t rowoff = ((size_t)b * OCTOT + oc) * NPIX + pxb + lg * 4;
                #pragma unroll
                for (int pt = 0; pt < 4; pt++) {
                    if (MODE == 0) {
                        us4 o;
                        #pragma unroll
                        for (int r = 0; r < 4; r++) o[r] = f2b(acc[pt][ot][r] + bi);
                        *(us4*)((unsigned short*)Out + rowoff + pt * 16) = o;
                    } else if (MODE == 2) {
                        f4 rv = *(const f4*)((const float*)resid + rowoff + pt * 16);
                        f4 o;
                        #pragma unroll
                        for (int r = 0; r < 4; r++) o[r] = acc[pt][ot][r] + bi + rv[r];
                        *(f4*)((float*)Out + rowoff + pt * 16) = o;
                    } else {
                        us4 rv = *(const us4*)((const unsigned short*)resid + rowoff + pt * 16);
                        f4 o;
                        #pragma unroll
                        for (int r = 0; r < 4; r++) o[r] = acc[pt][ot][r] + bi + b2f(rv[r]);
                        *(f4*)((float*)Out + rowoff + pt * 16) = o;
                    }
                }
            }
        } else {
            #pragma unroll
            for (int pt = 0; pt < 4; pt++) {
                const int gp = gp0 + pt * 16 + lr;
                unsigned short* orow = (unsigned short*)Out + (size_t)gp * OCTOT + ocb + lg * 4;
                #pragma unroll
                for (int ot = 0; ot < 3; ot++) {
                    f4 bi4 = *(const f4*)&bias[ocb + ot * 16 + lg * 4];
                    us4 o;
                    #pragma unroll
                    for (int r = 0; r < 4; r++) o[r] = f2b(geluf(acc[pt][ot][r] + bi4[r]));
                    *(us4*)(orow + ot * 16) = o;
                }
            }
        }
    }
}

// ---------------------------------------------------------------------------
// Per-row max + log-sum-exp; 2 independent online chains for ILP.
// ---------------------------------------------------------------------------
__global__ __launch_bounds__(256) void krow_k(const unsigned short* __restrict__ kv,
                                              float* __restrict__ koff)
{
    int r = blockIdx.x;
    int b = r / 192, ch = r % 192;
    const unsigned short* Kp = kv + ((size_t)b * 384 + ch) * NPIX;
    int tid = threadIdx.x;
    float m0 = -1e30f, s0 = 0.f, m1 = -1e30f, s1 = 0.f;
    for (int i = 0; i < 128; i++) {
        float v0 = b2f(Kp[tid + (size_t)(2 * i) * 256]);
        float v1 = b2f(Kp[tid + (size_t)(2 * i + 1) * 256]);
        if (v0 > m0) { s0 = s0 * __expf(m0 - v0) + 1.f; m0 = v0; }
        else s0 += __expf(v0 - m0);
        if (v1 > m1) { s1 = s1 * __expf(m1 - v1) + 1.f; m1 = v1; }
        else s1 += __expf(v1 - m1);
    }
    float m = fmaxf(m0, m1);
    float s = s0 * __expf(m0 - m) + s1 * __expf(m1 - m);
    __shared__ float ms[256], ss[256];
    ms[tid] = m; ss[tid] = s;
    __syncthreads();
    for (int off = 128; off > 0; off >>= 1) {
        if (tid < off) {
            float m2 = ms[tid + off], s2 = ss[tid + off];
            float M2 = fmaxf(ms[tid], m2);
            ss[tid] = ss[tid] * __expf(ms[tid] - M2) + s2 * __expf(m2 - M2);
            ms[tid] = M2;
        }
        __syncthreads();
    }
    if (tid == 0) koff[r] = ms[0] + logf(ss[0]);
}

__global__ void zero_k(float* __restrict__ p, int n)
{
    int i = blockIdx.x * 256 + threadIdx.x;
    if (i < n) p[i] = 0.f;
}

__global__ void cvt_k(const float* __restrict__ src, unsigned short* __restrict__ dst, int n)
{
    int i = blockIdx.x * 256 + threadIdx.x;
    if (i < n) dst[i] = f2b(src[i]);
}

// ---------------------------------------------------------------------------
// context: 256-thr blocks; 4 n-chunks merged in LDS; atomics /4.
// ---------------------------------------------------------------------------
__global__ __launch_bounds__(256) void context_k(const unsigned short* __restrict__ kv,
                                                 const float* __restrict__ koff,
                                                 float* __restrict__ ctxT)
{
    __shared__ float red[4][64][16];      // 16 KB
    int bid = blockIdx.x;                 // 512 blocks
    int bh = bid >> 4, cgrp = bid & 15;
    int b = bh >> 3, h = bh & 7;
    int tid = threadIdx.x;
    int wave = tid >> 6, lane = tid & 63, lr = lane & 15, lg = lane >> 4;
    int chunk = cgrp * 4 + wave;
    size_t nbase = (size_t)chunk * 1024 + lg * 8;

    int c0 = h * 24 + lr;
    int c1 = h * 24 + 16 + lr;
    float ko0 = koff[b * 192 + c0];
    int i1 = b * 192 + c1; if (i1 > 767) i1 = 767;
    float ko1 = koff[i1];
    bool val1 = lr < 8;

    const unsigned short* k0p = kv + ((size_t)b * 384 + c0) * NPIX + nbase;
    const unsigned short* k1p = kv + ((size_t)b * 384 + (c1 > 191 ? 191 : c1)) * NPIX + nbase;
    const unsigned short* v0p = kv + ((size_t)b * 384 + 192 + h * 24 + lr) * NPIX + nbase;
    const unsigned short* v1p = kv + ((size_t)b * 384 + 192 + ((h * 24 + 16 + lr > 191) ? 191 : h * 24 + 16 + lr)) * NPIX + nbase;

    f4 acc[2][2];
    #pragma unroll
    for (int i = 0; i < 2; i++) for (int j = 0; j < 2; j++) acc[i][j] = (f4)0.0f;

    for (int s = 0; s < 32; s++) {
        int off = s * 32;
        s8 kr0 = *(const s8*)(k0p + off);
        s8 kr1 = *(const s8*)(k1p + off);
        s8 vr0 = *(const s8*)(v0p + off);
        s8 vr1 = *(const s8*)(v1p + off);
        s8 p0, p1;
        #pragma unroll
        for (int j = 0; j < 8; j++) {
            p0[j] = (short)f2b(__expf(b2f((unsigned short)kr0[j]) - ko0));
            p1[j] = val1 ? (short)f2b(__expf(b2f((unsigned short)kr1[j]) - ko1)) : (short)0;
        }
        acc[0][0] = __builtin_amdgcn_mfma_f32_16x16x32_bf16(p0, vr0, acc[0][0], 0, 0, 0);
        acc[0][1] = __builtin_amdgcn_mfma_f32_16x16x32_bf16(p0, vr1, acc[0][1], 0, 0, 0);
        acc[1][0] = __builtin_amdgcn_mfma_f32_16x16x32_bf16(p1, vr0, acc[1][0], 0, 0, 0);
        acc[1][1] = __builtin_amdgcn_mfma_f32_16x16x32_bf16(p1, vr1, acc[1][1], 0, 0, 0);
    }
    #pragma unroll
    for (int mt = 0; mt < 2; mt++)
        #pragma unroll
        for (int ct = 0; ct < 2; ct++)
            #pragma unroll
            for (int r = 0; r < 4; r++)
                red[wave][lane][mt * 8 + ct * 4 + r] = acc[mt][ct][r];
    __syncthreads();

    if (wave == 0) {
        float* base = ctxT + (size_t)(b * 8 + h) * 1024;
        #pragma unroll
        for (int j = 0; j < 16; j++) {
            float sum = red[0][lane][j] + red[1][lane][j] + red[2][lane][j] + red[3][lane][j];
            int mt = j >> 3, ct = (j >> 2) & 1, r = j & 3;
            int c = mt * 16 + lg * 4 + r;
            int d = ct * 16 + lr;
            atomicAdd(base + d * 32 + c, sum);
        }
    }
}

// ---------------------------------------------------------------------------
// fused qctx: q-softmax (register) -> ctx apply -> proj (px-on-reg-axis)
//   -> +x resid (f4) -> x2 out (f32 f4 stores, or bf16 x2b if BIGWS)
//   -> LN2 -> xnt via LDS bounce (us8 stores)
// ---------------------------------------------------------------------------
template<bool BIGWS>
__global__ __launch_bounds__(256) void qctx_proj_k(
    const unsigned short* __restrict__ qT, const float* __restrict__ ctxT,
    const unsigned short* __restrict__ outWb, const float* __restrict__ outBias,
    const float* __restrict__ xres, float* __restrict__ Out,
    unsigned short* __restrict__ x2b,
    const float* __restrict__ ln2g, const float* __restrict__ ln2b,
    unsigned short* __restrict__ xnt)
{
    __shared__ unsigned short outp[64][200];
    __shared__ float lnS[4][64], lnQ[4][64];

    int tid = threadIdx.x, bid = blockIdx.x;
    int b = bid >> 10, n0 = (bid & 1023) * 64;
    int wave = tid >> 6, lane = tid & 63, lr = lane & 15, lg = lane >> 4;
    const size_t bpx = (size_t)b << 16;

    // phase 1: q softmax + ctx apply -> outp[px][192]
    #pragma unroll
    for (int hh = 0; hh < 2; hh++) {
        int h = wave * 2 + hh;
        s8 cf[2];
        #pragma unroll
        for (int mt = 0; mt < 2; mt++) {
            const float* cp = ctxT + ((size_t)(b * 8 + h) * 32 + mt * 16 + lr) * 32 + lg * 8;
            s8 a;
            #pragma unroll
            for (int j = 0; j < 8; j++) a[j] = (short)f2b(cp[j]);
            cf[mt] = a;
        }
        #pragma unroll
        for (int nt = 0; nt < 4; nt++) {
            int n = nt * 16 + lr;
            s8 bfq = (s8)0;
            float sown = 0.f;
            if (lg < 3) {
                us8 qv = *(const us8*)(qT + (bpx + n0 + n) * 192 + h * 24 + lg * 8);
                #pragma unroll
                for (int j = 0; j < 8; j++) {
                    float e = __expf(b2f((unsigned short)qv[j]));
                    sown += e;
                    bfq[j] = (short)f2b(e);
                }
            }
            float den = sown;
            den += __shfl_xor(den, 16);
            den += __shfl_xor(den, 32);
            f4 z = (f4)0.0f;
            f4 d0 = __builtin_amdgcn_mfma_f32_16x16x32_bf16(cf[0], bfq, z, 0, 0, 0);
            f4 d1 = __builtin_amdgcn_mfma_f32_16x16x32_bf16(cf[1], bfq, z, 0, 0, 0);
            float sinv = 1.0f / den;
            us4 w0;
            #pragma unroll
            for (int r = 0; r < 4; r++) w0[r] = f2b(d0[r] * sinv);
            *(us4*)&outp[n][h * 24 + lg * 4] = w0;
            if (lg < 2) {
                us4 w1;
                #pragma unroll
                for (int r = 0; r < 4; r++) w1[r] = f2b(d1[r] * sinv);
                *(us4*)&outp[n][h * 24 + 16 + lg * 4] = w1;
            }
        }
    }
    __syncthreads();

    // proj GEMM, swapped: acc[pt][ot] = mfma(px-frag, W-frag)
    // -> px = n0 + pt*16 + lg*4 + r ; oc = wave*48 + ot*16 + lr
    f4 acc[4][3];
    #pragma unroll
    for (int i = 0; i < 4; i++) for (int j = 0; j < 3; j++) acc[i][j] = (f4)0.0f;
    #pragma unroll
    for (int k0 = 0; k0 < 192; k0 += 32) {
        s8 bf[4];
        #pragma unroll
        for (int pt = 0; pt < 4; pt++)
            bf[pt] = *(const s8*)&outp[pt * 16 + lr][k0 + lg * 8];
        #pragma unroll
        for (int ot = 0; ot < 3; ot++) {
            s8 af = *(const s8*)&outWb[(size_t)(wave * 48 + ot * 16 + lr) * 192 + k0 + lg * 8];
            #pragma unroll
            for (int pt = 0; pt < 4; pt++)
                acc[pt][ot] = __builtin_amdgcn_mfma_f32_16x16x32_bf16(bf[pt], af, acc[pt][ot], 0, 0, 0);
        }
    }

    // epilogue: x2 = proj + bias + x; per-px LN partials
    float sP[4][4], qP[4][4];
    #pragma unroll
    for (int pt = 0; pt < 4; pt++)
        #pragma unroll
        for (int r = 0; r < 4; r++) { sP[pt][r] = 0.f; qP[pt][r] = 0.f; }

    #pragma unroll
    for (int ot = 0; ot < 3; ot++) {
        const int oc = wave * 48 + ot * 16 + lr;
        const float bi = outBias[oc];
        const size_t rowbase = ((size_t)b * 192 + oc) * NPIX + n0 + lg * 4;
        #pragma unroll
        for (int pt = 0; pt < 4; pt++) {
            f4 rv = *(const f4*)(xres + rowbase + pt * 16);
            f4 v;
            #pragma unroll
            for (int r = 0; r < 4; r++) {
                v[r] = acc[pt][ot][r] + bi + rv[r];
                sP[pt][r] += v[r]; qP[pt][r] += v[r] * v[r];
            }
            acc[pt][ot] = v;
            if (BIGWS) {
                us4 o;
                #pragma unroll
                for (int r = 0; r < 4; r++) o[r] = f2b(v[r]);
                *(us4*)(x2b + rowbase + pt * 16) = o;
            } else {
                *(f4*)(Out + rowbase + pt * 16) = v;
            }
        }
    }
    // reduce over lr (lane bits 0..3)
    #pragma unroll
    for (int pt = 0; pt < 4; pt++)
        #pragma unroll
        for (int r = 0; r < 4; r++) {
            float s = sP[pt][r], q = qP[pt][r];
            s += __shfl_xor(s, 1); s += __shfl_xor(s, 2);
            s += __shfl_xor(s, 4); s += __shfl_xor(s, 8);
            q += __shfl_xor(q, 1); q += __shfl_xor(q, 2);
            q += __shfl_xor(q, 4); q += __shfl_xor(q, 8);
            sP[pt][r] = s; qP[pt][r] = q;
        }
    if (lr == 0) {
        #pragma unroll
        for (int pt = 0; pt < 4; pt++)
            #pragma unroll
            for (int r = 0; r < 4; r++) {
                lnS[wave][pt * 16 + lg * 4 + r] = sP[pt][r];
                lnQ[wave][pt * 16 + lg * 4 + r] = qP[pt][r];
            }
    }
    __syncthreads();   // also guarantees all outp reads (proj) are done

    // LN2 apply -> bounce xn through outp -> coalesced us8 writes
    float lgv[3], lbv[3];
    #pragma unroll
    for (int ot = 0; ot < 3; ot++) {
        int oc = wave * 48 + ot * 16 + lr;
        lgv[ot] = ln2g[oc]; lbv[ot] = ln2b[oc];
    }
    #pragma unroll
    for (int pt = 0; pt < 4; pt++) {
        float mu4[4], rs4[4];
        #pragma unroll
        for (int r = 0; r < 4; r++) {
            int px = pt * 16 + lg * 4 + r;
            float S = lnS[0][px] + lnS[1][px] + lnS[2][px] + lnS[3][px];
            float Qq = lnQ[0][px] + lnQ[1][px] + lnQ[2][px] + lnQ[3][px];
            float mu = S * (1.0f / 192.0f);
            float var = Qq * (1.0f / 192.0f) - mu * mu;
            mu4[r] = mu; rs4[r] = rsqrtf(var + 1e-5f);
        }
        #pragma unroll
        for (int ot = 0; ot < 3; ot++) {
            int oc = wave * 48 + ot * 16 + lr;
            #pragma unroll
            for (int r = 0; r < 4; r++) {
                int px = pt * 16 + lg * 4 + r;
                float xn = (acc[pt][ot][r] - mu4[r]) * rs4[r] * lgv[ot] + lbv[ot];
                outp[px][oc] = f2b(xn);
            }
        }
    }
    __syncthreads();

    #pragma unroll
    for (int q = 0; q < 6; q++) {
        int idx = q * 256 + tid;          // 0..1535
        int px = idx / 24, c8 = idx % 24;
        us8 v = *(const us8*)&outp[px][c8 * 8];
        *(us8*)(xnt + (bpx + n0 + px) * 192 + c8 * 8) = v;
    }
}

// ---------------------------------------------------------------------------
// depthwise 3x3 + gelu on [px][384], row-streamed LDS ring (16.9KB)
// ---------------------------------------------------------------------------
__global__ __launch_bounds__(256) void dwconv_t2_k(
    const unsigned short* __restrict__ h1t, const float* __restrict__ w,
    const float* __restrict__ bias, unsigned short* __restrict__ h2t)
{
    __shared__ unsigned short ring[4 * 4 * 66 * 8];
    const int bz = blockIdx.z;
    const int b = bz / 12, cb = (bz % 12) * 32;
    const int y0 = blockIdx.y * 8, x0 = blockIdx.x * 64;
    const int tid = threadIdx.x;
    const int x = tid & 63, cg = tid >> 6;
    const int c0 = cb + cg * 8;
    const size_t bbase = (size_t)b << 16;

    float wr[9][8], bi[8];
    #pragma unroll
    for (int i = 0; i < 8; i++) {
        #pragma unroll
        for (int j = 0; j < 9; j++) wr[j][i] = rfl(w[(c0 + i) * 9 + j]);
        bi[i] = rfl(bias[c0 + i]);
    }

    const us8 zz = {0, 0, 0, 0, 0, 0, 0, 0};

    auto stage_row = [&](int gy, int s) {
        unsigned short* ldsrow = &ring[((s * 4 + cg) * 66) * 8];
        if (gy >= 0 && gy <= 255) {
            us8 ev = zz;
            if (x == 0 && x0 > 0)
                ev = *(const us8*)(h1t + (bbase + gy * 256 + x0 - 1) * 384 + c0);
            if (x == 63 && x0 + 64 < 256)
                ev = *(const us8*)(h1t + (bbase + gy * 256 + x0 + 64) * 384 + c0);
            gload_lds16(h1t + (bbase + gy * 256 + x0 + x) * 384 + c0,
                        ldsrow + (1 + x) * 8);
            if (x == 0)  *(us8*)&ldsrow[0]      = ev;
            if (x == 63) *(us8*)&ldsrow[65 * 8] = ev;
        } else {
            *(us8*)&ldsrow[(1 + x) * 8] = zz;
            if (x == 0)  *(us8*)&ldsrow[0]      = zz;
            if (x == 63) *(us8*)&ldsrow[65 * 8] = zz;
        }
    };

    stage_row(y0 - 1, 0);
    stage_row(y0,     1);
    stage_row(y0 + 1, 2);
    __syncthreads();

    #pragma unroll
    for (int y = 0; y < 8; y++) {
        if (y < 7) stage_row(y0 + y + 2, (y + 3) & 3);

        float a[8];
        #pragma unroll
        for (int i = 0; i < 8; i++) a[i] = bi[i];
        #pragma unroll
        for (int t = 0; t < 3; t++) {
            const int s = (y + t) & 3;
            const unsigned short* rp = &ring[((s * 4 + cg) * 66 + x) * 8];
            us8 L = *(const us8*)(rp);
            us8 C = *(const us8*)(rp + 8);
            us8 R = *(const us8*)(rp + 16);
            #pragma unroll
            for (int i = 0; i < 8; i++) {
                a[i] += wr[t * 3 + 0][i] * b2f(L[i]);
                a[i] += wr[t * 3 + 1][i] * b2f(C[i]);
                a[i] += wr[t * 3 + 2][i] * b2f(R[i]);
            }
        }
        us8 ov;
        #pragma unroll
        for (int i = 0; i < 8; i++) ov[i] = f2b(gelu_t(a[i]));
        *(us8*)(h2t + (bbase + (y0 + y) * 256 + x0 + x) * 384 + c0) = ov;

        __syncthreads();
    }
}

// ---------------------------------------------------------------------------
extern "C" void kernel_launch(void* const* d_in, const int* in_sizes, int n_in,
                              void* d_out, int out_size, void* d_ws, size_t ws_size,
                              hipStream_t stream)
{
    const float* x    = (const float*)d_in[0];
    const float* ln1g = (const float*)d_in[1];
    const float* ln1b = (const float*)d_in[2];
    const float* qkvw = (const float*)d_in[3];
    const float* qkvb = (const float*)d_in[4];
    const float* outw = (const float*)d_in[5];
    const float* outb = (const float*)d_in[6];
    const float* ln2g = (const float*)d_in[7];
    const float* ln2b = (const float*)d_in[8];
    const float* w1   = (const float*)d_in[9];
    const float* b1   = (const float*)d_in[10];
    const float* dww  = (const float*)d_in[11];
    const float* dwb  = (const float*)d_in[12];
    const float* w2   = (const float*)d_in[13];
    const float* b2   = (const float*)d_in[14];
    float* out = (float*)d_out;

    char* ws = (char*)d_ws;
    unsigned short* kv  = (unsigned short*)ws;                            // [0,192MiB)
    unsigned short* h1t = (unsigned short*)ws;                            // [0,192MiB)
    unsigned short* h2t = (unsigned short*)(ws + (size_t)201326592);      // [192,384MiB)
    unsigned short* qT  = (unsigned short*)(ws + (size_t)201326592);      // [192,288MiB)
    unsigned short* xnt = (unsigned short*)(ws + (size_t)301989888);      // [288,384MiB)
    size_t off = (size_t)402653184;
    float* koff = (float*)(ws + off); off += 4096;
    float* ctxT = (float*)(ws + off); off += 131072;
    unsigned short* qkvwb = (unsigned short*)(ws + off); off += 221184;
    unsigned short* outwb = (unsigned short*)(ws + off); off += 73728 * 2;
    unsigned short* w1b   = (unsigned short*)(ws + off); off += 147456;
    unsigned short* w2b   = (unsigned short*)(ws + off); off += 147456;
    off = (off + 255) & ~(size_t)255;
    unsigned short* x2b = (unsigned short*)(ws + off);
    const bool bigws = ws_size >= off + (size_t)100663296;

    cvt_k<<<(110592 + 255) / 256, 256, 0, stream>>>(qkvw, qkvwb, 110592);
    cvt_k<<<(36864 + 255) / 256, 256, 0, stream>>>(outw, outwb, 36864);
    cvt_k<<<(73728 + 255) / 256, 256, 0, stream>>>(w1, w1b, 73728);
    cvt_k<<<(73728 + 255) / 256, 256, 0, stream>>>(w2, w2b, 73728);

    // 1) LN1 + transpose -> xnt
    lnt_k<<<1024, 256, 0, stream>>>(x, ln1g, ln1b, xnt);

    // 2) qkv GEMM: q -> qT[px][192], k/v -> kv[b][384][px]
    gemm2_k<192, 3, 3><<<4096, 256, 0, stream>>>(xnt, qkvwb, qkvb, nullptr, kv, 384, qT);

    // 3) k-row softmax offsets
    krow_k<<<768, 256, 0, stream>>>(kv, koff);

    // 4) context accumulation (256-thr, LDS-merged atomics)
    zero_k<<<128, 256, 0, stream>>>(ctxT, 32768);
    context_k<<<512, 256, 0, stream>>>(kv, koff, ctxT);

    // 5) qctx fused
    if (bigws)
        qctx_proj_k<true><<<4096, 256, 0, stream>>>(qT, ctxT, outwb, outb, x, out,
                                                    x2b, ln2g, ln2b, xnt);
    else
        qctx_proj_k<false><<<4096, 256, 0, stream>>>(qT, ctxT, outwb, outb, x, out,
                                                     x2b, ln2g, ln2b, xnt);

    // 6) w1 GEMM + gelu -> h1t [px][384]
    gemm2_k<192, 1, 2><<<4096, 256, 0, stream>>>(xnt, w1b, b1, nullptr, h1t, 384, nullptr);

    // 7) depthwise 3x3 + gelu -> h2t [px][384]
    dwconv_t2_k<<<dim3(4, 32, 48), 256, 0, stream>>>(h1t, dww, dwb, h2t);

    // 8) w2 GEMM + bias + x2 residual -> d_out f32
    if (bigws)
        gemm2_k<384, 4, 1><<<4096, 256, 0, stream>>>(h2t, w2b, b2, x2b, out, 192, nullptr);
    else
        gemm2_k<384, 2, 1><<<4096, 256, 0, stream>>>(h2t, w2b, b2, out, out, 192, nullptr);
}

// Round 11
// 971.692 us; speedup vs baseline: 1.4633x; 1.0789x over previous
//
#include <hip/hip_runtime.h>
#include <math.h>

typedef __attribute__((ext_vector_type(8))) short s8;
typedef __attribute__((ext_vector_type(8))) unsigned short us8;
typedef __attribute__((ext_vector_type(4))) float f4;
typedef __attribute__((ext_vector_type(4))) unsigned short us4;
typedef __attribute__((ext_vector_type(4))) unsigned int u32x4;

#define DEVI __device__ __forceinline__

static const int NPIX = 65536;   // 256*256

DEVI float b2f(unsigned short u) {
    unsigned int v = ((unsigned int)u) << 16;
    float f; __builtin_memcpy(&f, &v, 4); return f;
}
DEVI unsigned short f2b(float f) {
    unsigned int u; __builtin_memcpy(&u, &f, 4);
    unsigned int r = (u + 0x7FFFu + ((u >> 16) & 1u)) >> 16;
    return (unsigned short)r;
}
DEVI float geluf(float x) { return 0.5f * x * (1.0f + erff(x * 0.70710678118f)); }
DEVI float gelu_t(float x) {
    float z = 1.595769122f * (x + 0.044715f * x * x * x);
    return x * __builtin_amdgcn_rcpf(1.0f + __expf(-z));
}
DEVI float rfl(float v) {
    int i; __builtin_memcpy(&i, &v, 4);
    i = __builtin_amdgcn_readfirstlane(i);
    float o; __builtin_memcpy(&o, &i, 4); return o;
}

DEVI void gload_lds16(const unsigned short* g, unsigned short* l) {
    __builtin_amdgcn_global_load_lds(
        (const __attribute__((address_space(1))) unsigned int*)g,
        (__attribute__((address_space(3))) unsigned int*)l,
        16, 0, 0);
}

// ---------------------------------------------------------------------------
// LayerNorm + transpose: x f32 [b][192][px] -> xnt bf16 [b*px][192]
// ---------------------------------------------------------------------------
__global__ __launch_bounds__(256) void lnt_k(const float* __restrict__ X,
                                             const float* __restrict__ gw,
                                             const float* __restrict__ gb,
                                             unsigned short* __restrict__ Out)
{
    const int i = blockIdx.x * 256 + threadIdx.x;
    const int b = i >> 16, px = i & 65535;
    const float* xp = X + (size_t)b * 192 * NPIX + px;

    unsigned int pk[96];
    float sum = 0.f, ssq = 0.f;
    #pragma unroll
    for (int c = 0; c < 192; c++) {
        float v = xp[(size_t)c * NPIX];
        sum += v; ssq += v * v;
        unsigned int h = f2b(v);
        if (c & 1) pk[c >> 1] |= h << 16;
        else       pk[c >> 1] = h;
    }
    float mu = sum * (1.0f / 192.0f);
    float var = ssq * (1.0f / 192.0f) - mu * mu;
    float rs = rsqrtf(var + 1e-5f);

    #pragma unroll
    for (int c2 = 0; c2 < 96; c2++) {
        int c = c2 * 2;
        float lo = b2f((unsigned short)(pk[c2] & 0xFFFF));
        float hi = b2f((unsigned short)(pk[c2] >> 16));
        lo = (lo - mu) * rs * gw[c] + gb[c];
        hi = (hi - mu) * rs * gw[c + 1] + gb[c + 1];
        pk[c2] = (unsigned int)f2b(lo) | ((unsigned int)f2b(hi) << 16);
    }
    u32x4* dst = (u32x4*)(Out + (size_t)i * 192);
    #pragma unroll
    for (int j = 0; j < 6; j++) {
        u32x4 v = { pk[4 * j], pk[4 * j + 1], pk[4 * j + 2], pk[4 * j + 3] };
        dst[j] = v;
    }
}

// ---------------------------------------------------------------------------
// Pipelined staged GEMM: block processes NTILE tiles of 64 px; stage unit =
// 64px x 192k (24KB), double-buffered; stage(s+1) issued right after the
// barrier, before compute(s) -> HBM latency hides under MFMA phase.
// UNITS = K/192 stage-units per tile (w2: 2, acc accumulates across units).
// MODE 1: out bf16 [gp][OCTOT], bias+gelu            (w1 -> h1t)
// MODE 2: out f32  [b][192][px], bias + f32 resid    (w2, small-ws)
// MODE 3: qkv: cn==0 -> qT[gp][192]; cn=1,2 -> kv[b][384][px]
// MODE 4: out f32  [b][192][px], bias + bf16 resid   (w2, big-ws)
// ---------------------------------------------------------------------------
template<int MODE, int NCHUNK, int UNITS, int NTILE>
__global__ __launch_bounds__(256) void gemm3_k(
    const unsigned short* __restrict__ X, const unsigned short* __restrict__ Wb,
    const float* __restrict__ bias, const void* __restrict__ resid,
    void* __restrict__ Out, int OCTOT, unsigned short* __restrict__ qT)
{
    constexpr int KTOT = UNITS * 192;
    __shared__ unsigned short tile[2][64 * 192];

    const int tid = threadIdx.x;
    const int wave = tid >> 6, lane = tid & 63;
    const int lr = lane & 15, lg = lane >> 4;
    const int xr = lr & 7;

    auto stage = [&](int s, int buf) {
        const int t = s / UNITS, u = s - t * UNITS;
        const int gp0s = (blockIdx.x * NTILE + t) * 64;
        const unsigned short* Xb = X + (size_t)gp0s * KTOT + u * 192;
        #pragma unroll
        for (int j = 0; j < 6; j++) {
            int ci = (wave * 6 + j) * 64 + lane;
            int row = ci / 24;
            int c = ci - row * 24;
            int csw = (c & ~7) | ((c ^ row) & 7);
            gload_lds16(Xb + (size_t)row * KTOT + csw * 8, &tile[buf][ci * 8]);
        }
    };

    stage(0, 0);

    for (int t = 0; t < NTILE; t++) {
        const int gp0 = (blockIdx.x * NTILE + t) * 64;
        const int b = gp0 >> 16;
        const int pxb = gp0 & 65535;

        if constexpr (UNITS == 1) {
            __syncthreads();
            if (t + 1 < NTILE) stage(t + 1, (t + 1) & 1);
            const unsigned short* tb = tile[t & 1];

            #pragma unroll
            for (int cn = 0; cn < NCHUNK; cn++) {
                const int ocb = cn * 192 + wave * 48;
                const unsigned short* wrow = Wb + (size_t)(ocb + lr) * KTOT + lg * 8;
                const bool swapped = (MODE == 1) || (MODE == 3 && cn == 0);

                s8 wf[3][6];
                #pragma unroll
                for (int ot = 0; ot < 3; ot++)
                    #pragma unroll
                    for (int kk = 0; kk < 6; kk++)
                        wf[ot][kk] = *(const s8*)(wrow + (size_t)ot * 16 * KTOT + kk * 32);

                f4 acc[4][3];
                #pragma unroll
                for (int i = 0; i < 4; i++)
                    #pragma unroll
                    for (int j = 0; j < 3; j++) acc[i][j] = (f4)0.0f;

                #pragma unroll
                for (int kk = 0; kk < 6; kk++) {
                    const int kc = kk * 4 + lg;
                    const int kcs = (kc & ~7) | ((kc ^ xr) & 7);
                    s8 a[4];
                    #pragma unroll
                    for (int pt = 0; pt < 4; pt++)
                        a[pt] = *(const s8*)&tb[((pt * 16 + lr) * 24 + kcs) * 8];
                    #pragma unroll
                    for (int ot = 0; ot < 3; ot++)
                        #pragma unroll
                        for (int pt = 0; pt < 4; pt++)
                            acc[pt][ot] = swapped
                                ? __builtin_amdgcn_mfma_f32_16x16x32_bf16(wf[ot][kk], a[pt], acc[pt][ot], 0, 0, 0)
                                : __builtin_amdgcn_mfma_f32_16x16x32_bf16(a[pt], wf[ot][kk], acc[pt][ot], 0, 0, 0);
                }

                if (MODE == 3 && cn == 0) {
                    #pragma unroll
                    for (int pt = 0; pt < 4; pt++) {
                        const int gp = gp0 + pt * 16 + lr;
                        unsigned short* orow = qT + (size_t)gp * 192 + wave * 48 + lg * 4;
                        #pragma unroll
                        for (int ot = 0; ot < 3; ot++) {
                            f4 bi4 = *(const f4*)&bias[wave * 48 + ot * 16 + lg * 4];
                            us4 o;
                            #pragma unroll
                            for (int r = 0; r < 4; r++) o[r] = f2b(acc[pt][ot][r] + bi4[r]);
                            *(us4*)(orow + ot * 16) = o;
                        }
                    }
                } else if (MODE == 3) {
                    #pragma unroll
                    for (int ot = 0; ot < 3; ot++) {
                        const int oc = ocb + ot * 16 + lr;
                        const float bi = bias[oc];
                        const size_t rowoff = ((size_t)b * 384 + (oc - 192)) * NPIX + pxb + lg * 4;
                        #pragma unroll
                        for (int pt = 0; pt < 4; pt++) {
                            us4 o;
                            #pragma unroll
                            for (int r = 0; r < 4; r++) o[r] = f2b(acc[pt][ot][r] + bi);
                            *(us4*)((unsigned short*)Out + rowoff + pt * 16) = o;
                        }
                    }
                } else {  // MODE 1
                    #pragma unroll
                    for (int pt = 0; pt < 4; pt++) {
                        const int gp = gp0 + pt * 16 + lr;
                        unsigned short* orow = (unsigned short*)Out + (size_t)gp * OCTOT + ocb + lg * 4;
                        #pragma unroll
                        for (int ot = 0; ot < 3; ot++) {
                            f4 bi4 = *(const f4*)&bias[ocb + ot * 16 + lg * 4];
                            us4 o;
                            #pragma unroll
                            for (int r = 0; r < 4; r++) o[r] = f2b(geluf(acc[pt][ot][r] + bi4[r]));
                            *(us4*)(orow + ot * 16) = o;
                        }
                    }
                }
            }
        } else {
            // UNITS == 2, NCHUNK == 1 (w2)
            const int ocb = wave * 48;
            const unsigned short* wrow = Wb + (size_t)(ocb + lr) * KTOT + lg * 8;

            f4 acc[4][3];
            #pragma unroll
            for (int i = 0; i < 4; i++)
                #pragma unroll
                for (int j = 0; j < 3; j++) acc[i][j] = (f4)0.0f;

            #pragma unroll
            for (int u = 0; u < 2; u++) {
                const int s = t * 2 + u;
                __syncthreads();
                if (s + 1 < NTILE * 2) stage(s + 1, (s + 1) & 1);
                const unsigned short* tb = tile[s & 1];

                s8 wf[3][6];
                #pragma unroll
                for (int ot = 0; ot < 3; ot++)
                    #pragma unroll
                    for (int kk = 0; kk < 6; kk++)
                        wf[ot][kk] = *(const s8*)(wrow + (size_t)ot * 16 * KTOT + u * 192 + kk * 32);

                #pragma unroll
                for (int kk = 0; kk < 6; kk++) {
                    const int kc = kk * 4 + lg;
                    const int kcs = (kc & ~7) | ((kc ^ xr) & 7);
                    s8 a[4];
                    #pragma unroll
                    for (int pt = 0; pt < 4; pt++)
                        a[pt] = *(const s8*)&tb[((pt * 16 + lr) * 24 + kcs) * 8];
                    #pragma unroll
                    for (int ot = 0; ot < 3; ot++)
                        #pragma unroll
                        for (int pt = 0; pt < 4; pt++)
                            acc[pt][ot] = __builtin_amdgcn_mfma_f32_16x16x32_bf16(a[pt], wf[ot][kk], acc[pt][ot], 0, 0, 0);
                }
            }

            #pragma unroll
            for (int ot = 0; ot < 3; ot++) {
                const int oc = ocb + ot * 16 + lr;
                const float bi = bias[oc];
                const size_t rowoff = ((size_t)b * 192 + oc) * NPIX + pxb + lg * 4;
                #pragma unroll
                for (int pt = 0; pt < 4; pt++) {
                    if (MODE == 2) {
                        f4 rv = *(const f4*)((const float*)resid + rowoff + pt * 16);
                        f4 o;
                        #pragma unroll
                        for (int r = 0; r < 4; r++) o[r] = acc[pt][ot][r] + bi + rv[r];
                        *(f4*)((float*)Out + rowoff + pt * 16) = o;
                    } else {  // MODE 4
                        us4 rv = *(const us4*)((const unsigned short*)resid + rowoff + pt * 16);
                        f4 o;
                        #pragma unroll
                        for (int r = 0; r < 4; r++) o[r] = acc[pt][ot][r] + bi + b2f(rv[r]);
                        *(f4*)((float*)Out + rowoff + pt * 16) = o;
                    }
                }
            }
        }
    }
}

// ---------------------------------------------------------------------------
// Per-row max + log-sum-exp; 2 independent online chains for ILP.
// ---------------------------------------------------------------------------
__global__ __launch_bounds__(256) void krow_k(const unsigned short* __restrict__ kv,
                                              float* __restrict__ koff)
{
    int r = blockIdx.x;
    int b = r / 192, ch = r % 192;
    const unsigned short* Kp = kv + ((size_t)b * 384 + ch) * NPIX;
    int tid = threadIdx.x;
    float m0 = -1e30f, s0 = 0.f, m1 = -1e30f, s1 = 0.f;
    for (int i = 0; i < 128; i++) {
        float v0 = b2f(Kp[tid + (size_t)(2 * i) * 256]);
        float v1 = b2f(Kp[tid + (size_t)(2 * i + 1) * 256]);
        if (v0 > m0) { s0 = s0 * __expf(m0 - v0) + 1.f; m0 = v0; }
        else s0 += __expf(v0 - m0);
        if (v1 > m1) { s1 = s1 * __expf(m1 - v1) + 1.f; m1 = v1; }
        else s1 += __expf(v1 - m1);
    }
    float m = fmaxf(m0, m1);
    float s = s0 * __expf(m0 - m) + s1 * __expf(m1 - m);
    __shared__ float ms[256], ss[256];
    ms[tid] = m; ss[tid] = s;
    __syncthreads();
    for (int off = 128; off > 0; off >>= 1) {
        if (tid < off) {
            float m2 = ms[tid + off], s2 = ss[tid + off];
            float M2 = fmaxf(ms[tid], m2);
            ss[tid] = ss[tid] * __expf(ms[tid] - M2) + s2 * __expf(m2 - M2);
            ms[tid] = M2;
        }
        __syncthreads();
    }
    if (tid == 0) koff[r] = ms[0] + logf(ss[0]);
}

__global__ void zero_k(float* __restrict__ p, int n)
{
    int i = blockIdx.x * 256 + threadIdx.x;
    if (i < n) p[i] = 0.f;
}

__global__ void cvt_k(const float* __restrict__ src, unsigned short* __restrict__ dst, int n)
{
    int i = blockIdx.x * 256 + threadIdx.x;
    if (i < n) dst[i] = f2b(src[i]);
}

// ---------------------------------------------------------------------------
// context: 256-thr blocks; 4 n-chunks merged in LDS; atomics /4.
// ---------------------------------------------------------------------------
__global__ __launch_bounds__(256) void context_k(const unsigned short* __restrict__ kv,
                                                 const float* __restrict__ koff,
                                                 float* __restrict__ ctxT)
{
    __shared__ float red[4][64][16];
    int bid = blockIdx.x;
    int bh = bid >> 4, cgrp = bid & 15;
    int b = bh >> 3, h = bh & 7;
    int tid = threadIdx.x;
    int wave = tid >> 6, lane = tid & 63, lr = lane & 15, lg = lane >> 4;
    int chunk = cgrp * 4 + wave;
    size_t nbase = (size_t)chunk * 1024 + lg * 8;

    int c0 = h * 24 + lr;
    int c1 = h * 24 + 16 + lr;
    float ko0 = koff[b * 192 + c0];
    int i1 = b * 192 + c1; if (i1 > 767) i1 = 767;
    float ko1 = koff[i1];
    bool val1 = lr < 8;

    const unsigned short* k0p = kv + ((size_t)b * 384 + c0) * NPIX + nbase;
    const unsigned short* k1p = kv + ((size_t)b * 384 + (c1 > 191 ? 191 : c1)) * NPIX + nbase;
    const unsigned short* v0p = kv + ((size_t)b * 384 + 192 + h * 24 + lr) * NPIX + nbase;
    const unsigned short* v1p = kv + ((size_t)b * 384 + 192 + ((h * 24 + 16 + lr > 191) ? 191 : h * 24 + 16 + lr)) * NPIX + nbase;

    f4 acc[2][2];
    #pragma unroll
    for (int i = 0; i < 2; i++) for (int j = 0; j < 2; j++) acc[i][j] = (f4)0.0f;

    for (int s = 0; s < 32; s++) {
        int off = s * 32;
        s8 kr0 = *(const s8*)(k0p + off);
        s8 kr1 = *(const s8*)(k1p + off);
        s8 vr0 = *(const s8*)(v0p + off);
        s8 vr1 = *(const s8*)(v1p + off);
        s8 p0, p1;
        #pragma unroll
        for (int j = 0; j < 8; j++) {
            p0[j] = (short)f2b(__expf(b2f((unsigned short)kr0[j]) - ko0));
            p1[j] = val1 ? (short)f2b(__expf(b2f((unsigned short)kr1[j]) - ko1)) : (short)0;
        }
        acc[0][0] = __builtin_amdgcn_mfma_f32_16x16x32_bf16(p0, vr0, acc[0][0], 0, 0, 0);
        acc[0][1] = __builtin_amdgcn_mfma_f32_16x16x32_bf16(p0, vr1, acc[0][1], 0, 0, 0);
        acc[1][0] = __builtin_amdgcn_mfma_f32_16x16x32_bf16(p1, vr0, acc[1][0], 0, 0, 0);
        acc[1][1] = __builtin_amdgcn_mfma_f32_16x16x32_bf16(p1, vr1, acc[1][1], 0, 0, 0);
    }
    #pragma unroll
    for (int mt = 0; mt < 2; mt++)
        #pragma unroll
        for (int ct = 0; ct < 2; ct++)
            #pragma unroll
            for (int r = 0; r < 4; r++)
                red[wave][lane][mt * 8 + ct * 4 + r] = acc[mt][ct][r];
    __syncthreads();

    if (wave == 0) {
        float* base = ctxT + (size_t)(b * 8 + h) * 1024;
        #pragma unroll
        for (int j = 0; j < 16; j++) {
            float sum = red[0][lane][j] + red[1][lane][j] + red[2][lane][j] + red[3][lane][j];
            int mt = j >> 3, ct = (j >> 2) & 1, r = j & 3;
            int c = mt * 16 + lg * 4 + r;
            int d = ct * 16 + lr;
            atomicAdd(base + d * 32 + c, sum);
        }
    }
}

// ---------------------------------------------------------------------------
// fused qctx: q-softmax (register) -> ctx apply -> proj (px-on-reg-axis)
//   -> +x resid (f4) -> x2 out (f32 or bf16 x2b) -> LN2 -> xnt
// ---------------------------------------------------------------------------
template<bool BIGWS>
__global__ __launch_bounds__(256) void qctx_proj_k(
    const unsigned short* __restrict__ qT, const float* __restrict__ ctxT,
    const unsigned short* __restrict__ outWb, const float* __restrict__ outBias,
    const float* __restrict__ xres, float* __restrict__ Out,
    unsigned short* __restrict__ x2b,
    const float* __restrict__ ln2g, const float* __restrict__ ln2b,
    unsigned short* __restrict__ xnt)
{
    __shared__ unsigned short outp[64][200];
    __shared__ float lnS[4][64], lnQ[4][64];

    int tid = threadIdx.x, bid = blockIdx.x;
    int b = bid >> 10, n0 = (bid & 1023) * 64;
    int wave = tid >> 6, lane = tid & 63, lr = lane & 15, lg = lane >> 4;
    const size_t bpx = (size_t)b << 16;

    #pragma unroll
    for (int hh = 0; hh < 2; hh++) {
        int h = wave * 2 + hh;
        s8 cf[2];
        #pragma unroll
        for (int mt = 0; mt < 2; mt++) {
            const float* cp = ctxT + ((size_t)(b * 8 + h) * 32 + mt * 16 + lr) * 32 + lg * 8;
            s8 a;
            #pragma unroll
            for (int j = 0; j < 8; j++) a[j] = (short)f2b(cp[j]);
            cf[mt] = a;
        }
        #pragma unroll
        for (int nt = 0; nt < 4; nt++) {
            int n = nt * 16 + lr;
            s8 bfq = (s8)0;
            float sown = 0.f;
            if (lg < 3) {
                us8 qv = *(const us8*)(qT + (bpx + n0 + n) * 192 + h * 24 + lg * 8);
                #pragma unroll
                for (int j = 0; j < 8; j++) {
                    float e = __expf(b2f((unsigned short)qv[j]));
                    sown += e;
                    bfq[j] = (short)f2b(e);
                }
            }
            float den = sown;
            den += __shfl_xor(den, 16);
            den += __shfl_xor(den, 32);
            f4 z = (f4)0.0f;
            f4 d0 = __builtin_amdgcn_mfma_f32_16x16x32_bf16(cf[0], bfq, z, 0, 0, 0);
            f4 d1 = __builtin_amdgcn_mfma_f32_16x16x32_bf16(cf[1], bfq, z, 0, 0, 0);
            float sinv = 1.0f / den;
            us4 w0;
            #pragma unroll
            for (int r = 0; r < 4; r++) w0[r] = f2b(d0[r] * sinv);
            *(us4*)&outp[n][h * 24 + lg * 4] = w0;
            if (lg < 2) {
                us4 w1;
                #pragma unroll
                for (int r = 0; r < 4; r++) w1[r] = f2b(d1[r] * sinv);
                *(us4*)&outp[n][h * 24 + 16 + lg * 4] = w1;
            }
        }
    }
    __syncthreads();

    f4 acc[4][3];
    #pragma unroll
    for (int i = 0; i < 4; i++) for (int j = 0; j < 3; j++) acc[i][j] = (f4)0.0f;
    #pragma unroll
    for (int k0 = 0; k0 < 192; k0 += 32) {
        s8 bf[4];
        #pragma unroll
        for (int pt = 0; pt < 4; pt++)
            bf[pt] = *(const s8*)&outp[pt * 16 + lr][k0 + lg * 8];
        #pragma unroll
        for (int ot = 0; ot < 3; ot++) {
            s8 af = *(const s8*)&outWb[(size_t)(wave * 48 + ot * 16 + lr) * 192 + k0 + lg * 8];
            #pragma unroll
            for (int pt = 0; pt < 4; pt++)
                acc[pt][ot] = __builtin_amdgcn_mfma_f32_16x16x32_bf16(bf[pt], af, acc[pt][ot], 0, 0, 0);
        }
    }

    float sP[4][4], qP[4][4];
    #pragma unroll
    for (int pt = 0; pt < 4; pt++)
        #pragma unroll
        for (int r = 0; r < 4; r++) { sP[pt][r] = 0.f; qP[pt][r] = 0.f; }

    #pragma unroll
    for (int ot = 0; ot < 3; ot++) {
        const int oc = wave * 48 + ot * 16 + lr;
        const float bi = outBias[oc];
        const size_t rowbase = ((size_t)b * 192 + oc) * NPIX + n0 + lg * 4;
        #pragma unroll
        for (int pt = 0; pt < 4; pt++) {
            f4 rv = *(const f4*)(xres + rowbase + pt * 16);
            f4 v;
            #pragma unroll
            for (int r = 0; r < 4; r++) {
                v[r] = acc[pt][ot][r] + bi + rv[r];
                sP[pt][r] += v[r]; qP[pt][r] += v[r] * v[r];
            }
            acc[pt][ot] = v;
            if (BIGWS) {
                us4 o;
                #pragma unroll
                for (int r = 0; r < 4; r++) o[r] = f2b(v[r]);
                *(us4*)(x2b + rowbase + pt * 16) = o;
            } else {
                *(f4*)(Out + rowbase + pt * 16) = v;
            }
        }
    }
    #pragma unroll
    for (int pt = 0; pt < 4; pt++)
        #pragma unroll
        for (int r = 0; r < 4; r++) {
            float s = sP[pt][r], q = qP[pt][r];
            s += __shfl_xor(s, 1); s += __shfl_xor(s, 2);
            s += __shfl_xor(s, 4); s += __shfl_xor(s, 8);
            q += __shfl_xor(q, 1); q += __shfl_xor(q, 2);
            q += __shfl_xor(q, 4); q += __shfl_xor(q, 8);
            sP[pt][r] = s; qP[pt][r] = q;
        }
    if (lr == 0) {
        #pragma unroll
        for (int pt = 0; pt < 4; pt++)
            #pragma unroll
            for (int r = 0; r < 4; r++) {
                lnS[wave][pt * 16 + lg * 4 + r] = sP[pt][r];
                lnQ[wave][pt * 16 + lg * 4 + r] = qP[pt][r];
            }
    }
    __syncthreads();

    float lgv[3], lbv[3];
    #pragma unroll
    for (int ot = 0; ot < 3; ot++) {
        int oc = wave * 48 + ot * 16 + lr;
        lgv[ot] = ln2g[oc]; lbv[ot] = ln2b[oc];
    }
    #pragma unroll
    for (int pt = 0; pt < 4; pt++) {
        float mu4[4], rs4[4];
        #pragma unroll
        for (int r = 0; r < 4; r++) {
            int px = pt * 16 + lg * 4 + r;
            float S = lnS[0][px] + lnS[1][px] + lnS[2][px] + lnS[3][px];
            float Qq = lnQ[0][px] + lnQ[1][px] + lnQ[2][px] + lnQ[3][px];
            float mu = S * (1.0f / 192.0f);
            float var = Qq * (1.0f / 192.0f) - mu * mu;
            mu4[r] = mu; rs4[r] = rsqrtf(var + 1e-5f);
        }
        #pragma unroll
        for (int ot = 0; ot < 3; ot++) {
            int oc = wave * 48 + ot * 16 + lr;
            #pragma unroll
            for (int r = 0; r < 4; r++) {
                int px = pt * 16 + lg * 4 + r;
                float xn = (acc[pt][ot][r] - mu4[r]) * rs4[r] * lgv[ot] + lbv[ot];
                outp[px][oc] = f2b(xn);
            }
        }
    }
    __syncthreads();

    #pragma unroll
    for (int q = 0; q < 6; q++) {
        int idx = q * 256 + tid;
        int px = idx / 24, c8 = idx % 24;
        us8 v = *(const us8*)&outp[px][c8 * 8];
        *(us8*)(xnt + (bpx + n0 + px) * 192 + c8 * 8) = v;
    }
}

// ---------------------------------------------------------------------------
// depthwise 3x3 + gelu on [px][384], row-streamed LDS ring (16.9KB)
// ---------------------------------------------------------------------------
__global__ __launch_bounds__(256) void dwconv_t2_k(
    const unsigned short* __restrict__ h1t, const float* __restrict__ w,
    const float* __restrict__ bias, unsigned short* __restrict__ h2t)
{
    __shared__ unsigned short ring[4 * 4 * 66 * 8];
    const int bz = blockIdx.z;
    const int b = bz / 12, cb = (bz % 12) * 32;
    const int y0 = blockIdx.y * 8, x0 = blockIdx.x * 64;
    const int tid = threadIdx.x;
    const int x = tid & 63, cg = tid >> 6;
    const int c0 = cb + cg * 8;
    const size_t bbase = (size_t)b << 16;

    float wr[9][8], bi[8];
    #pragma unroll
    for (int i = 0; i < 8; i++) {
        #pragma unroll
        for (int j = 0; j < 9; j++) wr[j][i] = rfl(w[(c0 + i) * 9 + j]);
        bi[i] = rfl(bias[c0 + i]);
    }

    const us8 zz = {0, 0, 0, 0, 0, 0, 0, 0};

    auto stage_row = [&](int gy, int s) {
        unsigned short* ldsrow = &ring[((s * 4 + cg) * 66) * 8];
        if (gy >= 0 && gy <= 255) {
            us8 ev = zz;
            if (x == 0 && x0 > 0)
                ev = *(const us8*)(h1t + (bbase + gy * 256 + x0 - 1) * 384 + c0);
            if (x == 63 && x0 + 64 < 256)
                ev = *(const us8*)(h1t + (bbase + gy * 256 + x0 + 64) * 384 + c0);
            gload_lds16(h1t + (bbase + gy * 256 + x0 + x) * 384 + c0,
                        ldsrow + (1 + x) * 8);
            if (x == 0)  *(us8*)&ldsrow[0]      = ev;
            if (x == 63) *(us8*)&ldsrow[65 * 8] = ev;
        } else {
            *(us8*)&ldsrow[(1 + x) * 8] = zz;
            if (x == 0)  *(us8*)&ldsrow[0]      = zz;
            if (x == 63) *(us8*)&ldsrow[65 * 8] = zz;
        }
    };

    stage_row(y0 - 1, 0);
    stage_row(y0,     1);
    stage_row(y0 + 1, 2);
    __syncthreads();

    #pragma unroll
    for (int y = 0; y < 8; y++) {
        if (y < 7) stage_row(y0 + y + 2, (y + 3) & 3);

        float a[8];
        #pragma unroll
        for (int i = 0; i < 8; i++) a[i] = bi[i];
        #pragma unroll
        for (int t = 0; t < 3; t++) {
            const int s = (y + t) & 3;
            const unsigned short* rp = &ring[((s * 4 + cg) * 66 + x) * 8];
            us8 L = *(const us8*)(rp);
            us8 C = *(const us8*)(rp + 8);
            us8 R = *(const us8*)(rp + 16);
            #pragma unroll
            for (int i = 0; i < 8; i++) {
                a[i] += wr[t * 3 + 0][i] * b2f(L[i]);
                a[i] += wr[t * 3 + 1][i] * b2f(C[i]);
                a[i] += wr[t * 3 + 2][i] * b2f(R[i]);
            }
        }
        us8 ov;
        #pragma unroll
        for (int i = 0; i < 8; i++) ov[i] = f2b(gelu_t(a[i]));
        *(us8*)(h2t + (bbase + (y0 + y) * 256 + x0 + x) * 384 + c0) = ov;

        __syncthreads();
    }
}

// ---------------------------------------------------------------------------
extern "C" void kernel_launch(void* const* d_in, const int* in_sizes, int n_in,
                              void* d_out, int out_size, void* d_ws, size_t ws_size,
                              hipStream_t stream)
{
    const float* x    = (const float*)d_in[0];
    const float* ln1g = (const float*)d_in[1];
    const float* ln1b = (const float*)d_in[2];
    const float* qkvw = (const float*)d_in[3];
    const float* qkvb = (const float*)d_in[4];
    const float* outw = (const float*)d_in[5];
    const float* outb = (const float*)d_in[6];
    const float* ln2g = (const float*)d_in[7];
    const float* ln2b = (const float*)d_in[8];
    const float* w1   = (const float*)d_in[9];
    const float* b1   = (const float*)d_in[10];
    const float* dww  = (const float*)d_in[11];
    const float* dwb  = (const float*)d_in[12];
    const float* w2   = (const float*)d_in[13];
    const float* b2   = (const float*)d_in[14];
    float* out = (float*)d_out;

    char* ws = (char*)d_ws;
    unsigned short* kv  = (unsigned short*)ws;                            // [0,192MiB)
    unsigned short* h1t = (unsigned short*)ws;                            // [0,192MiB)
    unsigned short* h2t = (unsigned short*)(ws + (size_t)201326592);      // [192,384MiB)
    unsigned short* qT  = (unsigned short*)(ws + (size_t)201326592);      // [192,288MiB)
    unsigned short* xnt = (unsigned short*)(ws + (size_t)301989888);      // [288,384MiB)
    size_t off = (size_t)402653184;
    float* koff = (float*)(ws + off); off += 4096;
    float* ctxT = (float*)(ws + off); off += 131072;
    unsigned short* qkvwb = (unsigned short*)(ws + off); off += 221184;
    unsigned short* outwb = (unsigned short*)(ws + off); off += 73728 * 2;
    unsigned short* w1b   = (unsigned short*)(ws + off); off += 147456;
    unsigned short* w2b   = (unsigned short*)(ws + off); off += 147456;
    off = (off + 255) & ~(size_t)255;
    unsigned short* x2b = (unsigned short*)(ws + off);
    const bool bigws = ws_size >= off + (size_t)100663296;

    cvt_k<<<(110592 + 255) / 256, 256, 0, stream>>>(qkvw, qkvwb, 110592);
    cvt_k<<<(36864 + 255) / 256, 256, 0, stream>>>(outw, outwb, 36864);
    cvt_k<<<(73728 + 255) / 256, 256, 0, stream>>>(w1, w1b, 73728);
    cvt_k<<<(73728 + 255) / 256, 256, 0, stream>>>(w2, w2b, 73728);

    // 1) LN1 + transpose -> xnt
    lnt_k<<<1024, 256, 0, stream>>>(x, ln1g, ln1b, xnt);

    // 2) qkv GEMM (pipelined, 4 tiles/block): q -> qT, k/v -> kv
    gemm3_k<3, 3, 1, 4><<<1024, 256, 0, stream>>>(xnt, qkvwb, qkvb, nullptr, kv, 384, qT);

    // 3) k-row softmax offsets
    krow_k<<<768, 256, 0, stream>>>(kv, koff);

    // 4) context accumulation
    zero_k<<<128, 256, 0, stream>>>(ctxT, 32768);
    context_k<<<512, 256, 0, stream>>>(kv, koff, ctxT);

    // 5) qctx fused
    if (bigws)
        qctx_proj_k<true><<<4096, 256, 0, stream>>>(qT, ctxT, outwb, outb, x, out,
                                                    x2b, ln2g, ln2b, xnt);
    else
        qctx_proj_k<false><<<4096, 256, 0, stream>>>(qT, ctxT, outwb, outb, x, out,
                                                     x2b, ln2g, ln2b, xnt);

    // 6) w1 GEMM + gelu -> h1t (pipelined)
    gemm3_k<1, 2, 1, 4><<<1024, 256, 0, stream>>>(xnt, w1b, b1, nullptr, h1t, 384, nullptr);

    // 7) depthwise 3x3 + gelu -> h2t
    dwconv_t2_k<<<dim3(4, 32, 48), 256, 0, stream>>>(h1t, dww, dwb, h2t);

    // 8) w2 GEMM + bias + x2 residual -> d_out f32 (pipelined, 2 units/tile)
    if (bigws)
        gemm3_k<4, 1, 2, 4><<<1024, 256, 0, stream>>>(h2t, w2b, b2, x2b, out, 192, nullptr);
    else
        gemm3_k<2, 1, 2, 4><<<1024, 256, 0, stream>>>(h2t, w2b, b2, out, out, 192, nullptr);
}